// Round 1
// 2796.931 us; speedup vs baseline: 1.2183x; 1.2183x over previous
//
#include <hip/hip_runtime.h>
#include <hip/hip_bf16.h>

// ---------------------------------------------------------------------------
// Decision-Transformer forward, MI355X round 5:
//  - Attention moved to MFMA (mfma_f32_16x16x32_f16): Q/K written fp16
//    row-major (Q pre-scaled 1/8), V produced TRANSPOSED by swapped-operand
//    GEMM (V^T = WvT @ X^T via gemm_core(A=WvT, Bt=Xb)).
//  - attn_mfma: 64-q tile, 4 waves x 16 rows, K/V/P tiles in LDS with XOR
//    chunk swizzle (conflict-free ds_read_b128 fragments), online softmax in
//    registers (shfl_xor width-16), async-stage prefetch of next K/V tile,
//    LDS 24 KB (was 68 KB).
// Workspace: 84 MB (X 12 | Qh 6 | Kh 6 | Vt 6 | Xb 6 | Yb 6 | Wb 24).
// ---------------------------------------------------------------------------

#define S_LEN 768
#define C_DIM 1024
#define NHEAD 16
#define HDIM 64
#define BATCH 4
#define TCTX 256
#define DFF 4096
#define NACT 80
#define MROWS (BATCH * S_LEN)   // 3072

typedef __attribute__((ext_vector_type(4))) float f32x4;
typedef __attribute__((ext_vector_type(8))) short bf16x8;
typedef __attribute__((ext_vector_type(8))) _Float16 f16x8;

static __device__ __forceinline__ unsigned short f2bf(float f) {
    unsigned int u = __float_as_uint(f);
    u += 0x7FFF + ((u >> 16) & 1);          // RNE
    return (unsigned short)(u >> 16);
}
static __device__ __forceinline__ float bf2f(unsigned short h) {
    return __uint_as_float(((unsigned int)h) << 16);
}
static __device__ __forceinline__ unsigned short f2h(float f) {
    _Float16 h = (_Float16)f;
    return __builtin_bit_cast(unsigned short, h);
}

// ---------------------------------------------------------------------------
// Weight conversion: per layer, f32 [K][N] -> bf16 transposed [N][K] in Wb.
// Wb elem offsets: WqT 0, WkT 1M, WvT 2M, WoT 3M, Wm1T 4M (N=4096,K=1024),
// Wm2T 8M (N=1024,K=4096). 64x64 tiles via LDS, coalesced in and out.
// ---------------------------------------------------------------------------
__global__ __launch_bounds__(256) void transpose_w_kernel(
    const float* __restrict__ Wq, const float* __restrict__ Wk,
    const float* __restrict__ Wv, const float* __restrict__ Wo,
    const float* __restrict__ Wm1, const float* __restrict__ Wm2,
    unsigned short* __restrict__ Wb)
{
    const int t = blockIdx.x;
    const float* src; unsigned short* dst; int K, N, kt, nt;
    if (t < 1024) {
        const int m = t >> 8, tile = t & 255;
        src = (m == 0) ? Wq : (m == 1) ? Wk : (m == 2) ? Wv : Wo;
        dst = Wb + (size_t)m * 1048576;
        K = 1024; N = 1024; kt = tile >> 4; nt = tile & 15;
    } else if (t < 2048) {
        const int tile = t - 1024;
        src = Wm1; dst = Wb + (size_t)4 * 1048576;
        K = 1024; N = 4096; kt = tile >> 6; nt = tile & 63;
    } else {
        const int tile = t - 2048;
        src = Wm2; dst = Wb + (size_t)8 * 1048576;
        K = 4096; N = 1024; kt = tile >> 4; nt = tile & 15;
    }
    const int k0 = kt * 64, n0 = nt * 64;
    __shared__ float Ls[64][65];

    const int r = threadIdx.x >> 2, p = threadIdx.x & 3;
    #pragma unroll
    for (int i = 0; i < 4; ++i)
        *(float4*)&Ls[r][p * 16 + i * 4] =
            *(const float4*)&src[(size_t)(k0 + r) * N + n0 + p * 16 + i * 4];
    __syncthreads();

    unsigned short __align__(16) h[16];
    #pragma unroll
    for (int i = 0; i < 16; ++i) h[i] = f2bf(Ls[p * 16 + i][r]);
    unsigned short* d = dst + (size_t)(n0 + r) * K + k0 + p * 16;
    *(uint4*)d       = *(uint4*)&h[0];
    *(uint4*)(d + 8) = *(uint4*)&h[8];
}

// ---------------------------------------------------------------------------
// Embedding (unchanged): one block per (b,t) -> X f32.
// ---------------------------------------------------------------------------
__global__ __launch_bounds__(256) void embed_kernel(
    const float* __restrict__ states, const float* __restrict__ rtgs,
    const float* __restrict__ meta,
    const float* __restrict__ c1w, const float* __restrict__ c1b,
    const float* __restrict__ c2w, const float* __restrict__ c2b,
    const float* __restrict__ c3w, const float* __restrict__ c3b,
    const float* __restrict__ encw, const float* __restrict__ encb,
    const float* __restrict__ mw1, const float* __restrict__ mb1,
    const float* __restrict__ mw2, const float* __restrict__ mb2,
    const float* __restrict__ retw, const float* __restrict__ retb,
    const float* __restrict__ aemb, const float* __restrict__ pos,
    const float* __restrict__ gpos,
    const int* __restrict__ actions, const int* __restrict__ timesteps,
    float* __restrict__ X)
{
    const int n = blockIdx.x;
    const int b = n >> 8, t = n & 255;
    const int tid = threadIdx.x;

    __shared__ float sin_[640];
    __shared__ float h1[96];
    __shared__ float h2[32];
    __shared__ float feat[16];
    __shared__ float hidm[32];
    __shared__ float mer[4];

    for (int e = tid; e < 640; e += 256)
        sin_[e] = states[(size_t)n * 640 + e];
    __syncthreads();

    if (tid < 96) {
        int o = tid / 6, rem = tid % 6, oh = rem / 3, ow = rem % 3;
        float a = c1b[o];
        for (int ci = 0; ci < 8; ++ci)
            for (int kh = 0; kh < 8; ++kh) {
                int ih = oh * 2 - 1 + kh;
                if (ih < 0 || ih >= 8) continue;
                for (int kw = 0; kw < 8; ++kw) {
                    int iw = ow * 2 - 1 + kw;
                    if (iw < 0 || iw >= 10) continue;
                    a += c1w[((o * 8 + ci) * 8 + kh) * 8 + kw] * sin_[ci * 80 + ih * 10 + iw];
                }
            }
        h1[tid] = fmaxf(a, 0.f);
    }
    if (tid < 32) {
        float a = mb1[tid];
        for (int i = 0; i < 4; ++i)
            a += meta[(size_t)n * 4 + i] * mw1[i * 32 + tid];
        hidm[tid] = fmaxf(a, 0.f);
    }
    __syncthreads();

    if (tid < 32) {
        float a = c2b[tid];
        for (int ci = 0; ci < 16; ++ci)
            for (int kh = 0; kh < 4; ++kh) {
                int ih = -1 + kh;
                if (ih < 0 || ih >= 2) continue;
                for (int kw = 0; kw < 4; ++kw) {
                    int iw = -1 + kw;
                    if (iw < 0 || iw >= 3) continue;
                    a += c2w[((tid * 16 + ci) * 4 + kh) * 4 + kw] * h1[ci * 6 + ih * 3 + iw];
                }
            }
        h2[tid] = fmaxf(a, 0.f);
    }
    __syncthreads();

    if (tid < 16) {
        float a = c3b[tid];
        for (int ci = 0; ci < 32; ++ci)
            a += c3w[(tid * 32 + ci) * 9 + 4] * h2[ci];
        feat[tid] = fmaxf(a, 0.f);
    }
    if (tid < 4) {
        float a = mb2[tid];
        for (int j = 0; j < 32; ++j) a += hidm[j] * mw2[j * 4 + tid];
        mer[tid] = a;
    }
    __syncthreads();

    const float r = rtgs[n];
    const int a_idx = actions[n];
    const int g = timesteps[b];
    const size_t xbase = ((size_t)b * S_LEN + 3 * t) * C_DIM;

    for (int c = tid; c < C_DIM; c += 256) {
        float se;
        if (c < 1020) {
            float acc = encb[c];
            #pragma unroll
            for (int k = 0; k < 16; ++k) acc += feat[k] * encw[k * 1020 + c];
            se = acc;
        } else {
            se = mer[c - 1020];
        }
        const float st = tanhf(se);
        const float rt = tanhf(r * retw[c] + retb[c]);
        const float ae = aemb[(size_t)a_idx * C_DIM + c];
        const float gp = gpos[(size_t)g * C_DIM + c];
        X[xbase + c]             = rt + gp + pos[(size_t)(3 * t + 0) * C_DIM + c];
        X[xbase + C_DIM + c]     = st + gp + pos[(size_t)(3 * t + 1) * C_DIM + c];
        X[xbase + 2 * C_DIM + c] = ae + gp + pos[(size_t)(3 * t + 2) * C_DIM + c];
    }
}

// ---------------------------------------------------------------------------
// LayerNorm over last dim (1024), bf16 output.
// ---------------------------------------------------------------------------
__global__ __launch_bounds__(256) void ln_bf16_kernel(
    const float* __restrict__ in, unsigned short* __restrict__ out,
    const float* __restrict__ gw, const float* __restrict__ bw)
{
    const int row = blockIdx.x, tid = threadIdx.x;
    __shared__ float red[256];
    const float* x = in + (size_t)row * C_DIM;

    float v[4];
    float s = 0.f;
    #pragma unroll
    for (int j = 0; j < 4; ++j) { v[j] = x[tid + j * 256]; s += v[j]; }
    red[tid] = s; __syncthreads();
    for (int st = 128; st > 0; st >>= 1) { if (tid < st) red[tid] += red[tid + st]; __syncthreads(); }
    const float mean = red[0] * (1.0f / 1024.0f);
    __syncthreads();

    float s2 = 0.f;
    #pragma unroll
    for (int j = 0; j < 4; ++j) { float d = v[j] - mean; s2 += d * d; }
    red[tid] = s2; __syncthreads();
    for (int st = 128; st > 0; st >>= 1) { if (tid < st) red[tid] += red[tid + st]; __syncthreads(); }
    const float inv = rsqrtf(red[0] * (1.0f / 1024.0f) + 1e-5f);

    #pragma unroll
    for (int j = 0; j < 4; ++j) {
        const int c = tid + j * 256;
        out[(size_t)row * C_DIM + c] = f2bf((v[j] - mean) * inv * gw[c] + bw[c]);
    }
}

// ---------------------------------------------------------------------------
// MFMA GEMM core: A bf16 [M][K] row-major; Bt bf16 [N][K] (pre-transposed).
// 128x128 tile, BK=32, 4 waves, 4x4 16x16x32 frags each, f32 accum.
// ---------------------------------------------------------------------------
__device__ __forceinline__ void gemm_core(
    const unsigned short* __restrict__ A, const unsigned short* __restrict__ Bt,
    int row0, int col0, int K, f32x4 (&acc)[4][4])
{
    __shared__ __align__(16) unsigned short As2[4][128][8];
    __shared__ __align__(16) unsigned short Bs2[4][128][8];

    const int tid = threadIdx.x;
    const int ar  = tid & 63, akg = tid >> 6;     // staging: row/col, k-group
    const int lane = tid & 63, w = tid >> 6;
    const int rwl = (w >> 1) * 64, cwl = (w & 1) * 64;
    const int mi = lane & 15, kg = lane >> 4;

    for (int k0 = 0; k0 < K; k0 += 32) {
        const unsigned short* pa = A + (size_t)(row0 + ar) * K + (k0 + akg * 8);
        uint4 va0 = *(const uint4*)pa;
        uint4 va1 = *(const uint4*)(pa + (size_t)64 * K);
        const unsigned short* pb = Bt + (size_t)(col0 + ar) * K + (k0 + akg * 8);
        uint4 vb0 = *(const uint4*)pb;
        uint4 vb1 = *(const uint4*)(pb + (size_t)64 * K);

        *(uint4*)&As2[akg][ar][0]      = va0;
        *(uint4*)&As2[akg][ar + 64][0] = va1;
        *(uint4*)&Bs2[akg][ar][0]      = vb0;
        *(uint4*)&Bs2[akg][ar + 64][0] = vb1;
        __syncthreads();

        bf16x8 af[4], bfr[4];
        #pragma unroll
        for (int i = 0; i < 4; ++i) {
            af[i]  = *(const bf16x8*)&As2[kg][rwl + i * 16 + mi][0];
            bfr[i] = *(const bf16x8*)&Bs2[kg][cwl + i * 16 + mi][0];
        }
        #pragma unroll
        for (int ri = 0; ri < 4; ++ri)
            #pragma unroll
            for (int ci = 0; ci < 4; ++ci)
                acc[ri][ci] = __builtin_amdgcn_mfma_f32_16x16x32_bf16(
                    af[ri], bfr[ci], acc[ri][ci], 0, 0, 0);
        __syncthreads();
    }
}

// Epilogue variants. ACT: 1=gelu. OUTB: 1=bf16 out. RES: add resid.
template<int ACT, int OUTB, int RES>
__global__ __launch_bounds__(256) void mfma_gemm(
    const unsigned short* __restrict__ A, const unsigned short* __restrict__ Bt,
    const float* __restrict__ bias, const float* resid,
    float* outf, unsigned short* __restrict__ outb,
    int N, int K)
{
    const int row0 = blockIdx.y * 128, col0 = blockIdx.x * 128;
    f32x4 acc[4][4] = {};
    gemm_core(A, Bt, row0, col0, K, acc);

    const int lane = threadIdx.x & 63, w = threadIdx.x >> 6;
    const int rwl = (w >> 1) * 64, cwl = (w & 1) * 64;
    const int mi = lane & 15, kg = lane >> 4;

    #pragma unroll
    for (int ri = 0; ri < 4; ++ri) {
        #pragma unroll
        for (int ci = 0; ci < 4; ++ci) {
            #pragma unroll
            for (int j = 0; j < 4; ++j) {
                const int row = row0 + rwl + ri * 16 + kg * 4 + j;
                const int col = col0 + cwl + ci * 16 + mi;
                float v = acc[ri][ci][j] + bias[col];
                if (ACT) v = 0.5f * v * (1.0f + erff(v * 0.70710678118f));
                if (RES) v += resid[(size_t)row * N + col];
                if (OUTB) outb[(size_t)row * N + col] = f2bf(v);
                else      outf[(size_t)row * N + col] = v;
            }
        }
    }
}

// Q/K fused: blockIdx.x = grp(2)*8 + coltile; fp16 out, Q pre-scaled by 1/8.
__global__ __launch_bounds__(256) void mfma_gemm_qk(
    const unsigned short* __restrict__ A, const unsigned short* __restrict__ Wb,
    const float* __restrict__ bq, const float* __restrict__ bk,
    unsigned short* __restrict__ Qh, unsigned short* __restrict__ Kh)
{
    const int grp = blockIdx.x >> 3;
    const unsigned short* Bt = Wb + (size_t)grp * 1048576;
    const float* bias = grp == 0 ? bq : bk;
    unsigned short* out = grp == 0 ? Qh : Kh;
    const float scale = grp == 0 ? 0.125f : 1.0f;
    const int row0 = blockIdx.y * 128, col0 = (blockIdx.x & 7) * 128;

    f32x4 acc[4][4] = {};
    gemm_core(A, Bt, row0, col0, C_DIM, acc);

    const int lane = threadIdx.x & 63, w = threadIdx.x >> 6;
    const int rwl = (w >> 1) * 64, cwl = (w & 1) * 64;
    const int mi = lane & 15, kg = lane >> 4;

    #pragma unroll
    for (int ri = 0; ri < 4; ++ri)
        #pragma unroll
        for (int ci = 0; ci < 4; ++ci)
            #pragma unroll
            for (int j = 0; j < 4; ++j) {
                const int row = row0 + rwl + ri * 16 + kg * 4 + j;
                const int col = col0 + cwl + ci * 16 + mi;
                out[(size_t)row * C_DIM + col] = f2h((acc[ri][ci][j] + bias[col]) * scale);
            }
}

// V TRANSPOSED by operand swap: V^T[cout][token] = WvT @ X^T
//   = gemm_core(A = WvT [1024][1024], Bt = Xb [3072][1024]).  Bias per ROW.
__global__ __launch_bounds__(256) void mfma_gemm_vt(
    const unsigned short* __restrict__ WvT, const unsigned short* __restrict__ Xb,
    const float* __restrict__ bv, unsigned short* __restrict__ Vt)
{
    const int row0 = blockIdx.y * 128, col0 = blockIdx.x * 128;
    f32x4 acc[4][4] = {};
    gemm_core(WvT, Xb, row0, col0, C_DIM, acc);

    const int lane = threadIdx.x & 63, w = threadIdx.x >> 6;
    const int rwl = (w >> 1) * 64, cwl = (w & 1) * 64;
    const int mi = lane & 15, kg = lane >> 4;

    #pragma unroll
    for (int ri = 0; ri < 4; ++ri)
        #pragma unroll
        for (int ci = 0; ci < 4; ++ci)
            #pragma unroll
            for (int j = 0; j < 4; ++j) {
                const int row = row0 + rwl + ri * 16 + kg * 4 + j;   // cout
                const int col = col0 + cwl + ci * 16 + mi;           // token
                Vt[(size_t)row * MROWS + col] = f2h(acc[ri][ci][j] + bv[row]);
            }
}

// ---------------------------------------------------------------------------
// MFMA flash attention: block per (qtile=64, h, b), 4 waves x 16 q-rows.
// Qh/Kh fp16 [b][s][1024] (Q pre-scaled 1/8); Vt fp16 [1024][3072] (V^T).
// LDS 24KB: Ks/Vs/Ps 8KB each, XOR-chunk-swizzled so every fragment
// ds_read_b128 is conflict-free; Ob f32 [64][68] aliases all after the loop.
// Async-stage: next K/V tile's global loads issue before compute (T14).
// ---------------------------------------------------------------------------
__global__ __launch_bounds__(256) void attn_mfma(
    const unsigned short* __restrict__ Qh, const unsigned short* __restrict__ Kh,
    const unsigned short* __restrict__ Vt, unsigned short* __restrict__ Yb)
{
    const int qt = blockIdx.x, h = blockIdx.y, b = blockIdx.z;
    const int tid = threadIdx.x;
    const int lane = tid & 63, w = tid >> 6;
    const int mi = lane & 15, kg = lane >> 4;
    const int q0 = qt * 64;

    __shared__ __align__(16) char ldsraw[24576];
    unsigned short* Ks = (unsigned short*)ldsraw;            // [64 key][64 c]
    unsigned short* Vs = (unsigned short*)(ldsraw + 8192);   // [64 d][64 key]
    unsigned short* Ps = (unsigned short*)(ldsraw + 16384);  // [64 q][64 key]
    float* Ob = (float*)ldsraw;                              // [64][68] after loop

    const size_t qkbase = (size_t)b * S_LEN * C_DIM + (size_t)h * HDIM;
    const unsigned short* Kbase = Kh + qkbase;
    const unsigned short* Vbase = Vt + (size_t)h * HDIM * MROWS + (size_t)b * S_LEN;

    // Q A-fragments: lane holds Q[q0+w*16+mi][kg*8..+8 (+32)]
    f16x8 QA0, QA1;
    {
        const unsigned short* qp = Qh + qkbase + (size_t)(q0 + w * 16 + mi) * C_DIM + kg * 8;
        QA0 = *(const f16x8*)qp;
        QA1 = *(const f16x8*)(qp + 32);
    }

    // staging: thread covers tile rows {srow, srow+32}, 16B chunk sc16
    const int srow = tid >> 3, sc16 = tid & 7;
    const int dch = (sc16 ^ (srow & 7)) << 3;   // swizzled half-offset in row

    float mrow[4], lrow[4], alj[4];
    f32x4 Oacc[4];
    #pragma unroll
    for (int j = 0; j < 4; ++j) { mrow[j] = -1e30f; lrow[j] = 0.f; }
    #pragma unroll
    for (int df = 0; df < 4; ++df) Oacc[df] = (f32x4){0.f, 0.f, 0.f, 0.f};

    // preload tile 0
    uint4 rk0, rk1, rv0, rv1;
    {
        const unsigned short* kp = Kbase + (size_t)srow * C_DIM + sc16 * 8;
        rk0 = *(const uint4*)kp;
        rk1 = *(const uint4*)(kp + (size_t)32 * C_DIM);
        const unsigned short* vp = Vbase + (size_t)srow * MROWS + sc16 * 8;
        rv0 = *(const uint4*)vp;
        rv1 = *(const uint4*)(vp + (size_t)32 * MROWS);
    }

    for (int kt = 0; kt <= qt; ++kt) {
        __syncthreads();   // prev tile's readers done
        *(uint4*)&Ks[srow * 64 + dch]        = rk0;
        *(uint4*)&Ks[(srow + 32) * 64 + dch] = rk1;
        *(uint4*)&Vs[srow * 64 + dch]        = rv0;
        *(uint4*)&Vs[(srow + 32) * 64 + dch] = rv1;
        if (kt < qt) {   // async prefetch next tile (latency hides under compute)
            const unsigned short* kp = Kbase + (size_t)((kt + 1) * 64 + srow) * C_DIM + sc16 * 8;
            rk0 = *(const uint4*)kp;
            rk1 = *(const uint4*)(kp + (size_t)32 * C_DIM);
            const unsigned short* vp = Vbase + (size_t)srow * MROWS + (kt + 1) * 64 + sc16 * 8;
            rv0 = *(const uint4*)vp;
            rv1 = *(const uint4*)(vp + (size_t)32 * MROWS);
        }
        __syncthreads();   // stage visible

        // ---- scores S = Q @ K^T (16q x 64k per wave)
        f32x4 sa[4];
        #pragma unroll
        for (int kf = 0; kf < 4; ++kf) {
            const int key = kf * 16 + mi;
            const unsigned short* kr = Ks + key * 64;
            const f16x8 kb0 = *(const f16x8*)(kr + ((kg ^ (key & 7)) << 3));
            const f16x8 kb1 = *(const f16x8*)(kr + (((4 + kg) ^ (key & 7)) << 3));
            f32x4 z = {0.f, 0.f, 0.f, 0.f};
            z = __builtin_amdgcn_mfma_f32_16x16x32_f16(QA0, kb0, z, 0, 0, 0);
            sa[kf] = __builtin_amdgcn_mfma_f32_16x16x32_f16(QA1, kb1, z, 0, 0, 0);
        }

        if (kt == qt) {   // causal mask within diagonal tile
            #pragma unroll
            for (int kf = 0; kf < 4; ++kf)
                #pragma unroll
                for (int j = 0; j < 4; ++j)
                    if (kf * 16 + mi > w * 16 + kg * 4 + j) sa[kf][j] = -1e30f;
        }

        // ---- online softmax: row j lives in (kg,reg); reduce over mi lanes
        #pragma unroll
        for (int j = 0; j < 4; ++j) {
            float rm = fmaxf(fmaxf(sa[0][j], sa[1][j]), fmaxf(sa[2][j], sa[3][j]));
            rm = fmaxf(rm, __shfl_xor(rm, 1, 16));
            rm = fmaxf(rm, __shfl_xor(rm, 2, 16));
            rm = fmaxf(rm, __shfl_xor(rm, 4, 16));
            rm = fmaxf(rm, __shfl_xor(rm, 8, 16));
            const float mn = fmaxf(mrow[j], rm);
            alj[j] = __expf(mrow[j] - mn);
            mrow[j] = mn;
            const float p0 = __expf(sa[0][j] - mn);
            const float p1 = __expf(sa[1][j] - mn);
            const float p2 = __expf(sa[2][j] - mn);
            const float p3 = __expf(sa[3][j] - mn);
            const int prow = w * 16 + kg * 4 + j;
            unsigned short* pr = Ps + prow * 64;
            const int sw = prow & 7, hi = mi >> 3, lo = mi & 7;
            pr[(((0 + hi) ^ sw) << 3) + lo] = f2h(p0);
            pr[(((2 + hi) ^ sw) << 3) + lo] = f2h(p1);
            pr[(((4 + hi) ^ sw) << 3) + lo] = f2h(p2);
            pr[(((6 + hi) ^ sw) << 3) + lo] = f2h(p3);
            float rs = p0 + p1 + p2 + p3;
            rs += __shfl_xor(rs, 1, 16);
            rs += __shfl_xor(rs, 2, 16);
            rs += __shfl_xor(rs, 4, 16);
            rs += __shfl_xor(rs, 8, 16);
            lrow[j] = lrow[j] * alj[j] + rs;
        }
        // no barrier needed: P written & read by the SAME wave's strip only

        // ---- O = O*alpha + P @ V (16q x 64d per wave)
        const unsigned short* pp = Ps + (w * 16 + mi) * 64;
        const int psw = mi & 7;
        const f16x8 PA0 = *(const f16x8*)(pp + ((kg ^ psw) << 3));
        const f16x8 PA1 = *(const f16x8*)(pp + (((4 + kg) ^ psw) << 3));
        #pragma unroll
        for (int df = 0; df < 4; ++df) {
            const int d = df * 16 + mi;
            const unsigned short* vr = Vs + d * 64;
            const f16x8 vb0 = *(const f16x8*)(vr + ((kg ^ (d & 7)) << 3));
            const f16x8 vb1 = *(const f16x8*)(vr + (((4 + kg) ^ (d & 7)) << 3));
            f32x4 o = Oacc[df];
            o[0] *= alj[0]; o[1] *= alj[1]; o[2] *= alj[2]; o[3] *= alj[3];
            o = __builtin_amdgcn_mfma_f32_16x16x32_f16(PA0, vb0, o, 0, 0, 0);
            Oacc[df] = __builtin_amdgcn_mfma_f32_16x16x32_f16(PA1, vb1, o, 0, 0, 0);
        }
    }

    // ---- normalize, bounce through LDS (Ob aliases Ks/Vs/Ps), coalesced store
    __syncthreads();
    float inv[4];
    #pragma unroll
    for (int j = 0; j < 4; ++j) inv[j] = 1.0f / lrow[j];
    #pragma unroll
    for (int df = 0; df < 4; ++df)
        #pragma unroll
        for (int j = 0; j < 4; ++j)
            Ob[(w * 16 + kg * 4 + j) * 68 + df * 16 + mi] = Oacc[df][j] * inv[j];
    __syncthreads();

    const int orow = tid >> 2, oc0 = (tid & 3) * 16;
    unsigned short __align__(16) hx[16];
    #pragma unroll
    for (int i = 0; i < 16; ++i) hx[i] = f2bf(Ob[orow * 68 + oc0 + i]);
    unsigned short* yp = Yb + qkbase + (size_t)(q0 + orow) * C_DIM + oc0;
    *(uint4*)yp       = *(uint4*)&hx[0];
    *(uint4*)(yp + 8) = *(uint4*)&hx[8];
}

// ---------------------------------------------------------------------------
// Head: block per (b,t); bf16 final-LN row @ s=3t+1 times head_w -> f32 out.
// ---------------------------------------------------------------------------
__global__ __launch_bounds__(256) void head_kernel(
    const unsigned short* __restrict__ Xb, const float* __restrict__ hw,
    float* __restrict__ out)
{
    const int n = blockIdx.x;
    const int b = n >> 8, t = n & 255;
    const int tid = threadIdx.x;
    __shared__ float rowv[C_DIM];

    const unsigned short* x = Xb + ((size_t)b * S_LEN + 3 * t + 1) * C_DIM;
    #pragma unroll
    for (int j = 0; j < 4; ++j) rowv[tid + j * 256] = bf2f(x[tid + j * 256]);
    __syncthreads();

    if (tid < NACT) {
        float a = 0.f;
        for (int k = 0; k < C_DIM; ++k) a += rowv[k] * hw[k * NACT + tid];
        out[(size_t)n * NACT + tid] = a;
    }
}

// ---------------------------------------------------------------------------
extern "C" void kernel_launch(void* const* d_in, const int* in_sizes, int n_in,
                              void* d_out, int out_size, void* d_ws, size_t ws_size,
                              hipStream_t stream) {
    const float* states  = (const float*)d_in[0];
    const float* rtgs    = (const float*)d_in[1];
    const float* meta    = (const float*)d_in[2];
    const float* c1w = (const float*)d_in[4];
    const float* c1b = (const float*)d_in[5];
    const float* c2w = (const float*)d_in[6];
    const float* c2b = (const float*)d_in[7];
    const float* c3w = (const float*)d_in[8];
    const float* c3b = (const float*)d_in[9];
    const float* encw = (const float*)d_in[10];
    const float* encb = (const float*)d_in[11];
    const float* mw1 = (const float*)d_in[12];
    const float* mb1 = (const float*)d_in[13];
    const float* mw2 = (const float*)d_in[14];
    const float* mb2 = (const float*)d_in[15];
    const float* retw = (const float*)d_in[16];
    const float* retb = (const float*)d_in[17];
    const float* aemb = (const float*)d_in[18];
    const float* pos  = (const float*)d_in[19];
    const float* gpos = (const float*)d_in[20];
    const float* ln1g = (const float*)d_in[21];
    const float* ln1b = (const float*)d_in[22];
    const float* ln2g = (const float*)d_in[23];
    const float* ln2b = (const float*)d_in[24];
    const float* Wq = (const float*)d_in[25];
    const float* bq = (const float*)d_in[26];
    const float* Wk = (const float*)d_in[27];
    const float* bk = (const float*)d_in[28];
    const float* Wv = (const float*)d_in[29];
    const float* bv = (const float*)d_in[30];
    const float* Wo = (const float*)d_in[31];
    const float* bo = (const float*)d_in[32];
    const float* Wm1 = (const float*)d_in[33];
    const float* bm1 = (const float*)d_in[34];
    const float* Wm2 = (const float*)d_in[35];
    const float* bm2 = (const float*)d_in[36];
    const float* lnfg = (const float*)d_in[37];
    const float* lnfb = (const float*)d_in[38];
    const float* hw   = (const float*)d_in[39];
    const int* actions   = (const int*)d_in[40];
    const int* timesteps = (const int*)d_in[41];

    float* out = (float*)d_out;

    // ws layout (bytes): X[0,12M) Qh[12,18) Kh[18,24) Vt[24,30) Xb[48,54)
    //                    Yb[54,60) Wb[60,84).  Hb (MLP hidden bf16, 24 MB)
    //                    overlaps Qh/Kh/Vt (dead during MLP phase).
    char* wsc = (char*)d_ws;
    const size_t SLABB = (size_t)MROWS * C_DIM * 4;   // 12 MB
    float* X  = (float*)wsc;
    unsigned short* Qh = (unsigned short*)(wsc + SLABB);
    unsigned short* Kh = Qh + (size_t)MROWS * C_DIM;
    unsigned short* Vt = (unsigned short*)(wsc + 2 * SLABB);
    unsigned short* Hb = (unsigned short*)(wsc + SLABB);
    unsigned short* Xb = (unsigned short*)(wsc + 4 * SLABB);
    unsigned short* Yb = (unsigned short*)(wsc + 4 * SLABB + SLABB / 2);
    unsigned short* Wb = (unsigned short*)(wsc + 5 * SLABB);   // 24 MB

    embed_kernel<<<BATCH * TCTX, 256, 0, stream>>>(
        states, rtgs, meta, c1w, c1b, c2w, c2b, c3w, c3b, encw, encb,
        mw1, mb1, mw2, mb2, retw, retb, aemb, pos, gpos, actions, timesteps, X);

    const dim3 gqk(16, 24);
    const dim3 gvt(24, 8);
    const dim3 g1024(8, 24);
    const dim3 g4096(32, 24);
    const dim3 gattn(12, NHEAD, BATCH);

    for (int i = 0; i < 6; ++i) {
        const size_t wOff = (size_t)i * C_DIM * C_DIM;
        const size_t bOff = (size_t)i * C_DIM;
        const size_t m1Off = (size_t)i * C_DIM * DFF;

        transpose_w_kernel<<<3072, 256, 0, stream>>>(
            Wq + wOff, Wk + wOff, Wv + wOff, Wo + wOff, Wm1 + m1Off, Wm2 + m1Off, Wb);

        ln_bf16_kernel<<<MROWS, 256, 0, stream>>>(X, Xb, ln1g + bOff, ln1b + bOff);
        mfma_gemm_qk<<<gqk, 256, 0, stream>>>(Xb, Wb, bq + bOff, bk + bOff, Qh, Kh);
        mfma_gemm_vt<<<gvt, 256, 0, stream>>>(Wb + (size_t)2 * 1048576, Xb, bv + bOff, Vt);
        attn_mfma<<<gattn, 256, 0, stream>>>(Qh, Kh, Vt, Yb);
        mfma_gemm<0, 0, 1><<<g1024, 256, 0, stream>>>(
            Yb, Wb + (size_t)3 * 1048576, bo + bOff, X, X, nullptr, C_DIM, C_DIM);
        ln_bf16_kernel<<<MROWS, 256, 0, stream>>>(X, Xb, ln2g + bOff, ln2b + bOff);
        mfma_gemm<1, 1, 0><<<g4096, 256, 0, stream>>>(
            Xb, Wb + (size_t)4 * 1048576, bm1 + (size_t)i * DFF, nullptr, nullptr, Hb, DFF, C_DIM);
        mfma_gemm<0, 0, 1><<<g1024, 256, 0, stream>>>(
            Hb, Wb + (size_t)8 * 1048576, bm2 + bOff, X, X, nullptr, C_DIM, DFF);
    }

    ln_bf16_kernel<<<MROWS, 256, 0, stream>>>(X, Xb, lnfg, lnfb);
    head_kernel<<<BATCH * TCTX, 256, 0, stream>>>(Xb, hw, out);
}

// Round 2
// 2547.699 us; speedup vs baseline: 1.3375x; 1.0978x over previous
//
#include <hip/hip_runtime.h>
#include <hip/hip_bf16.h>

// ---------------------------------------------------------------------------
// Decision-Transformer forward, MI355X round 6:
//  - gemm_core rewritten as 2-deep/3-buffer pipeline: global_load_lds
//    width-16 async staging, counted s_waitcnt vmcnt(4) (never 0 mid-loop),
//    one raw s_barrier + sched_barrier(0) per K-step. Converts the
//    latency-bound small-grid GEMMs (192 blocks, ~2800 cy/K-step) into
//    overlap-pipelined (~700 cy/K-step).
//  - LayerNorm wave-per-row (shfl_xor width-64 reduce, no barriers).
//  - Attention MFMA kernel from round 5 unchanged.
// Workspace: 84 MB (X 12 | Qh 6 | Kh 6 | Vt 6 | Xb 6 | Yb 6 | Wb 24).
// ---------------------------------------------------------------------------

#define S_LEN 768
#define C_DIM 1024
#define NHEAD 16
#define HDIM 64
#define BATCH 4
#define TCTX 256
#define DFF 4096
#define NACT 80
#define MROWS (BATCH * S_LEN)   // 3072

typedef __attribute__((ext_vector_type(4))) float f32x4;
typedef __attribute__((ext_vector_type(8))) short bf16x8;
typedef __attribute__((ext_vector_type(8))) _Float16 f16x8;

static __device__ __forceinline__ unsigned short f2bf(float f) {
    unsigned int u = __float_as_uint(f);
    u += 0x7FFF + ((u >> 16) & 1);          // RNE
    return (unsigned short)(u >> 16);
}
static __device__ __forceinline__ float bf2f(unsigned short h) {
    return __uint_as_float(((unsigned int)h) << 16);
}
static __device__ __forceinline__ unsigned short f2h(float f) {
    _Float16 h = (_Float16)f;
    return __builtin_bit_cast(unsigned short, h);
}

// async global -> LDS, 16 bytes per lane. LDS dest must be wave-uniform base
// + lane*16 contiguous (our staging layout is exactly that).
static __device__ __forceinline__ void gload16(void* l, const void* g) {
    __builtin_amdgcn_global_load_lds(
        (__attribute__((address_space(1))) void*)(g),
        (__attribute__((address_space(3))) void*)(l), 16, 0, 0);
}

// ---------------------------------------------------------------------------
// Weight conversion: per layer, f32 [K][N] -> bf16 transposed [N][K] in Wb.
// Wb elem offsets: WqT 0, WkT 1M, WvT 2M, WoT 3M, Wm1T 4M (N=4096,K=1024),
// Wm2T 8M (N=1024,K=4096). 64x64 tiles via LDS, coalesced in and out.
// ---------------------------------------------------------------------------
__global__ __launch_bounds__(256) void transpose_w_kernel(
    const float* __restrict__ Wq, const float* __restrict__ Wk,
    const float* __restrict__ Wv, const float* __restrict__ Wo,
    const float* __restrict__ Wm1, const float* __restrict__ Wm2,
    unsigned short* __restrict__ Wb)
{
    const int t = blockIdx.x;
    const float* src; unsigned short* dst; int K, N, kt, nt;
    if (t < 1024) {
        const int m = t >> 8, tile = t & 255;
        src = (m == 0) ? Wq : (m == 1) ? Wk : (m == 2) ? Wv : Wo;
        dst = Wb + (size_t)m * 1048576;
        K = 1024; N = 1024; kt = tile >> 4; nt = tile & 15;
    } else if (t < 2048) {
        const int tile = t - 1024;
        src = Wm1; dst = Wb + (size_t)4 * 1048576;
        K = 1024; N = 4096; kt = tile >> 6; nt = tile & 63;
    } else {
        const int tile = t - 2048;
        src = Wm2; dst = Wb + (size_t)8 * 1048576;
        K = 4096; N = 1024; kt = tile >> 4; nt = tile & 15;
    }
    const int k0 = kt * 64, n0 = nt * 64;
    __shared__ float Ls[64][65];

    const int r = threadIdx.x >> 2, p = threadIdx.x & 3;
    #pragma unroll
    for (int i = 0; i < 4; ++i)
        *(float4*)&Ls[r][p * 16 + i * 4] =
            *(const float4*)&src[(size_t)(k0 + r) * N + n0 + p * 16 + i * 4];
    __syncthreads();

    unsigned short __align__(16) h[16];
    #pragma unroll
    for (int i = 0; i < 16; ++i) h[i] = f2bf(Ls[p * 16 + i][r]);
    unsigned short* d = dst + (size_t)(n0 + r) * K + k0 + p * 16;
    *(uint4*)d       = *(uint4*)&h[0];
    *(uint4*)(d + 8) = *(uint4*)&h[8];
}

// ---------------------------------------------------------------------------
// Embedding (unchanged): one block per (b,t) -> X f32.
// ---------------------------------------------------------------------------
__global__ __launch_bounds__(256) void embed_kernel(
    const float* __restrict__ states, const float* __restrict__ rtgs,
    const float* __restrict__ meta,
    const float* __restrict__ c1w, const float* __restrict__ c1b,
    const float* __restrict__ c2w, const float* __restrict__ c2b,
    const float* __restrict__ c3w, const float* __restrict__ c3b,
    const float* __restrict__ encw, const float* __restrict__ encb,
    const float* __restrict__ mw1, const float* __restrict__ mb1,
    const float* __restrict__ mw2, const float* __restrict__ mb2,
    const float* __restrict__ retw, const float* __restrict__ retb,
    const float* __restrict__ aemb, const float* __restrict__ pos,
    const float* __restrict__ gpos,
    const int* __restrict__ actions, const int* __restrict__ timesteps,
    float* __restrict__ X)
{
    const int n = blockIdx.x;
    const int b = n >> 8, t = n & 255;
    const int tid = threadIdx.x;

    __shared__ float sin_[640];
    __shared__ float h1[96];
    __shared__ float h2[32];
    __shared__ float feat[16];
    __shared__ float hidm[32];
    __shared__ float mer[4];

    for (int e = tid; e < 640; e += 256)
        sin_[e] = states[(size_t)n * 640 + e];
    __syncthreads();

    if (tid < 96) {
        int o = tid / 6, rem = tid % 6, oh = rem / 3, ow = rem % 3;
        float a = c1b[o];
        for (int ci = 0; ci < 8; ++ci)
            for (int kh = 0; kh < 8; ++kh) {
                int ih = oh * 2 - 1 + kh;
                if (ih < 0 || ih >= 8) continue;
                for (int kw = 0; kw < 8; ++kw) {
                    int iw = ow * 2 - 1 + kw;
                    if (iw < 0 || iw >= 10) continue;
                    a += c1w[((o * 8 + ci) * 8 + kh) * 8 + kw] * sin_[ci * 80 + ih * 10 + iw];
                }
            }
        h1[tid] = fmaxf(a, 0.f);
    }
    if (tid < 32) {
        float a = mb1[tid];
        for (int i = 0; i < 4; ++i)
            a += meta[(size_t)n * 4 + i] * mw1[i * 32 + tid];
        hidm[tid] = fmaxf(a, 0.f);
    }
    __syncthreads();

    if (tid < 32) {
        float a = c2b[tid];
        for (int ci = 0; ci < 16; ++ci)
            for (int kh = 0; kh < 4; ++kh) {
                int ih = -1 + kh;
                if (ih < 0 || ih >= 2) continue;
                for (int kw = 0; kw < 4; ++kw) {
                    int iw = -1 + kw;
                    if (iw < 0 || iw >= 3) continue;
                    a += c2w[((tid * 16 + ci) * 4 + kh) * 4 + kw] * h1[ci * 6 + ih * 3 + iw];
                }
            }
        h2[tid] = fmaxf(a, 0.f);
    }
    __syncthreads();

    if (tid < 16) {
        float a = c3b[tid];
        for (int ci = 0; ci < 32; ++ci)
            a += c3w[(tid * 32 + ci) * 9 + 4] * h2[ci];
        feat[tid] = fmaxf(a, 0.f);
    }
    if (tid < 4) {
        float a = mb2[tid];
        for (int j = 0; j < 32; ++j) a += hidm[j] * mw2[j * 4 + tid];
        mer[tid] = a;
    }
    __syncthreads();

    const float r = rtgs[n];
    const int a_idx = actions[n];
    const int g = timesteps[b];
    const size_t xbase = ((size_t)b * S_LEN + 3 * t) * C_DIM;

    for (int c = tid; c < C_DIM; c += 256) {
        float se;
        if (c < 1020) {
            float acc = encb[c];
            #pragma unroll
            for (int k = 0; k < 16; ++k) acc += feat[k] * encw[k * 1020 + c];
            se = acc;
        } else {
            se = mer[c - 1020];
        }
        const float st = tanhf(se);
        const float rt = tanhf(r * retw[c] + retb[c]);
        const float ae = aemb[(size_t)a_idx * C_DIM + c];
        const float gp = gpos[(size_t)g * C_DIM + c];
        X[xbase + c]             = rt + gp + pos[(size_t)(3 * t + 0) * C_DIM + c];
        X[xbase + C_DIM + c]     = st + gp + pos[(size_t)(3 * t + 1) * C_DIM + c];
        X[xbase + 2 * C_DIM + c] = ae + gp + pos[(size_t)(3 * t + 2) * C_DIM + c];
    }
}

// ---------------------------------------------------------------------------
// LayerNorm over last dim (1024), bf16 output. Wave-per-row: 64-lane
// shfl_xor reduction, no LDS, no barriers. Block = 4 rows.
// ---------------------------------------------------------------------------
__global__ __launch_bounds__(256) void ln_bf16_kernel(
    const float* __restrict__ in, unsigned short* __restrict__ out,
    const float* __restrict__ gw, const float* __restrict__ bw)
{
    const int row = blockIdx.x * 4 + (threadIdx.x >> 6);
    const int lane = threadIdx.x & 63;
    const float* x = in + (size_t)row * C_DIM;

    float4 v[4];
    float s = 0.f;
    #pragma unroll
    for (int j = 0; j < 4; ++j) {
        v[j] = *(const float4*)&x[lane * 4 + j * 256];
        s += (v[j].x + v[j].y) + (v[j].z + v[j].w);
    }
    #pragma unroll
    for (int o = 1; o < 64; o <<= 1) s += __shfl_xor(s, o, 64);
    const float mean = s * (1.0f / 1024.0f);

    float s2 = 0.f;
    #pragma unroll
    for (int j = 0; j < 4; ++j) {
        float dx = v[j].x - mean, dy = v[j].y - mean;
        float dz = v[j].z - mean, dw = v[j].w - mean;
        s2 += (dx * dx + dy * dy) + (dz * dz + dw * dw);
    }
    #pragma unroll
    for (int o = 1; o < 64; o <<= 1) s2 += __shfl_xor(s2, o, 64);
    const float inv = rsqrtf(s2 * (1.0f / 1024.0f) + 1e-5f);

    #pragma unroll
    for (int j = 0; j < 4; ++j) {
        const int c = lane * 4 + j * 256;
        ushort4 o4;
        o4.x = f2bf((v[j].x - mean) * inv * gw[c + 0] + bw[c + 0]);
        o4.y = f2bf((v[j].y - mean) * inv * gw[c + 1] + bw[c + 1]);
        o4.z = f2bf((v[j].z - mean) * inv * gw[c + 2] + bw[c + 2]);
        o4.w = f2bf((v[j].w - mean) * inv * gw[c + 3] + bw[c + 3]);
        *(ushort4*)&out[(size_t)row * C_DIM + c] = o4;
    }
}

// ---------------------------------------------------------------------------
// MFMA GEMM core v2: A bf16 [M][K] row-major; Bt bf16 [N][K] (pre-transposed).
// 128x128 tile, BK=32, 4 waves, 4x4 16x16x32 frags each, f32 accum.
// 2-deep / 3-buffer pipeline: global_load_lds async staging, counted
// vmcnt(4), one s_barrier per K-step (T3+T4).
// Staging map: wave w stages k-chunk [w*8..w*8+8) for rows lane & lane+64 ->
// LDS dest = uniform base + lane*16 (global_load_lds contiguity rule).
// ---------------------------------------------------------------------------
__device__ __forceinline__ void gemm_core(
    const unsigned short* __restrict__ A, const unsigned short* __restrict__ Bt,
    int row0, int col0, int K, f32x4 (&acc)[4][4])
{
    __shared__ __align__(16) unsigned short As[3][4][128][8];
    __shared__ __align__(16) unsigned short Bs[3][4][128][8];

    const int tid = threadIdx.x;
    const int ar  = tid & 63, akg = tid >> 6;     // staging: row, k-group(=wave)
    const int lane = tid & 63, w = tid >> 6;
    const int rwl = (w >> 1) * 64, cwl = (w & 1) * 64;
    const int mi = lane & 15, kg = lane >> 4;

    const unsigned short* pa = A + (size_t)(row0 + ar) * K + akg * 8;
    const unsigned short* pb = Bt + (size_t)(col0 + ar) * K + akg * 8;
    const size_t rstep = (size_t)64 * K;
    const int nk = K >> 5;

    // prologue: stage k=0 (buf0) and k=1 (buf1); 8 loads in flight per wave
    gload16(&As[0][akg][ar][0],      pa);
    gload16(&As[0][akg][ar + 64][0], pa + rstep);
    gload16(&Bs[0][akg][ar][0],      pb);
    gload16(&Bs[0][akg][ar + 64][0], pb + rstep);
    gload16(&As[1][akg][ar][0],      pa + 32);
    gload16(&As[1][akg][ar + 64][0], pa + rstep + 32);
    gload16(&Bs[1][akg][ar][0],      pb + 32);
    gload16(&Bs[1][akg][ar + 64][0], pb + rstep + 32);

    int bsel = 0;
    for (int k = 0; k < nk; ++k) {
        // wait own stage-k loads (leave stage k+1 in flight), then publish
        if (k + 1 < nk) asm volatile("s_waitcnt vmcnt(4)" ::: "memory");
        else            asm volatile("s_waitcnt vmcnt(0)" ::: "memory");
        __builtin_amdgcn_s_barrier();
        __builtin_amdgcn_sched_barrier(0);   // nothing crosses the barrier

        if (k + 2 < nk) {                    // issue stage k+2 (async)
            const int b2 = (bsel >= 1) ? bsel - 1 : 2;   // (bsel+2)%3
            const unsigned short* ga = pa + (size_t)(k + 2) * 32;
            const unsigned short* gb = pb + (size_t)(k + 2) * 32;
            gload16(&As[b2][akg][ar][0],      ga);
            gload16(&As[b2][akg][ar + 64][0], ga + rstep);
            gload16(&Bs[b2][akg][ar][0],      gb);
            gload16(&Bs[b2][akg][ar + 64][0], gb + rstep);
        }

        const unsigned short (*Ac)[128][8] = As[bsel];
        const unsigned short (*Bc)[128][8] = Bs[bsel];
        bf16x8 af[4], bfr[4];
        #pragma unroll
        for (int i = 0; i < 4; ++i) {
            af[i]  = *(const bf16x8*)&Ac[kg][rwl + i * 16 + mi][0];
            bfr[i] = *(const bf16x8*)&Bc[kg][cwl + i * 16 + mi][0];
        }
        #pragma unroll
        for (int ri = 0; ri < 4; ++ri)
            #pragma unroll
            for (int ci = 0; ci < 4; ++ci)
                acc[ri][ci] = __builtin_amdgcn_mfma_f32_16x16x32_bf16(
                    af[ri], bfr[ci], acc[ri][ci], 0, 0, 0);

        bsel = (bsel < 2) ? bsel + 1 : 0;
    }
}

// Epilogue variants. ACT: 1=gelu. OUTB: 1=bf16 out. RES: add resid.
template<int ACT, int OUTB, int RES>
__global__ __launch_bounds__(256) void mfma_gemm(
    const unsigned short* __restrict__ A, const unsigned short* __restrict__ Bt,
    const float* __restrict__ bias, const float* resid,
    float* outf, unsigned short* __restrict__ outb,
    int N, int K)
{
    const int row0 = blockIdx.y * 128, col0 = blockIdx.x * 128;
    f32x4 acc[4][4] = {};
    gemm_core(A, Bt, row0, col0, K, acc);

    const int lane = threadIdx.x & 63, w = threadIdx.x >> 6;
    const int rwl = (w >> 1) * 64, cwl = (w & 1) * 64;
    const int mi = lane & 15, kg = lane >> 4;

    #pragma unroll
    for (int ri = 0; ri < 4; ++ri) {
        #pragma unroll
        for (int ci = 0; ci < 4; ++ci) {
            #pragma unroll
            for (int j = 0; j < 4; ++j) {
                const int row = row0 + rwl + ri * 16 + kg * 4 + j;
                const int col = col0 + cwl + ci * 16 + mi;
                float v = acc[ri][ci][j] + bias[col];
                if (ACT) v = 0.5f * v * (1.0f + erff(v * 0.70710678118f));
                if (RES) v += resid[(size_t)row * N + col];
                if (OUTB) outb[(size_t)row * N + col] = f2bf(v);
                else      outf[(size_t)row * N + col] = v;
            }
        }
    }
}

// Q/K fused: blockIdx.x = grp(2)*8 + coltile; fp16 out, Q pre-scaled by 1/8.
__global__ __launch_bounds__(256) void mfma_gemm_qk(
    const unsigned short* __restrict__ A, const unsigned short* __restrict__ Wb,
    const float* __restrict__ bq, const float* __restrict__ bk,
    unsigned short* __restrict__ Qh, unsigned short* __restrict__ Kh)
{
    const int grp = blockIdx.x >> 3;
    const unsigned short* Bt = Wb + (size_t)grp * 1048576;
    const float* bias = grp == 0 ? bq : bk;
    unsigned short* out = grp == 0 ? Qh : Kh;
    const float scale = grp == 0 ? 0.125f : 1.0f;
    const int row0 = blockIdx.y * 128, col0 = (blockIdx.x & 7) * 128;

    f32x4 acc[4][4] = {};
    gemm_core(A, Bt, row0, col0, C_DIM, acc);

    const int lane = threadIdx.x & 63, w = threadIdx.x >> 6;
    const int rwl = (w >> 1) * 64, cwl = (w & 1) * 64;
    const int mi = lane & 15, kg = lane >> 4;

    #pragma unroll
    for (int ri = 0; ri < 4; ++ri)
        #pragma unroll
        for (int ci = 0; ci < 4; ++ci)
            #pragma unroll
            for (int j = 0; j < 4; ++j) {
                const int row = row0 + rwl + ri * 16 + kg * 4 + j;
                const int col = col0 + cwl + ci * 16 + mi;
                out[(size_t)row * C_DIM + col] = f2h((acc[ri][ci][j] + bias[col]) * scale);
            }
}

// V TRANSPOSED by operand swap: V^T[cout][token] = WvT @ X^T
//   = gemm_core(A = WvT [1024][1024], Bt = Xb [3072][1024]).  Bias per ROW.
__global__ __launch_bounds__(256) void mfma_gemm_vt(
    const unsigned short* __restrict__ WvT, const unsigned short* __restrict__ Xb,
    const float* __restrict__ bv, unsigned short* __restrict__ Vt)
{
    const int row0 = blockIdx.y * 128, col0 = blockIdx.x * 128;
    f32x4 acc[4][4] = {};
    gemm_core(WvT, Xb, row0, col0, C_DIM, acc);

    const int lane = threadIdx.x & 63, w = threadIdx.x >> 6;
    const int rwl = (w >> 1) * 64, cwl = (w & 1) * 64;
    const int mi = lane & 15, kg = lane >> 4;

    #pragma unroll
    for (int ri = 0; ri < 4; ++ri)
        #pragma unroll
        for (int ci = 0; ci < 4; ++ci)
            #pragma unroll
            for (int j = 0; j < 4; ++j) {
                const int row = row0 + rwl + ri * 16 + kg * 4 + j;   // cout
                const int col = col0 + cwl + ci * 16 + mi;           // token
                Vt[(size_t)row * MROWS + col] = f2h(acc[ri][ci][j] + bv[row]);
            }
}

// ---------------------------------------------------------------------------
// MFMA flash attention (round-5, unchanged): block per (qtile=64, h, b),
// 4 waves x 16 q-rows, XOR-chunk-swizzled LDS, online softmax in registers,
// reg-prefetch of next K/V tile.
// ---------------------------------------------------------------------------
__global__ __launch_bounds__(256) void attn_mfma(
    const unsigned short* __restrict__ Qh, const unsigned short* __restrict__ Kh,
    const unsigned short* __restrict__ Vt, unsigned short* __restrict__ Yb)
{
    const int qt = blockIdx.x, h = blockIdx.y, b = blockIdx.z;
    const int tid = threadIdx.x;
    const int lane = tid & 63, w = tid >> 6;
    const int mi = lane & 15, kg = lane >> 4;
    const int q0 = qt * 64;

    __shared__ __align__(16) char ldsraw[24576];
    unsigned short* Ks = (unsigned short*)ldsraw;            // [64 key][64 c]
    unsigned short* Vs = (unsigned short*)(ldsraw + 8192);   // [64 d][64 key]
    unsigned short* Ps = (unsigned short*)(ldsraw + 16384);  // [64 q][64 key]
    float* Ob = (float*)ldsraw;                              // [64][68] after loop

    const size_t qkbase = (size_t)b * S_LEN * C_DIM + (size_t)h * HDIM;
    const unsigned short* Kbase = Kh + qkbase;
    const unsigned short* Vbase = Vt + (size_t)h * HDIM * MROWS + (size_t)b * S_LEN;

    // Q A-fragments: lane holds Q[q0+w*16+mi][kg*8..+8 (+32)]
    f16x8 QA0, QA1;
    {
        const unsigned short* qp = Qh + qkbase + (size_t)(q0 + w * 16 + mi) * C_DIM + kg * 8;
        QA0 = *(const f16x8*)qp;
        QA1 = *(const f16x8*)(qp + 32);
    }

    // staging: thread covers tile rows {srow, srow+32}, 16B chunk sc16
    const int srow = tid >> 3, sc16 = tid & 7;
    const int dch = (sc16 ^ (srow & 7)) << 3;   // swizzled half-offset in row

    float mrow[4], lrow[4], alj[4];
    f32x4 Oacc[4];
    #pragma unroll
    for (int j = 0; j < 4; ++j) { mrow[j] = -1e30f; lrow[j] = 0.f; }
    #pragma unroll
    for (int df = 0; df < 4; ++df) Oacc[df] = (f32x4){0.f, 0.f, 0.f, 0.f};

    // preload tile 0
    uint4 rk0, rk1, rv0, rv1;
    {
        const unsigned short* kp = Kbase + (size_t)srow * C_DIM + sc16 * 8;
        rk0 = *(const uint4*)kp;
        rk1 = *(const uint4*)(kp + (size_t)32 * C_DIM);
        const unsigned short* vp = Vbase + (size_t)srow * MROWS + sc16 * 8;
        rv0 = *(const uint4*)vp;
        rv1 = *(const uint4*)(vp + (size_t)32 * MROWS);
    }

    for (int kt = 0; kt <= qt; ++kt) {
        __syncthreads();   // prev tile's readers done
        *(uint4*)&Ks[srow * 64 + dch]        = rk0;
        *(uint4*)&Ks[(srow + 32) * 64 + dch] = rk1;
        *(uint4*)&Vs[srow * 64 + dch]        = rv0;
        *(uint4*)&Vs[(srow + 32) * 64 + dch] = rv1;
        if (kt < qt) {   // prefetch next tile (latency hides under compute)
            const unsigned short* kp = Kbase + (size_t)((kt + 1) * 64 + srow) * C_DIM + sc16 * 8;
            rk0 = *(const uint4*)kp;
            rk1 = *(const uint4*)(kp + (size_t)32 * C_DIM);
            const unsigned short* vp = Vbase + (size_t)srow * MROWS + (kt + 1) * 64 + sc16 * 8;
            rv0 = *(const uint4*)vp;
            rv1 = *(const uint4*)(vp + (size_t)32 * MROWS);
        }
        __syncthreads();   // stage visible

        // ---- scores S = Q @ K^T (16q x 64k per wave)
        f32x4 sa[4];
        #pragma unroll
        for (int kf = 0; kf < 4; ++kf) {
            const int key = kf * 16 + mi;
            const unsigned short* kr = Ks + key * 64;
            const f16x8 kb0 = *(const f16x8*)(kr + ((kg ^ (key & 7)) << 3));
            const f16x8 kb1 = *(const f16x8*)(kr + (((4 + kg) ^ (key & 7)) << 3));
            f32x4 z = {0.f, 0.f, 0.f, 0.f};
            z = __builtin_amdgcn_mfma_f32_16x16x32_f16(QA0, kb0, z, 0, 0, 0);
            sa[kf] = __builtin_amdgcn_mfma_f32_16x16x32_f16(QA1, kb1, z, 0, 0, 0);
        }

        if (kt == qt) {   // causal mask within diagonal tile
            #pragma unroll
            for (int kf = 0; kf < 4; ++kf)
                #pragma unroll
                for (int j = 0; j < 4; ++j)
                    if (kf * 16 + mi > w * 16 + kg * 4 + j) sa[kf][j] = -1e30f;
        }

        // ---- online softmax: row j lives in (kg,reg); reduce over mi lanes
        #pragma unroll
        for (int j = 0; j < 4; ++j) {
            float rm = fmaxf(fmaxf(sa[0][j], sa[1][j]), fmaxf(sa[2][j], sa[3][j]));
            rm = fmaxf(rm, __shfl_xor(rm, 1, 16));
            rm = fmaxf(rm, __shfl_xor(rm, 2, 16));
            rm = fmaxf(rm, __shfl_xor(rm, 4, 16));
            rm = fmaxf(rm, __shfl_xor(rm, 8, 16));
            const float mn = fmaxf(mrow[j], rm);
            alj[j] = __expf(mrow[j] - mn);
            mrow[j] = mn;
            const float p0 = __expf(sa[0][j] - mn);
            const float p1 = __expf(sa[1][j] - mn);
            const float p2 = __expf(sa[2][j] - mn);
            const float p3 = __expf(sa[3][j] - mn);
            const int prow = w * 16 + kg * 4 + j;
            unsigned short* pr = Ps + prow * 64;
            const int sw = prow & 7, hi = mi >> 3, lo = mi & 7;
            pr[(((0 + hi) ^ sw) << 3) + lo] = f2h(p0);
            pr[(((2 + hi) ^ sw) << 3) + lo] = f2h(p1);
            pr[(((4 + hi) ^ sw) << 3) + lo] = f2h(p2);
            pr[(((6 + hi) ^ sw) << 3) + lo] = f2h(p3);
            float rs = p0 + p1 + p2 + p3;
            rs += __shfl_xor(rs, 1, 16);
            rs += __shfl_xor(rs, 2, 16);
            rs += __shfl_xor(rs, 4, 16);
            rs += __shfl_xor(rs, 8, 16);
            lrow[j] = lrow[j] * alj[j] + rs;
        }
        // no barrier needed: P written & read by the SAME wave's strip only

        // ---- O = O*alpha + P @ V (16q x 64d per wave)
        const unsigned short* pp = Ps + (w * 16 + mi) * 64;
        const int psw = mi & 7;
        const f16x8 PA0 = *(const f16x8*)(pp + ((kg ^ psw) << 3));
        const f16x8 PA1 = *(const f16x8*)(pp + (((4 + kg) ^ psw) << 3));
        #pragma unroll
        for (int df = 0; df < 4; ++df) {
            const int d = df * 16 + mi;
            const unsigned short* vr = Vs + d * 64;
            const f16x8 vb0 = *(const f16x8*)(vr + ((kg ^ (d & 7)) << 3));
            const f16x8 vb1 = *(const f16x8*)(vr + (((4 + kg) ^ (d & 7)) << 3));
            f32x4 o = Oacc[df];
            o[0] *= alj[0]; o[1] *= alj[1]; o[2] *= alj[2]; o[3] *= alj[3];
            o = __builtin_amdgcn_mfma_f32_16x16x32_f16(PA0, vb0, o, 0, 0, 0);
            Oacc[df] = __builtin_amdgcn_mfma_f32_16x16x32_f16(PA1, vb1, o, 0, 0, 0);
        }
    }

    // ---- normalize, bounce through LDS (Ob aliases Ks/Vs/Ps), coalesced store
    __syncthreads();
    float inv[4];
    #pragma unroll
    for (int j = 0; j < 4; ++j) inv[j] = 1.0f / lrow[j];
    #pragma unroll
    for (int df = 0; df < 4; ++df)
        #pragma unroll
        for (int j = 0; j < 4; ++j)
            Ob[(w * 16 + kg * 4 + j) * 68 + df * 16 + mi] = Oacc[df][j] * inv[j];
    __syncthreads();

    const int orow = tid >> 2, oc0 = (tid & 3) * 16;
    unsigned short __align__(16) hx[16];
    #pragma unroll
    for (int i = 0; i < 16; ++i) hx[i] = f2bf(Ob[orow * 68 + oc0 + i]);
    unsigned short* yp = Yb + qkbase + (size_t)(q0 + orow) * C_DIM + oc0;
    *(uint4*)yp       = *(uint4*)&hx[0];
    *(uint4*)(yp + 8) = *(uint4*)&hx[8];
}

// ---------------------------------------------------------------------------
// Head: block per (b,t); bf16 final-LN row @ s=3t+1 times head_w -> f32 out.
// ---------------------------------------------------------------------------
__global__ __launch_bounds__(256) void head_kernel(
    const unsigned short* __restrict__ Xb, const float* __restrict__ hw,
    float* __restrict__ out)
{
    const int n = blockIdx.x;
    const int b = n >> 8, t = n & 255;
    const int tid = threadIdx.x;
    __shared__ float rowv[C_DIM];

    const unsigned short* x = Xb + ((size_t)b * S_LEN + 3 * t + 1) * C_DIM;
    #pragma unroll
    for (int j = 0; j < 4; ++j) rowv[tid + j * 256] = bf2f(x[tid + j * 256]);
    __syncthreads();

    if (tid < NACT) {
        float a = 0.f;
        for (int k = 0; k < C_DIM; ++k) a += rowv[k] * hw[k * NACT + tid];
        out[(size_t)n * NACT + tid] = a;
    }
}

// ---------------------------------------------------------------------------
extern "C" void kernel_launch(void* const* d_in, const int* in_sizes, int n_in,
                              void* d_out, int out_size, void* d_ws, size_t ws_size,
                              hipStream_t stream) {
    const float* states  = (const float*)d_in[0];
    const float* rtgs    = (const float*)d_in[1];
    const float* meta    = (const float*)d_in[2];
    const float* c1w = (const float*)d_in[4];
    const float* c1b = (const float*)d_in[5];
    const float* c2w = (const float*)d_in[6];
    const float* c2b = (const float*)d_in[7];
    const float* c3w = (const float*)d_in[8];
    const float* c3b = (const float*)d_in[9];
    const float* encw = (const float*)d_in[10];
    const float* encb = (const float*)d_in[11];
    const float* mw1 = (const float*)d_in[12];
    const float* mb1 = (const float*)d_in[13];
    const float* mw2 = (const float*)d_in[14];
    const float* mb2 = (const float*)d_in[15];
    const float* retw = (const float*)d_in[16];
    const float* retb = (const float*)d_in[17];
    const float* aemb = (const float*)d_in[18];
    const float* pos  = (const float*)d_in[19];
    const float* gpos = (const float*)d_in[20];
    const float* ln1g = (const float*)d_in[21];
    const float* ln1b = (const float*)d_in[22];
    const float* ln2g = (const float*)d_in[23];
    const float* ln2b = (const float*)d_in[24];
    const float* Wq = (const float*)d_in[25];
    const float* bq = (const float*)d_in[26];
    const float* Wk = (const float*)d_in[27];
    const float* bk = (const float*)d_in[28];
    const float* Wv = (const float*)d_in[29];
    const float* bv = (const float*)d_in[30];
    const float* Wo = (const float*)d_in[31];
    const float* bo = (const float*)d_in[32];
    const float* Wm1 = (const float*)d_in[33];
    const float* bm1 = (const float*)d_in[34];
    const float* Wm2 = (const float*)d_in[35];
    const float* bm2 = (const float*)d_in[36];
    const float* lnfg = (const float*)d_in[37];
    const float* lnfb = (const float*)d_in[38];
    const float* hw   = (const float*)d_in[39];
    const int* actions   = (const int*)d_in[40];
    const int* timesteps = (const int*)d_in[41];

    float* out = (float*)d_out;

    // ws layout (bytes): X[0,12M) Qh[12,18) Kh[18,24) Vt[24,30) Xb[48,54)
    //                    Yb[54,60) Wb[60,84).  Hb (MLP hidden bf16, 24 MB)
    //                    overlaps Qh/Kh/Vt (dead during MLP phase).
    char* wsc = (char*)d_ws;
    const size_t SLABB = (size_t)MROWS * C_DIM * 4;   // 12 MB
    float* X  = (float*)wsc;
    unsigned short* Qh = (unsigned short*)(wsc + SLABB);
    unsigned short* Kh = Qh + (size_t)MROWS * C_DIM;
    unsigned short* Vt = (unsigned short*)(wsc + 2 * SLABB);
    unsigned short* Hb = (unsigned short*)(wsc + SLABB);
    unsigned short* Xb = (unsigned short*)(wsc + 4 * SLABB);
    unsigned short* Yb = (unsigned short*)(wsc + 4 * SLABB + SLABB / 2);
    unsigned short* Wb = (unsigned short*)(wsc + 5 * SLABB);   // 24 MB

    embed_kernel<<<BATCH * TCTX, 256, 0, stream>>>(
        states, rtgs, meta, c1w, c1b, c2w, c2b, c3w, c3b, encw, encb,
        mw1, mb1, mw2, mb2, retw, retb, aemb, pos, gpos, actions, timesteps, X);

    const dim3 gqk(16, 24);
    const dim3 gvt(24, 8);
    const dim3 g1024(8, 24);
    const dim3 g4096(32, 24);
    const dim3 gattn(12, NHEAD, BATCH);

    for (int i = 0; i < 6; ++i) {
        const size_t wOff = (size_t)i * C_DIM * C_DIM;
        const size_t bOff = (size_t)i * C_DIM;
        const size_t m1Off = (size_t)i * C_DIM * DFF;

        transpose_w_kernel<<<3072, 256, 0, stream>>>(
            Wq + wOff, Wk + wOff, Wv + wOff, Wo + wOff, Wm1 + m1Off, Wm2 + m1Off, Wb);

        ln_bf16_kernel<<<MROWS / 4, 256, 0, stream>>>(X, Xb, ln1g + bOff, ln1b + bOff);
        mfma_gemm_qk<<<gqk, 256, 0, stream>>>(Xb, Wb, bq + bOff, bk + bOff, Qh, Kh);
        mfma_gemm_vt<<<gvt, 256, 0, stream>>>(Wb + (size_t)2 * 1048576, Xb, bv + bOff, Vt);
        attn_mfma<<<gattn, 256, 0, stream>>>(Qh, Kh, Vt, Yb);
        mfma_gemm<0, 0, 1><<<g1024, 256, 0, stream>>>(
            Yb, Wb + (size_t)3 * 1048576, bo + bOff, X, X, nullptr, C_DIM, C_DIM);
        ln_bf16_kernel<<<MROWS / 4, 256, 0, stream>>>(X, Xb, ln2g + bOff, ln2b + bOff);
        mfma_gemm<1, 1, 0><<<g4096, 256, 0, stream>>>(
            Xb, Wb + (size_t)4 * 1048576, bm1 + (size_t)i * DFF, nullptr, nullptr, Hb, DFF, C_DIM);
        mfma_gemm<0, 0, 1><<<g1024, 256, 0, stream>>>(
            Hb, Wb + (size_t)8 * 1048576, bm2 + bOff, X, X, nullptr, C_DIM, DFF);
    }

    ln_bf16_kernel<<<MROWS / 4, 256, 0, stream>>>(X, Xb, lnfg, lnfb);
    head_kernel<<<BATCH * TCTX, 256, 0, stream>>>(Xb, hw, out);
}

// Round 3
// 2458.697 us; speedup vs baseline: 1.3859x; 1.0362x over previous
//
#include <hip/hip_runtime.h>
#include <hip/hip_bf16.h>

// ---------------------------------------------------------------------------
// Decision-Transformer forward, MI355X round 7:
//  - gemm_core pipeline FIXED: K-loop unrolled x3 with LITERAL LDS buffer
//    indices (alias analysis can now disambiguate ds_read[buf] from
//    in-flight global_load_lds[buf+2] -> no compiler-inserted vmcnt(0) drain;
//    counted vmcnt(4) holds 2 stages in flight). s_setprio around MFMA.
//  - o-proj & MLP-down (192-block, 1-block/CU latency-bound GEMMs) are now
//    split-K=4 with atomicAdd accumulation DIRECTLY onto the residual
//    stream X (X already holds the residual; bias added by split 0). Grid
//    768 blocks = 3 blocks/CU = 12 waves/CU.
// Workspace: 84 MB (X 12 | Qh 6 | Kh 6 | Vt 6 | Xb 6 | Yb 6 | Wb 24).
// ---------------------------------------------------------------------------

#define S_LEN 768
#define C_DIM 1024
#define NHEAD 16
#define HDIM 64
#define BATCH 4
#define TCTX 256
#define DFF 4096
#define NACT 80
#define MROWS (BATCH * S_LEN)   // 3072

typedef __attribute__((ext_vector_type(4))) float f32x4;
typedef __attribute__((ext_vector_type(8))) short bf16x8;
typedef __attribute__((ext_vector_type(8))) _Float16 f16x8;

static __device__ __forceinline__ unsigned short f2bf(float f) {
    unsigned int u = __float_as_uint(f);
    u += 0x7FFF + ((u >> 16) & 1);          // RNE
    return (unsigned short)(u >> 16);
}
static __device__ __forceinline__ float bf2f(unsigned short h) {
    return __uint_as_float(((unsigned int)h) << 16);
}
static __device__ __forceinline__ unsigned short f2h(float f) {
    _Float16 h = (_Float16)f;
    return __builtin_bit_cast(unsigned short, h);
}

// async global -> LDS, 16 bytes per lane. LDS dest must be wave-uniform base
// + lane*16 contiguous (our staging layout is exactly that).
static __device__ __forceinline__ void gload16(void* l, const void* g) {
    __builtin_amdgcn_global_load_lds(
        (__attribute__((address_space(1))) void*)(g),
        (__attribute__((address_space(3))) void*)(l), 16, 0, 0);
}

// ---------------------------------------------------------------------------
// Weight conversion: per layer, f32 [K][N] -> bf16 transposed [N][K] in Wb.
// Wb elem offsets: WqT 0, WkT 1M, WvT 2M, WoT 3M, Wm1T 4M (N=4096,K=1024),
// Wm2T 8M (N=1024,K=4096). 64x64 tiles via LDS, coalesced in and out.
// ---------------------------------------------------------------------------
__global__ __launch_bounds__(256) void transpose_w_kernel(
    const float* __restrict__ Wq, const float* __restrict__ Wk,
    const float* __restrict__ Wv, const float* __restrict__ Wo,
    const float* __restrict__ Wm1, const float* __restrict__ Wm2,
    unsigned short* __restrict__ Wb)
{
    const int t = blockIdx.x;
    const float* src; unsigned short* dst; int K, N, kt, nt;
    if (t < 1024) {
        const int m = t >> 8, tile = t & 255;
        src = (m == 0) ? Wq : (m == 1) ? Wk : (m == 2) ? Wv : Wo;
        dst = Wb + (size_t)m * 1048576;
        K = 1024; N = 1024; kt = tile >> 4; nt = tile & 15;
    } else if (t < 2048) {
        const int tile = t - 1024;
        src = Wm1; dst = Wb + (size_t)4 * 1048576;
        K = 1024; N = 4096; kt = tile >> 6; nt = tile & 63;
    } else {
        const int tile = t - 2048;
        src = Wm2; dst = Wb + (size_t)8 * 1048576;
        K = 4096; N = 1024; kt = tile >> 4; nt = tile & 15;
    }
    const int k0 = kt * 64, n0 = nt * 64;
    __shared__ float Ls[64][65];

    const int r = threadIdx.x >> 2, p = threadIdx.x & 3;
    #pragma unroll
    for (int i = 0; i < 4; ++i)
        *(float4*)&Ls[r][p * 16 + i * 4] =
            *(const float4*)&src[(size_t)(k0 + r) * N + n0 + p * 16 + i * 4];
    __syncthreads();

    unsigned short __align__(16) h[16];
    #pragma unroll
    for (int i = 0; i < 16; ++i) h[i] = f2bf(Ls[p * 16 + i][r]);
    unsigned short* d = dst + (size_t)(n0 + r) * K + k0 + p * 16;
    *(uint4*)d       = *(uint4*)&h[0];
    *(uint4*)(d + 8) = *(uint4*)&h[8];
}

// ---------------------------------------------------------------------------
// Embedding (unchanged): one block per (b,t) -> X f32.
// ---------------------------------------------------------------------------
__global__ __launch_bounds__(256) void embed_kernel(
    const float* __restrict__ states, const float* __restrict__ rtgs,
    const float* __restrict__ meta,
    const float* __restrict__ c1w, const float* __restrict__ c1b,
    const float* __restrict__ c2w, const float* __restrict__ c2b,
    const float* __restrict__ c3w, const float* __restrict__ c3b,
    const float* __restrict__ encw, const float* __restrict__ encb,
    const float* __restrict__ mw1, const float* __restrict__ mb1,
    const float* __restrict__ mw2, const float* __restrict__ mb2,
    const float* __restrict__ retw, const float* __restrict__ retb,
    const float* __restrict__ aemb, const float* __restrict__ pos,
    const float* __restrict__ gpos,
    const int* __restrict__ actions, const int* __restrict__ timesteps,
    float* __restrict__ X)
{
    const int n = blockIdx.x;
    const int b = n >> 8, t = n & 255;
    const int tid = threadIdx.x;

    __shared__ float sin_[640];
    __shared__ float h1[96];
    __shared__ float h2[32];
    __shared__ float feat[16];
    __shared__ float hidm[32];
    __shared__ float mer[4];

    for (int e = tid; e < 640; e += 256)
        sin_[e] = states[(size_t)n * 640 + e];
    __syncthreads();

    if (tid < 96) {
        int o = tid / 6, rem = tid % 6, oh = rem / 3, ow = rem % 3;
        float a = c1b[o];
        for (int ci = 0; ci < 8; ++ci)
            for (int kh = 0; kh < 8; ++kh) {
                int ih = oh * 2 - 1 + kh;
                if (ih < 0 || ih >= 8) continue;
                for (int kw = 0; kw < 8; ++kw) {
                    int iw = ow * 2 - 1 + kw;
                    if (iw < 0 || iw >= 10) continue;
                    a += c1w[((o * 8 + ci) * 8 + kh) * 8 + kw] * sin_[ci * 80 + ih * 10 + iw];
                }
            }
        h1[tid] = fmaxf(a, 0.f);
    }
    if (tid < 32) {
        float a = mb1[tid];
        for (int i = 0; i < 4; ++i)
            a += meta[(size_t)n * 4 + i] * mw1[i * 32 + tid];
        hidm[tid] = fmaxf(a, 0.f);
    }
    __syncthreads();

    if (tid < 32) {
        float a = c2b[tid];
        for (int ci = 0; ci < 16; ++ci)
            for (int kh = 0; kh < 4; ++kh) {
                int ih = -1 + kh;
                if (ih < 0 || ih >= 2) continue;
                for (int kw = 0; kw < 4; ++kw) {
                    int iw = -1 + kw;
                    if (iw < 0 || iw >= 3) continue;
                    a += c2w[((tid * 16 + ci) * 4 + kh) * 4 + kw] * h1[ci * 6 + ih * 3 + iw];
                }
            }
        h2[tid] = fmaxf(a, 0.f);
    }
    __syncthreads();

    if (tid < 16) {
        float a = c3b[tid];
        for (int ci = 0; ci < 32; ++ci)
            a += c3w[(tid * 32 + ci) * 9 + 4] * h2[ci];
        feat[tid] = fmaxf(a, 0.f);
    }
    if (tid < 4) {
        float a = mb2[tid];
        for (int j = 0; j < 32; ++j) a += hidm[j] * mw2[j * 4 + tid];
        mer[tid] = a;
    }
    __syncthreads();

    const float r = rtgs[n];
    const int a_idx = actions[n];
    const int g = timesteps[b];
    const size_t xbase = ((size_t)b * S_LEN + 3 * t) * C_DIM;

    for (int c = tid; c < C_DIM; c += 256) {
        float se;
        if (c < 1020) {
            float acc = encb[c];
            #pragma unroll
            for (int k = 0; k < 16; ++k) acc += feat[k] * encw[k * 1020 + c];
            se = acc;
        } else {
            se = mer[c - 1020];
        }
        const float st = tanhf(se);
        const float rt = tanhf(r * retw[c] + retb[c]);
        const float ae = aemb[(size_t)a_idx * C_DIM + c];
        const float gp = gpos[(size_t)g * C_DIM + c];
        X[xbase + c]             = rt + gp + pos[(size_t)(3 * t + 0) * C_DIM + c];
        X[xbase + C_DIM + c]     = st + gp + pos[(size_t)(3 * t + 1) * C_DIM + c];
        X[xbase + 2 * C_DIM + c] = ae + gp + pos[(size_t)(3 * t + 2) * C_DIM + c];
    }
}

// ---------------------------------------------------------------------------
// LayerNorm over last dim (1024), bf16 output. Wave-per-row: 64-lane
// shfl_xor reduction, no LDS, no barriers. Block = 4 rows.
// ---------------------------------------------------------------------------
__global__ __launch_bounds__(256) void ln_bf16_kernel(
    const float* __restrict__ in, unsigned short* __restrict__ out,
    const float* __restrict__ gw, const float* __restrict__ bw)
{
    const int row = blockIdx.x * 4 + (threadIdx.x >> 6);
    const int lane = threadIdx.x & 63;
    const float* x = in + (size_t)row * C_DIM;

    float4 v[4];
    float s = 0.f;
    #pragma unroll
    for (int j = 0; j < 4; ++j) {
        v[j] = *(const float4*)&x[lane * 4 + j * 256];
        s += (v[j].x + v[j].y) + (v[j].z + v[j].w);
    }
    #pragma unroll
    for (int o = 1; o < 64; o <<= 1) s += __shfl_xor(s, o, 64);
    const float mean = s * (1.0f / 1024.0f);

    float s2 = 0.f;
    #pragma unroll
    for (int j = 0; j < 4; ++j) {
        float dx = v[j].x - mean, dy = v[j].y - mean;
        float dz = v[j].z - mean, dw = v[j].w - mean;
        s2 += (dx * dx + dy * dy) + (dz * dz + dw * dw);
    }
    #pragma unroll
    for (int o = 1; o < 64; o <<= 1) s2 += __shfl_xor(s2, o, 64);
    const float inv = rsqrtf(s2 * (1.0f / 1024.0f) + 1e-5f);

    #pragma unroll
    for (int j = 0; j < 4; ++j) {
        const int c = lane * 4 + j * 256;
        ushort4 o4;
        o4.x = f2bf((v[j].x - mean) * inv * gw[c + 0] + bw[c + 0]);
        o4.y = f2bf((v[j].y - mean) * inv * gw[c + 1] + bw[c + 1]);
        o4.z = f2bf((v[j].z - mean) * inv * gw[c + 2] + bw[c + 2]);
        o4.w = f2bf((v[j].w - mean) * inv * gw[c + 3] + bw[c + 3]);
        *(ushort4*)&out[(size_t)row * C_DIM + c] = o4;
    }
}

// ---------------------------------------------------------------------------
// MFMA GEMM core v3: A bf16 [M][ldk] row-major; Bt bf16 [N][ldk].
// 128x128 tile, BK=32, 4 waves, 4x4 16x16x32 frags each, f32 accum.
// 2-deep / 3-buffer pipeline, K-loop UNROLLED x3 with literal buffer
// indices (alias-analysis-friendly -> counted vmcnt survives).
// Requires nk % 3 == 2 (true for all callers: nk in {8, 32}).
// ---------------------------------------------------------------------------
__device__ __forceinline__ void gemm_core(
    const unsigned short* __restrict__ A, const unsigned short* __restrict__ Bt,
    int row0, int col0, int ldk, int nk, f32x4 (&acc)[4][4])
{
    __shared__ __align__(16) unsigned short As[3][4][128][8];
    __shared__ __align__(16) unsigned short Bs[3][4][128][8];

    const int tid = threadIdx.x;
    const int ar  = tid & 63, akg = tid >> 6;     // staging: row, k-group(=wave)
    const int lane = tid & 63, w = tid >> 6;
    const int rwl = (w >> 1) * 64, cwl = (w & 1) * 64;
    const int mi = lane & 15, kg = lane >> 4;

    const unsigned short* pa = A + (size_t)(row0 + ar) * ldk + akg * 8;
    const unsigned short* pb = Bt + (size_t)(col0 + ar) * ldk + akg * 8;
    const size_t rstep = (size_t)64 * ldk;

    // prologue: stage k=0 -> buf0, k=1 -> buf1 (8 loads in flight per wave)
    gload16(&As[0][akg][ar][0],      pa);
    gload16(&As[0][akg][ar + 64][0], pa + rstep);
    gload16(&Bs[0][akg][ar][0],      pb);
    gload16(&Bs[0][akg][ar + 64][0], pb + rstep);
    gload16(&As[1][akg][ar][0],      pa + 32);
    gload16(&As[1][akg][ar + 64][0], pa + rstep + 32);
    gload16(&Bs[1][akg][ar][0],      pb + 32);
    gload16(&Bs[1][akg][ar + 64][0], pb + rstep + 32);

#define GEMM_STEP(CB, PB, KK, VM)                                          \
    {                                                                      \
        asm volatile("s_waitcnt vmcnt(" #VM ")" ::: "memory");             \
        __builtin_amdgcn_s_barrier();                                      \
        __builtin_amdgcn_sched_barrier(0);                                 \
        if ((KK) + 2 < nk) {                                               \
            const unsigned short* ga = pa + (size_t)((KK) + 2) * 32;       \
            const unsigned short* gb = pb + (size_t)((KK) + 2) * 32;       \
            gload16(&As[PB][akg][ar][0],      ga);                         \
            gload16(&As[PB][akg][ar + 64][0], ga + rstep);                 \
            gload16(&Bs[PB][akg][ar][0],      gb);                         \
            gload16(&Bs[PB][akg][ar + 64][0], gb + rstep);                 \
        }                                                                  \
        bf16x8 af[4], bfr[4];                                              \
        _Pragma("unroll")                                                  \
        for (int i = 0; i < 4; ++i) {                                      \
            af[i]  = *(const bf16x8*)&As[CB][kg][rwl + i * 16 + mi][0];    \
            bfr[i] = *(const bf16x8*)&Bs[CB][kg][cwl + i * 16 + mi][0];    \
        }                                                                  \
        __builtin_amdgcn_s_setprio(1);                                     \
        _Pragma("unroll")                                                  \
        for (int ri = 0; ri < 4; ++ri)                                     \
            _Pragma("unroll")                                              \
            for (int ci = 0; ci < 4; ++ci)                                 \
                acc[ri][ci] = __builtin_amdgcn_mfma_f32_16x16x32_bf16(     \
                    af[ri], bfr[ci], acc[ri][ci], 0, 0, 0);                \
        __builtin_amdgcn_s_setprio(0);                                     \
    }

    int k = 0;
    while (k + 4 < nk) {           // all three bodies may prefetch
        GEMM_STEP(0, 2, k,     4)
        GEMM_STEP(1, 0, k + 1, 4)
        GEMM_STEP(2, 1, k + 2, 4)
        k += 3;
    }
    // tail: nk % 3 == 2 -> exactly two steps remain, buffers 0 then 1
    GEMM_STEP(0, 2, k,     4)
    GEMM_STEP(1, 0, k + 1, 0)
#undef GEMM_STEP
}

// Epilogue variants. ACT: 1=gelu. OUTB: 1=bf16 out. RES: add resid.
template<int ACT, int OUTB, int RES>
__global__ __launch_bounds__(256) void mfma_gemm(
    const unsigned short* __restrict__ A, const unsigned short* __restrict__ Bt,
    const float* __restrict__ bias, const float* resid,
    float* outf, unsigned short* __restrict__ outb,
    int N, int K)
{
    const int row0 = blockIdx.y * 128, col0 = blockIdx.x * 128;
    f32x4 acc[4][4] = {};
    gemm_core(A, Bt, row0, col0, K, K >> 5, acc);

    const int lane = threadIdx.x & 63, w = threadIdx.x >> 6;
    const int rwl = (w >> 1) * 64, cwl = (w & 1) * 64;
    const int mi = lane & 15, kg = lane >> 4;

    #pragma unroll
    for (int ri = 0; ri < 4; ++ri) {
        #pragma unroll
        for (int ci = 0; ci < 4; ++ci) {
            #pragma unroll
            for (int j = 0; j < 4; ++j) {
                const int row = row0 + rwl + ri * 16 + kg * 4 + j;
                const int col = col0 + cwl + ci * 16 + mi;
                float v = acc[ri][ci][j] + bias[col];
                if (ACT) v = 0.5f * v * (1.0f + erff(v * 0.70710678118f));
                if (RES) v += resid[(size_t)row * N + col];
                if (OUTB) outb[(size_t)row * N + col] = f2bf(v);
                else      outf[(size_t)row * N + col] = v;
            }
        }
    }
}

// Split-K=4 residual-accumulate GEMM: X += A@Bt^T (+bias on split 0).
// X already holds the residual stream -> in-place atomic accumulation,
// no resid read, no scratch, no reduce pass. Grid (N/128, M/128, 4).
__global__ __launch_bounds__(256) void mfma_gemm_ressplit(
    const unsigned short* __restrict__ A, const unsigned short* __restrict__ Bt,
    const float* __restrict__ bias, float* __restrict__ X,
    int N, int K)
{
    const int row0 = blockIdx.y * 128, col0 = blockIdx.x * 128;
    const int ks = blockIdx.z;
    const int kseg = K >> 2;
    f32x4 acc[4][4] = {};
    gemm_core(A + (size_t)ks * kseg, Bt + (size_t)ks * kseg,
              row0, col0, K, kseg >> 5, acc);

    const int lane = threadIdx.x & 63, w = threadIdx.x >> 6;
    const int rwl = (w >> 1) * 64, cwl = (w & 1) * 64;
    const int mi = lane & 15, kg = lane >> 4;

    #pragma unroll
    for (int ri = 0; ri < 4; ++ri)
        #pragma unroll
        for (int ci = 0; ci < 4; ++ci)
            #pragma unroll
            for (int j = 0; j < 4; ++j) {
                const int row = row0 + rwl + ri * 16 + kg * 4 + j;
                const int col = col0 + cwl + ci * 16 + mi;
                float v = acc[ri][ci][j] + (ks == 0 ? bias[col] : 0.f);
                atomicAdd(&X[(size_t)row * N + col], v);
            }
}

// Q/K fused: blockIdx.x = grp(2)*8 + coltile; fp16 out, Q pre-scaled by 1/8.
__global__ __launch_bounds__(256) void mfma_gemm_qk(
    const unsigned short* __restrict__ A, const unsigned short* __restrict__ Wb,
    const float* __restrict__ bq, const float* __restrict__ bk,
    unsigned short* __restrict__ Qh, unsigned short* __restrict__ Kh)
{
    const int grp = blockIdx.x >> 3;
    const unsigned short* Bt = Wb + (size_t)grp * 1048576;
    const float* bias = grp == 0 ? bq : bk;
    unsigned short* out = grp == 0 ? Qh : Kh;
    const float scale = grp == 0 ? 0.125f : 1.0f;
    const int row0 = blockIdx.y * 128, col0 = (blockIdx.x & 7) * 128;

    f32x4 acc[4][4] = {};
    gemm_core(A, Bt, row0, col0, C_DIM, 32, acc);

    const int lane = threadIdx.x & 63, w = threadIdx.x >> 6;
    const int rwl = (w >> 1) * 64, cwl = (w & 1) * 64;
    const int mi = lane & 15, kg = lane >> 4;

    #pragma unroll
    for (int ri = 0; ri < 4; ++ri)
        #pragma unroll
        for (int ci = 0; ci < 4; ++ci)
            #pragma unroll
            for (int j = 0; j < 4; ++j) {
                const int row = row0 + rwl + ri * 16 + kg * 4 + j;
                const int col = col0 + cwl + ci * 16 + mi;
                out[(size_t)row * C_DIM + col] = f2h((acc[ri][ci][j] + bias[col]) * scale);
            }
}

// V TRANSPOSED by operand swap: V^T[cout][token] = WvT @ X^T
//   = gemm_core(A = WvT [1024][1024], Bt = Xb [3072][1024]).  Bias per ROW.
__global__ __launch_bounds__(256) void mfma_gemm_vt(
    const unsigned short* __restrict__ WvT, const unsigned short* __restrict__ Xb,
    const float* __restrict__ bv, unsigned short* __restrict__ Vt)
{
    const int row0 = blockIdx.y * 128, col0 = blockIdx.x * 128;
    f32x4 acc[4][4] = {};
    gemm_core(WvT, Xb, row0, col0, C_DIM, 32, acc);

    const int lane = threadIdx.x & 63, w = threadIdx.x >> 6;
    const int rwl = (w >> 1) * 64, cwl = (w & 1) * 64;
    const int mi = lane & 15, kg = lane >> 4;

    #pragma unroll
    for (int ri = 0; ri < 4; ++ri)
        #pragma unroll
        for (int ci = 0; ci < 4; ++ci)
            #pragma unroll
            for (int j = 0; j < 4; ++j) {
                const int row = row0 + rwl + ri * 16 + kg * 4 + j;   // cout
                const int col = col0 + cwl + ci * 16 + mi;           // token
                Vt[(size_t)row * MROWS + col] = f2h(acc[ri][ci][j] + bv[row]);
            }
}

// ---------------------------------------------------------------------------
// MFMA flash attention (unchanged): block per (qtile=64, h, b), 4 waves x
// 16 q-rows, XOR-chunk-swizzled LDS, online softmax in registers,
// reg-prefetch of next K/V tile.
// ---------------------------------------------------------------------------
__global__ __launch_bounds__(256) void attn_mfma(
    const unsigned short* __restrict__ Qh, const unsigned short* __restrict__ Kh,
    const unsigned short* __restrict__ Vt, unsigned short* __restrict__ Yb)
{
    const int qt = blockIdx.x, h = blockIdx.y, b = blockIdx.z;
    const int tid = threadIdx.x;
    const int lane = tid & 63, w = tid >> 6;
    const int mi = lane & 15, kg = lane >> 4;
    const int q0 = qt * 64;

    __shared__ __align__(16) char ldsraw[24576];
    unsigned short* Ks = (unsigned short*)ldsraw;            // [64 key][64 c]
    unsigned short* Vs = (unsigned short*)(ldsraw + 8192);   // [64 d][64 key]
    unsigned short* Ps = (unsigned short*)(ldsraw + 16384);  // [64 q][64 key]
    float* Ob = (float*)ldsraw;                              // [64][68] after loop

    const size_t qkbase = (size_t)b * S_LEN * C_DIM + (size_t)h * HDIM;
    const unsigned short* Kbase = Kh + qkbase;
    const unsigned short* Vbase = Vt + (size_t)h * HDIM * MROWS + (size_t)b * S_LEN;

    // Q A-fragments: lane holds Q[q0+w*16+mi][kg*8..+8 (+32)]
    f16x8 QA0, QA1;
    {
        const unsigned short* qp = Qh + qkbase + (size_t)(q0 + w * 16 + mi) * C_DIM + kg * 8;
        QA0 = *(const f16x8*)qp;
        QA1 = *(const f16x8*)(qp + 32);
    }

    // staging: thread covers tile rows {srow, srow+32}, 16B chunk sc16
    const int srow = tid >> 3, sc16 = tid & 7;
    const int dch = (sc16 ^ (srow & 7)) << 3;   // swizzled half-offset in row

    float mrow[4], lrow[4], alj[4];
    f32x4 Oacc[4];
    #pragma unroll
    for (int j = 0; j < 4; ++j) { mrow[j] = -1e30f; lrow[j] = 0.f; }
    #pragma unroll
    for (int df = 0; df < 4; ++df) Oacc[df] = (f32x4){0.f, 0.f, 0.f, 0.f};

    // preload tile 0
    uint4 rk0, rk1, rv0, rv1;
    {
        const unsigned short* kp = Kbase + (size_t)srow * C_DIM + sc16 * 8;
        rk0 = *(const uint4*)kp;
        rk1 = *(const uint4*)(kp + (size_t)32 * C_DIM);
        const unsigned short* vp = Vbase + (size_t)srow * MROWS + sc16 * 8;
        rv0 = *(const uint4*)vp;
        rv1 = *(const uint4*)(vp + (size_t)32 * MROWS);
    }

    for (int kt = 0; kt <= qt; ++kt) {
        __syncthreads();   // prev tile's readers done
        *(uint4*)&Ks[srow * 64 + dch]        = rk0;
        *(uint4*)&Ks[(srow + 32) * 64 + dch] = rk1;
        *(uint4*)&Vs[srow * 64 + dch]        = rv0;
        *(uint4*)&Vs[(srow + 32) * 64 + dch] = rv1;
        if (kt < qt) {   // prefetch next tile (latency hides under compute)
            const unsigned short* kp = Kbase + (size_t)((kt + 1) * 64 + srow) * C_DIM + sc16 * 8;
            rk0 = *(const uint4*)kp;
            rk1 = *(const uint4*)(kp + (size_t)32 * C_DIM);
            const unsigned short* vp = Vbase + (size_t)srow * MROWS + (kt + 1) * 64 + sc16 * 8;
            rv0 = *(const uint4*)vp;
            rv1 = *(const uint4*)(vp + (size_t)32 * MROWS);
        }
        __syncthreads();   // stage visible

        // ---- scores S = Q @ K^T (16q x 64k per wave)
        f32x4 sa[4];
        #pragma unroll
        for (int kf = 0; kf < 4; ++kf) {
            const int key = kf * 16 + mi;
            const unsigned short* kr = Ks + key * 64;
            const f16x8 kb0 = *(const f16x8*)(kr + ((kg ^ (key & 7)) << 3));
            const f16x8 kb1 = *(const f16x8*)(kr + (((4 + kg) ^ (key & 7)) << 3));
            f32x4 z = {0.f, 0.f, 0.f, 0.f};
            z = __builtin_amdgcn_mfma_f32_16x16x32_f16(QA0, kb0, z, 0, 0, 0);
            sa[kf] = __builtin_amdgcn_mfma_f32_16x16x32_f16(QA1, kb1, z, 0, 0, 0);
        }

        if (kt == qt) {   // causal mask within diagonal tile
            #pragma unroll
            for (int kf = 0; kf < 4; ++kf)
                #pragma unroll
                for (int j = 0; j < 4; ++j)
                    if (kf * 16 + mi > w * 16 + kg * 4 + j) sa[kf][j] = -1e30f;
        }

        // ---- online softmax: row j lives in (kg,reg); reduce over mi lanes
        #pragma unroll
        for (int j = 0; j < 4; ++j) {
            float rm = fmaxf(fmaxf(sa[0][j], sa[1][j]), fmaxf(sa[2][j], sa[3][j]));
            rm = fmaxf(rm, __shfl_xor(rm, 1, 16));
            rm = fmaxf(rm, __shfl_xor(rm, 2, 16));
            rm = fmaxf(rm, __shfl_xor(rm, 4, 16));
            rm = fmaxf(rm, __shfl_xor(rm, 8, 16));
            const float mn = fmaxf(mrow[j], rm);
            alj[j] = __expf(mrow[j] - mn);
            mrow[j] = mn;
            const float p0 = __expf(sa[0][j] - mn);
            const float p1 = __expf(sa[1][j] - mn);
            const float p2 = __expf(sa[2][j] - mn);
            const float p3 = __expf(sa[3][j] - mn);
            const int prow = w * 16 + kg * 4 + j;
            unsigned short* pr = Ps + prow * 64;
            const int sw = prow & 7, hi = mi >> 3, lo = mi & 7;
            pr[(((0 + hi) ^ sw) << 3) + lo] = f2h(p0);
            pr[(((2 + hi) ^ sw) << 3) + lo] = f2h(p1);
            pr[(((4 + hi) ^ sw) << 3) + lo] = f2h(p2);
            pr[(((6 + hi) ^ sw) << 3) + lo] = f2h(p3);
            float rs = p0 + p1 + p2 + p3;
            rs += __shfl_xor(rs, 1, 16);
            rs += __shfl_xor(rs, 2, 16);
            rs += __shfl_xor(rs, 4, 16);
            rs += __shfl_xor(rs, 8, 16);
            lrow[j] = lrow[j] * alj[j] + rs;
        }
        // no barrier needed: P written & read by the SAME wave's strip only

        // ---- O = O*alpha + P @ V (16q x 64d per wave)
        const unsigned short* pp = Ps + (w * 16 + mi) * 64;
        const int psw = mi & 7;
        const f16x8 PA0 = *(const f16x8*)(pp + ((kg ^ psw) << 3));
        const f16x8 PA1 = *(const f16x8*)(pp + (((4 + kg) ^ psw) << 3));
        #pragma unroll
        for (int df = 0; df < 4; ++df) {
            const int d = df * 16 + mi;
            const unsigned short* vr = Vs + d * 64;
            const f16x8 vb0 = *(const f16x8*)(vr + ((kg ^ (d & 7)) << 3));
            const f16x8 vb1 = *(const f16x8*)(vr + (((4 + kg) ^ (d & 7)) << 3));
            f32x4 o = Oacc[df];
            o[0] *= alj[0]; o[1] *= alj[1]; o[2] *= alj[2]; o[3] *= alj[3];
            o = __builtin_amdgcn_mfma_f32_16x16x32_f16(PA0, vb0, o, 0, 0, 0);
            Oacc[df] = __builtin_amdgcn_mfma_f32_16x16x32_f16(PA1, vb1, o, 0, 0, 0);
        }
    }

    // ---- normalize, bounce through LDS (Ob aliases Ks/Vs/Ps), coalesced store
    __syncthreads();
    float inv[4];
    #pragma unroll
    for (int j = 0; j < 4; ++j) inv[j] = 1.0f / lrow[j];
    #pragma unroll
    for (int df = 0; df < 4; ++df)
        #pragma unroll
        for (int j = 0; j < 4; ++j)
            Ob[(w * 16 + kg * 4 + j) * 68 + df * 16 + mi] = Oacc[df][j] * inv[j];
    __syncthreads();

    const int orow = tid >> 2, oc0 = (tid & 3) * 16;
    unsigned short __align__(16) hx[16];
    #pragma unroll
    for (int i = 0; i < 16; ++i) hx[i] = f2bf(Ob[orow * 68 + oc0 + i]);
    unsigned short* yp = Yb + qkbase + (size_t)(q0 + orow) * C_DIM + oc0;
    *(uint4*)yp       = *(uint4*)&hx[0];
    *(uint4*)(yp + 8) = *(uint4*)&hx[8];
}

// ---------------------------------------------------------------------------
// Head: block per (b,t); bf16 final-LN row @ s=3t+1 times head_w -> f32 out.
// ---------------------------------------------------------------------------
__global__ __launch_bounds__(256) void head_kernel(
    const unsigned short* __restrict__ Xb, const float* __restrict__ hw,
    float* __restrict__ out)
{
    const int n = blockIdx.x;
    const int b = n >> 8, t = n & 255;
    const int tid = threadIdx.x;
    __shared__ float rowv[C_DIM];

    const unsigned short* x = Xb + ((size_t)b * S_LEN + 3 * t + 1) * C_DIM;
    #pragma unroll
    for (int j = 0; j < 4; ++j) rowv[tid + j * 256] = bf2f(x[tid + j * 256]);
    __syncthreads();

    if (tid < NACT) {
        float a = 0.f;
        for (int k = 0; k < C_DIM; ++k) a += rowv[k] * hw[k * NACT + tid];
        out[(size_t)n * NACT + tid] = a;
    }
}

// ---------------------------------------------------------------------------
extern "C" void kernel_launch(void* const* d_in, const int* in_sizes, int n_in,
                              void* d_out, int out_size, void* d_ws, size_t ws_size,
                              hipStream_t stream) {
    const float* states  = (const float*)d_in[0];
    const float* rtgs    = (const float*)d_in[1];
    const float* meta    = (const float*)d_in[2];
    const float* c1w = (const float*)d_in[4];
    const float* c1b = (const float*)d_in[5];
    const float* c2w = (const float*)d_in[6];
    const float* c2b = (const float*)d_in[7];
    const float* c3w = (const float*)d_in[8];
    const float* c3b = (const float*)d_in[9];
    const float* encw = (const float*)d_in[10];
    const float* encb = (const float*)d_in[11];
    const float* mw1 = (const float*)d_in[12];
    const float* mb1 = (const float*)d_in[13];
    const float* mw2 = (const float*)d_in[14];
    const float* mb2 = (const float*)d_in[15];
    const float* retw = (const float*)d_in[16];
    const float* retb = (const float*)d_in[17];
    const float* aemb = (const float*)d_in[18];
    const float* pos  = (const float*)d_in[19];
    const float* gpos = (const float*)d_in[20];
    const float* ln1g = (const float*)d_in[21];
    const float* ln1b = (const float*)d_in[22];
    const float* ln2g = (const float*)d_in[23];
    const float* ln2b = (const float*)d_in[24];
    const float* Wq = (const float*)d_in[25];
    const float* bq = (const float*)d_in[26];
    const float* Wk = (const float*)d_in[27];
    const float* bk = (const float*)d_in[28];
    const float* Wv = (const float*)d_in[29];
    const float* bv = (const float*)d_in[30];
    const float* Wo = (const float*)d_in[31];
    const float* bo = (const float*)d_in[32];
    const float* Wm1 = (const float*)d_in[33];
    const float* bm1 = (const float*)d_in[34];
    const float* Wm2 = (const float*)d_in[35];
    const float* bm2 = (const float*)d_in[36];
    const float* lnfg = (const float*)d_in[37];
    const float* lnfb = (const float*)d_in[38];
    const float* hw   = (const float*)d_in[39];
    const int* actions   = (const int*)d_in[40];
    const int* timesteps = (const int*)d_in[41];

    float* out = (float*)d_out;

    // ws layout (bytes): X[0,12M) Qh[12,18) Kh[18,24) Vt[24,30) Xb[48,54)
    //                    Yb[54,60) Wb[60,84).  Hb (MLP hidden bf16, 24 MB)
    //                    overlaps Qh/Kh/Vt (dead during MLP phase).
    char* wsc = (char*)d_ws;
    const size_t SLABB = (size_t)MROWS * C_DIM * 4;   // 12 MB
    float* X  = (float*)wsc;
    unsigned short* Qh = (unsigned short*)(wsc + SLABB);
    unsigned short* Kh = Qh + (size_t)MROWS * C_DIM;
    unsigned short* Vt = (unsigned short*)(wsc + 2 * SLABB);
    unsigned short* Hb = (unsigned short*)(wsc + SLABB);
    unsigned short* Xb = (unsigned short*)(wsc + 4 * SLABB);
    unsigned short* Yb = (unsigned short*)(wsc + 4 * SLABB + SLABB / 2);
    unsigned short* Wb = (unsigned short*)(wsc + 5 * SLABB);   // 24 MB

    embed_kernel<<<BATCH * TCTX, 256, 0, stream>>>(
        states, rtgs, meta, c1w, c1b, c2w, c2b, c3w, c3b, encw, encb,
        mw1, mb1, mw2, mb2, retw, retb, aemb, pos, gpos, actions, timesteps, X);

    const dim3 gqk(16, 24);
    const dim3 gvt(24, 8);
    const dim3 gres(8, 24, 4);     // split-K=4 residual GEMMs -> 768 blocks
    const dim3 g4096(32, 24);
    const dim3 gattn(12, NHEAD, BATCH);

    for (int i = 0; i < 6; ++i) {
        const size_t wOff = (size_t)i * C_DIM * C_DIM;
        const size_t bOff = (size_t)i * C_DIM;
        const size_t m1Off = (size_t)i * C_DIM * DFF;

        transpose_w_kernel<<<3072, 256, 0, stream>>>(
            Wq + wOff, Wk + wOff, Wv + wOff, Wo + wOff, Wm1 + m1Off, Wm2 + m1Off, Wb);

        ln_bf16_kernel<<<MROWS / 4, 256, 0, stream>>>(X, Xb, ln1g + bOff, ln1b + bOff);
        mfma_gemm_qk<<<gqk, 256, 0, stream>>>(Xb, Wb, bq + bOff, bk + bOff, Qh, Kh);
        mfma_gemm_vt<<<gvt, 256, 0, stream>>>(Wb + (size_t)2 * 1048576, Xb, bv + bOff, Vt);
        attn_mfma<<<gattn, 256, 0, stream>>>(Qh, Kh, Vt, Yb);
        mfma_gemm_ressplit<<<gres, 256, 0, stream>>>(
            Yb, Wb + (size_t)3 * 1048576, bo + bOff, X, C_DIM, C_DIM);
        ln_bf16_kernel<<<MROWS / 4, 256, 0, stream>>>(X, Xb, ln2g + bOff, ln2b + bOff);
        mfma_gemm<1, 1, 0><<<g4096, 256, 0, stream>>>(
            Xb, Wb + (size_t)4 * 1048576, bm1 + (size_t)i * DFF, nullptr, nullptr, Hb, DFF, C_DIM);
        mfma_gemm_ressplit<<<gres, 256, 0, stream>>>(
            Hb, Wb + (size_t)8 * 1048576, bm2 + bOff, X, C_DIM, DFF);
    }

    ln_bf16_kernel<<<MROWS / 4, 256, 0, stream>>>(X, Xb, lnfg, lnfb);
    head_kernel<<<BATCH * TCTX, 256, 0, stream>>>(Xb, hw, out);
}

// Round 4
// 2414.592 us; speedup vs baseline: 1.4112x; 1.0183x over previous
//
#include <hip/hip_runtime.h>
#include <hip/hip_bf16.h>

// ---------------------------------------------------------------------------
// Decision-Transformer forward, MI355X round 8:
//  - XCD-aware logical blockIdx remap on ALL GEMMs (T1, reuse-set targeted):
//    blocks sharing an A-row-panel are grouped onto ONE XCD (y = xcd+8*y'),
//    and for split-K the 4 K-splits of an output tile are ADJACENT slots on
//    the same XCD -> atomicAdd accumulates in that XCD's L2, one writeback.
//    (R7 counters: FETCH 105 MB vs 32 MB unique, WRITE 49 vs 12 MB -> all
//    reuse was cross-XCD.)
//  - qk + vt fused into one 576-block dispatch (mfma_gemm_qkvt).
//  - attn: (h,b) pair grouped per XCD (K/V reuse), long-qt-first ordering.
// Workspace: 84 MB (X 12 | Qh 6 | Kh 6 | Vt 6 | Xb 6 | Yb 6 | Wb 24).
// ---------------------------------------------------------------------------

#define S_LEN 768
#define C_DIM 1024
#define NHEAD 16
#define HDIM 64
#define BATCH 4
#define TCTX 256
#define DFF 4096
#define NACT 80
#define MROWS (BATCH * S_LEN)   // 3072

typedef __attribute__((ext_vector_type(4))) float f32x4;
typedef __attribute__((ext_vector_type(8))) short bf16x8;
typedef __attribute__((ext_vector_type(8))) _Float16 f16x8;

static __device__ __forceinline__ unsigned short f2bf(float f) {
    unsigned int u = __float_as_uint(f);
    u += 0x7FFF + ((u >> 16) & 1);          // RNE
    return (unsigned short)(u >> 16);
}
static __device__ __forceinline__ float bf2f(unsigned short h) {
    return __uint_as_float(((unsigned int)h) << 16);
}
static __device__ __forceinline__ unsigned short f2h(float f) {
    _Float16 h = (_Float16)f;
    return __builtin_bit_cast(unsigned short, h);
}

// async global -> LDS, 16 bytes per lane. LDS dest must be wave-uniform base
// + lane*16 contiguous (our staging layout is exactly that).
static __device__ __forceinline__ void gload16(void* l, const void* g) {
    __builtin_amdgcn_global_load_lds(
        (__attribute__((address_space(1))) void*)(g),
        (__attribute__((address_space(3))) void*)(l), 16, 0, 0);
}

// ---------------------------------------------------------------------------
// Weight conversion: per layer, f32 [K][N] -> bf16 transposed [N][K] in Wb.
// Wb elem offsets: WqT 0, WkT 1M, WvT 2M, WoT 3M, Wm1T 4M (N=4096,K=1024),
// Wm2T 8M (N=1024,K=4096). 64x64 tiles via LDS, coalesced in and out.
// ---------------------------------------------------------------------------
__global__ __launch_bounds__(256) void transpose_w_kernel(
    const float* __restrict__ Wq, const float* __restrict__ Wk,
    const float* __restrict__ Wv, const float* __restrict__ Wo,
    const float* __restrict__ Wm1, const float* __restrict__ Wm2,
    unsigned short* __restrict__ Wb)
{
    const int t = blockIdx.x;
    const float* src; unsigned short* dst; int K, N, kt, nt;
    if (t < 1024) {
        const int m = t >> 8, tile = t & 255;
        src = (m == 0) ? Wq : (m == 1) ? Wk : (m == 2) ? Wv : Wo;
        dst = Wb + (size_t)m * 1048576;
        K = 1024; N = 1024; kt = tile >> 4; nt = tile & 15;
    } else if (t < 2048) {
        const int tile = t - 1024;
        src = Wm1; dst = Wb + (size_t)4 * 1048576;
        K = 1024; N = 4096; kt = tile >> 6; nt = tile & 63;
    } else {
        const int tile = t - 2048;
        src = Wm2; dst = Wb + (size_t)8 * 1048576;
        K = 4096; N = 1024; kt = tile >> 4; nt = tile & 15;
    }
    const int k0 = kt * 64, n0 = nt * 64;
    __shared__ float Ls[64][65];

    const int r = threadIdx.x >> 2, p = threadIdx.x & 3;
    #pragma unroll
    for (int i = 0; i < 4; ++i)
        *(float4*)&Ls[r][p * 16 + i * 4] =
            *(const float4*)&src[(size_t)(k0 + r) * N + n0 + p * 16 + i * 4];
    __syncthreads();

    unsigned short __align__(16) h[16];
    #pragma unroll
    for (int i = 0; i < 16; ++i) h[i] = f2bf(Ls[p * 16 + i][r]);
    unsigned short* d = dst + (size_t)(n0 + r) * K + k0 + p * 16;
    *(uint4*)d       = *(uint4*)&h[0];
    *(uint4*)(d + 8) = *(uint4*)&h[8];
}

// ---------------------------------------------------------------------------
// Embedding (unchanged): one block per (b,t) -> X f32.
// ---------------------------------------------------------------------------
__global__ __launch_bounds__(256) void embed_kernel(
    const float* __restrict__ states, const float* __restrict__ rtgs,
    const float* __restrict__ meta,
    const float* __restrict__ c1w, const float* __restrict__ c1b,
    const float* __restrict__ c2w, const float* __restrict__ c2b,
    const float* __restrict__ c3w, const float* __restrict__ c3b,
    const float* __restrict__ encw, const float* __restrict__ encb,
    const float* __restrict__ mw1, const float* __restrict__ mb1,
    const float* __restrict__ mw2, const float* __restrict__ mb2,
    const float* __restrict__ retw, const float* __restrict__ retb,
    const float* __restrict__ aemb, const float* __restrict__ pos,
    const float* __restrict__ gpos,
    const int* __restrict__ actions, const int* __restrict__ timesteps,
    float* __restrict__ X)
{
    const int n = blockIdx.x;
    const int b = n >> 8, t = n & 255;
    const int tid = threadIdx.x;

    __shared__ float sin_[640];
    __shared__ float h1[96];
    __shared__ float h2[32];
    __shared__ float feat[16];
    __shared__ float hidm[32];
    __shared__ float mer[4];

    for (int e = tid; e < 640; e += 256)
        sin_[e] = states[(size_t)n * 640 + e];
    __syncthreads();

    if (tid < 96) {
        int o = tid / 6, rem = tid % 6, oh = rem / 3, ow = rem % 3;
        float a = c1b[o];
        for (int ci = 0; ci < 8; ++ci)
            for (int kh = 0; kh < 8; ++kh) {
                int ih = oh * 2 - 1 + kh;
                if (ih < 0 || ih >= 8) continue;
                for (int kw = 0; kw < 8; ++kw) {
                    int iw = ow * 2 - 1 + kw;
                    if (iw < 0 || iw >= 10) continue;
                    a += c1w[((o * 8 + ci) * 8 + kh) * 8 + kw] * sin_[ci * 80 + ih * 10 + iw];
                }
            }
        h1[tid] = fmaxf(a, 0.f);
    }
    if (tid < 32) {
        float a = mb1[tid];
        for (int i = 0; i < 4; ++i)
            a += meta[(size_t)n * 4 + i] * mw1[i * 32 + tid];
        hidm[tid] = fmaxf(a, 0.f);
    }
    __syncthreads();

    if (tid < 32) {
        float a = c2b[tid];
        for (int ci = 0; ci < 16; ++ci)
            for (int kh = 0; kh < 4; ++kh) {
                int ih = -1 + kh;
                if (ih < 0 || ih >= 2) continue;
                for (int kw = 0; kw < 4; ++kw) {
                    int iw = -1 + kw;
                    if (iw < 0 || iw >= 3) continue;
                    a += c2w[((tid * 16 + ci) * 4 + kh) * 4 + kw] * h1[ci * 6 + ih * 3 + iw];
                }
            }
        h2[tid] = fmaxf(a, 0.f);
    }
    __syncthreads();

    if (tid < 16) {
        float a = c3b[tid];
        for (int ci = 0; ci < 32; ++ci)
            a += c3w[(tid * 32 + ci) * 9 + 4] * h2[ci];
        feat[tid] = fmaxf(a, 0.f);
    }
    if (tid < 4) {
        float a = mb2[tid];
        for (int j = 0; j < 32; ++j) a += hidm[j] * mw2[j * 4 + tid];
        mer[tid] = a;
    }
    __syncthreads();

    const float r = rtgs[n];
    const int a_idx = actions[n];
    const int g = timesteps[b];
    const size_t xbase = ((size_t)b * S_LEN + 3 * t) * C_DIM;

    for (int c = tid; c < C_DIM; c += 256) {
        float se;
        if (c < 1020) {
            float acc = encb[c];
            #pragma unroll
            for (int k = 0; k < 16; ++k) acc += feat[k] * encw[k * 1020 + c];
            se = acc;
        } else {
            se = mer[c - 1020];
        }
        const float st = tanhf(se);
        const float rt = tanhf(r * retw[c] + retb[c]);
        const float ae = aemb[(size_t)a_idx * C_DIM + c];
        const float gp = gpos[(size_t)g * C_DIM + c];
        X[xbase + c]             = rt + gp + pos[(size_t)(3 * t + 0) * C_DIM + c];
        X[xbase + C_DIM + c]     = st + gp + pos[(size_t)(3 * t + 1) * C_DIM + c];
        X[xbase + 2 * C_DIM + c] = ae + gp + pos[(size_t)(3 * t + 2) * C_DIM + c];
    }
}

// ---------------------------------------------------------------------------
// LayerNorm over last dim (1024), bf16 output. Wave-per-row: 64-lane
// shfl_xor reduction, no LDS, no barriers. Block = 4 rows.
// ---------------------------------------------------------------------------
__global__ __launch_bounds__(256) void ln_bf16_kernel(
    const float* __restrict__ in, unsigned short* __restrict__ out,
    const float* __restrict__ gw, const float* __restrict__ bw)
{
    const int row = blockIdx.x * 4 + (threadIdx.x >> 6);
    const int lane = threadIdx.x & 63;
    const float* x = in + (size_t)row * C_DIM;

    float4 v[4];
    float s = 0.f;
    #pragma unroll
    for (int j = 0; j < 4; ++j) {
        v[j] = *(const float4*)&x[lane * 4 + j * 256];
        s += (v[j].x + v[j].y) + (v[j].z + v[j].w);
    }
    #pragma unroll
    for (int o = 1; o < 64; o <<= 1) s += __shfl_xor(s, o, 64);
    const float mean = s * (1.0f / 1024.0f);

    float s2 = 0.f;
    #pragma unroll
    for (int j = 0; j < 4; ++j) {
        float dx = v[j].x - mean, dy = v[j].y - mean;
        float dz = v[j].z - mean, dw = v[j].w - mean;
        s2 += (dx * dx + dy * dy) + (dz * dz + dw * dw);
    }
    #pragma unroll
    for (int o = 1; o < 64; o <<= 1) s2 += __shfl_xor(s2, o, 64);
    const float inv = rsqrtf(s2 * (1.0f / 1024.0f) + 1e-5f);

    #pragma unroll
    for (int j = 0; j < 4; ++j) {
        const int c = lane * 4 + j * 256;
        ushort4 o4;
        o4.x = f2bf((v[j].x - mean) * inv * gw[c + 0] + bw[c + 0]);
        o4.y = f2bf((v[j].y - mean) * inv * gw[c + 1] + bw[c + 1]);
        o4.z = f2bf((v[j].z - mean) * inv * gw[c + 2] + bw[c + 2]);
        o4.w = f2bf((v[j].w - mean) * inv * gw[c + 3] + bw[c + 3]);
        *(ushort4*)&out[(size_t)row * C_DIM + c] = o4;
    }
}

// ---------------------------------------------------------------------------
// MFMA GEMM core v3: A bf16 [M][ldk] row-major; Bt bf16 [N][ldk].
// 128x128 tile, BK=32, 4 waves, 4x4 16x16x32 frags each, f32 accum.
// 2-deep / 3-buffer pipeline, K-loop UNROLLED x3 with literal buffer
// indices (alias-analysis-friendly -> counted vmcnt survives).
// Requires nk % 3 == 2 (true for all callers: nk in {8, 32}).
// ---------------------------------------------------------------------------
__device__ __forceinline__ void gemm_core(
    const unsigned short* __restrict__ A, const unsigned short* __restrict__ Bt,
    int row0, int col0, int ldk, int nk, f32x4 (&acc)[4][4])
{
    __shared__ __align__(16) unsigned short As[3][4][128][8];
    __shared__ __align__(16) unsigned short Bs[3][4][128][8];

    const int tid = threadIdx.x;
    const int ar  = tid & 63, akg = tid >> 6;     // staging: row, k-group(=wave)
    const int lane = tid & 63, w = tid >> 6;
    const int rwl = (w >> 1) * 64, cwl = (w & 1) * 64;
    const int mi = lane & 15, kg = lane >> 4;

    const unsigned short* pa = A + (size_t)(row0 + ar) * ldk + akg * 8;
    const unsigned short* pb = Bt + (size_t)(col0 + ar) * ldk + akg * 8;
    const size_t rstep = (size_t)64 * ldk;

    // prologue: stage k=0 -> buf0, k=1 -> buf1 (8 loads in flight per wave)
    gload16(&As[0][akg][ar][0],      pa);
    gload16(&As[0][akg][ar + 64][0], pa + rstep);
    gload16(&Bs[0][akg][ar][0],      pb);
    gload16(&Bs[0][akg][ar + 64][0], pb + rstep);
    gload16(&As[1][akg][ar][0],      pa + 32);
    gload16(&As[1][akg][ar + 64][0], pa + rstep + 32);
    gload16(&Bs[1][akg][ar][0],      pb + 32);
    gload16(&Bs[1][akg][ar + 64][0], pb + rstep + 32);

#define GEMM_STEP(CB, PB, KK, VM)                                          \
    {                                                                      \
        asm volatile("s_waitcnt vmcnt(" #VM ")" ::: "memory");             \
        __builtin_amdgcn_s_barrier();                                      \
        __builtin_amdgcn_sched_barrier(0);                                 \
        if ((KK) + 2 < nk) {                                               \
            const unsigned short* ga = pa + (size_t)((KK) + 2) * 32;       \
            const unsigned short* gb = pb + (size_t)((KK) + 2) * 32;       \
            gload16(&As[PB][akg][ar][0],      ga);                         \
            gload16(&As[PB][akg][ar + 64][0], ga + rstep);                 \
            gload16(&Bs[PB][akg][ar][0],      gb);                         \
            gload16(&Bs[PB][akg][ar + 64][0], gb + rstep);                 \
        }                                                                  \
        bf16x8 af[4], bfr[4];                                              \
        _Pragma("unroll")                                                  \
        for (int i = 0; i < 4; ++i) {                                      \
            af[i]  = *(const bf16x8*)&As[CB][kg][rwl + i * 16 + mi][0];    \
            bfr[i] = *(const bf16x8*)&Bs[CB][kg][cwl + i * 16 + mi][0];    \
        }                                                                  \
        __builtin_amdgcn_s_setprio(1);                                     \
        _Pragma("unroll")                                                  \
        for (int ri = 0; ri < 4; ++ri)                                     \
            _Pragma("unroll")                                              \
            for (int ci = 0; ci < 4; ++ci)                                 \
                acc[ri][ci] = __builtin_amdgcn_mfma_f32_16x16x32_bf16(     \
                    af[ri], bfr[ci], acc[ri][ci], 0, 0, 0);                \
        __builtin_amdgcn_s_setprio(0);                                     \
    }

    int k = 0;
    while (k + 4 < nk) {           // all three bodies may prefetch
        GEMM_STEP(0, 2, k,     4)
        GEMM_STEP(1, 0, k + 1, 4)
        GEMM_STEP(2, 1, k + 2, 4)
        k += 3;
    }
    // tail: nk % 3 == 2 -> exactly two steps remain, buffers 0 then 1
    GEMM_STEP(0, 2, k,     4)
    GEMM_STEP(1, 0, k + 1, 0)
#undef GEMM_STEP
}

// ---------------------------------------------------------------------------
// MLP-up GEMM (gelu -> bf16 out). Grid MUST be (32, 24).
// XCD remap: rows grouped per XCD (A-panel reuse stays in one L2).
// ---------------------------------------------------------------------------
__global__ __launch_bounds__(256) void mfma_gemm_up(
    const unsigned short* __restrict__ A, const unsigned short* __restrict__ Bt,
    const float* __restrict__ bias, unsigned short* __restrict__ outb,
    int N, int K)
{
    const int h = blockIdx.x + (blockIdx.y << 5);   // 0..767
    const int xcd = h & 7, s = h >> 3;              // s 0..95
    const int col0 = (s & 31) * 128;                // x fastest
    const int row0 = (xcd + 8 * (s >> 5)) * 128;    // y = xcd + 8*y'

    f32x4 acc[4][4] = {};
    gemm_core(A, Bt, row0, col0, K, K >> 5, acc);

    const int lane = threadIdx.x & 63, w = threadIdx.x >> 6;
    const int rwl = (w >> 1) * 64, cwl = (w & 1) * 64;
    const int mi = lane & 15, kg = lane >> 4;

    #pragma unroll
    for (int ri = 0; ri < 4; ++ri)
        #pragma unroll
        for (int ci = 0; ci < 4; ++ci)
            #pragma unroll
            for (int j = 0; j < 4; ++j) {
                const int row = row0 + rwl + ri * 16 + kg * 4 + j;
                const int col = col0 + cwl + ci * 16 + mi;
                float v = acc[ri][ci][j] + bias[col];
                v = 0.5f * v * (1.0f + erff(v * 0.70710678118f));
                outb[(size_t)row * N + col] = f2bf(v);
            }
}

// ---------------------------------------------------------------------------
// Split-K=4 residual-accumulate GEMM: X += A@Bt^T (+bias on split 0).
// Grid MUST be (8, 24, 4). XCD remap: y = xcd+8*y' (A reuse in-L2) AND the
// 4 K-splits of a tile are adjacent slots on the SAME XCD -> atomics
// accumulate in that XCD's L2, single writeback.
// ---------------------------------------------------------------------------
__global__ __launch_bounds__(256) void mfma_gemm_ressplit(
    const unsigned short* __restrict__ A, const unsigned short* __restrict__ Bt,
    const float* __restrict__ bias, float* __restrict__ X,
    int N, int K)
{
    const int h = blockIdx.x + (blockIdx.y << 3) + blockIdx.z * 192;  // 0..767
    const int xcd = h & 7, s = h >> 3;              // s 0..95
    const int ks = s & 3;                           // split: fastest (adjacent)
    const int col0 = ((s >> 2) & 7) * 128;
    const int row0 = (xcd + 8 * (s >> 5)) * 128;

    const int kseg = K >> 2;
    f32x4 acc[4][4] = {};
    gemm_core(A + (size_t)ks * kseg, Bt + (size_t)ks * kseg,
              row0, col0, K, kseg >> 5, acc);

    const int lane = threadIdx.x & 63, w = threadIdx.x >> 6;
    const int rwl = (w >> 1) * 64, cwl = (w & 1) * 64;
    const int mi = lane & 15, kg = lane >> 4;

    #pragma unroll
    for (int ri = 0; ri < 4; ++ri)
        #pragma unroll
        for (int ci = 0; ci < 4; ++ci)
            #pragma unroll
            for (int j = 0; j < 4; ++j) {
                const int row = row0 + rwl + ri * 16 + kg * 4 + j;
                const int col = col0 + cwl + ci * 16 + mi;
                float v = acc[ri][ci][j] + (ks == 0 ? bias[col] : 0.f);
                atomicAdd(&X[(size_t)row * N + col], v);
            }
}

// ---------------------------------------------------------------------------
// Fused Q/K/V^T producer, ONE dispatch of 576 blocks.
//  h <  384: Q or K tile. grp = Q(0)/K(1); fp16 out, Q pre-scaled 1/8.
//            XCD remap: token-row y = xcd + 8*y' (Xb panel reuse in-L2).
//  h >= 384: V^T tile via operand swap (V^T = WvT @ Xb^T); bias per ROW.
//            XCD remap: cout-tile y = xcd (WvT panel resident per XCD).
// (384 % 8 == 0 so the two parts have independent clean XCD mappings.)
// ---------------------------------------------------------------------------
__global__ __launch_bounds__(256) void mfma_gemm_qkvt(
    const unsigned short* __restrict__ Xb, const unsigned short* __restrict__ Wb,
    const float* __restrict__ bq, const float* __restrict__ bk,
    const float* __restrict__ bv,
    unsigned short* __restrict__ Qh, unsigned short* __restrict__ Kh,
    unsigned short* __restrict__ Vt)
{
    const int h = blockIdx.x;
    const unsigned short *A, *Bt;
    int row0, col0, grp = -1;

    if (h < 384) {
        const int xcd = h & 7, s = h >> 3;          // s 0..47
        const int x = s & 15;                       // grp*8 + coltile
        const int y = xcd + 8 * (s >> 4);           // token row tile 0..23
        grp = x >> 3;
        A = Xb; Bt = Wb + (size_t)grp * 1048576;
        row0 = y * 128; col0 = (x & 7) * 128;
    } else {
        const int j = h - 384;
        const int xcd = j & 7, s = j >> 3;          // s 0..23
        A = Wb + (size_t)2 * 1048576; Bt = Xb;
        row0 = xcd * 128;                           // cout tile = xcd
        col0 = s * 128;                             // token tile
    }

    f32x4 acc[4][4] = {};
    gemm_core(A, Bt, row0, col0, C_DIM, 32, acc);

    const int lane = threadIdx.x & 63, w = threadIdx.x >> 6;
    const int rwl = (w >> 1) * 64, cwl = (w & 1) * 64;
    const int mi = lane & 15, kg = lane >> 4;

    if (grp >= 0) {
        const float* bias = grp == 0 ? bq : bk;
        unsigned short* out = grp == 0 ? Qh : Kh;
        const float scale = grp == 0 ? 0.125f : 1.0f;
        #pragma unroll
        for (int ri = 0; ri < 4; ++ri)
            #pragma unroll
            for (int ci = 0; ci < 4; ++ci)
                #pragma unroll
                for (int j = 0; j < 4; ++j) {
                    const int row = row0 + rwl + ri * 16 + kg * 4 + j;
                    const int col = col0 + cwl + ci * 16 + mi;
                    out[(size_t)row * C_DIM + col] =
                        f2h((acc[ri][ci][j] + bias[col]) * scale);
                }
    } else {
        #pragma unroll
        for (int ri = 0; ri < 4; ++ri)
            #pragma unroll
            for (int ci = 0; ci < 4; ++ci)
                #pragma unroll
                for (int j = 0; j < 4; ++j) {
                    const int row = row0 + rwl + ri * 16 + kg * 4 + j;   // cout
                    const int col = col0 + cwl + ci * 16 + mi;           // token
                    Vt[(size_t)row * MROWS + col] = f2h(acc[ri][ci][j] + bv[row]);
                }
    }
}

// ---------------------------------------------------------------------------
// MFMA flash attention: block per (qtile=64, h, b), 4 waves x 16 q-rows,
// XOR-chunk-swizzled LDS, online softmax in registers, reg-prefetch of next
// K/V tile. XCD remap: each (h,b) pair's 12 causal blocks on ONE XCD
// (K/V reuse, ~1.6 MB/XCD), long-qt first for tail packing.
// ---------------------------------------------------------------------------
__global__ __launch_bounds__(256) void attn_mfma(
    const unsigned short* __restrict__ Qh, const unsigned short* __restrict__ Kh,
    const unsigned short* __restrict__ Vt, unsigned short* __restrict__ Yb)
{
    const int hw = blockIdx.x + 12 * (blockIdx.y + 16 * blockIdx.z);  // 0..767
    const int xcd = hw & 7, s = hw >> 3;            // s 0..95
    const int qt = 11 - (s % 12);                   // long blocks first
    const int pair = xcd + 8 * (s / 12);            // 0..63
    const int h = pair & 15, b = pair >> 4;

    const int tid = threadIdx.x;
    const int lane = tid & 63, w = tid >> 6;
    const int mi = lane & 15, kg = lane >> 4;
    const int q0 = qt * 64;

    __shared__ __align__(16) char ldsraw[24576];
    unsigned short* Ks = (unsigned short*)ldsraw;            // [64 key][64 c]
    unsigned short* Vs = (unsigned short*)(ldsraw + 8192);   // [64 d][64 key]
    unsigned short* Ps = (unsigned short*)(ldsraw + 16384);  // [64 q][64 key]
    float* Ob = (float*)ldsraw;                              // [64][68] after loop

    const size_t qkbase = (size_t)b * S_LEN * C_DIM + (size_t)h * HDIM;
    const unsigned short* Kbase = Kh + qkbase;
    const unsigned short* Vbase = Vt + (size_t)h * HDIM * MROWS + (size_t)b * S_LEN;

    // Q A-fragments: lane holds Q[q0+w*16+mi][kg*8..+8 (+32)]
    f16x8 QA0, QA1;
    {
        const unsigned short* qp = Qh + qkbase + (size_t)(q0 + w * 16 + mi) * C_DIM + kg * 8;
        QA0 = *(const f16x8*)qp;
        QA1 = *(const f16x8*)(qp + 32);
    }

    // staging: thread covers tile rows {srow, srow+32}, 16B chunk sc16
    const int srow = tid >> 3, sc16 = tid & 7;
    const int dch = (sc16 ^ (srow & 7)) << 3;   // swizzled half-offset in row

    float mrow[4], lrow[4], alj[4];
    f32x4 Oacc[4];
    #pragma unroll
    for (int j = 0; j < 4; ++j) { mrow[j] = -1e30f; lrow[j] = 0.f; }
    #pragma unroll
    for (int df = 0; df < 4; ++df) Oacc[df] = (f32x4){0.f, 0.f, 0.f, 0.f};

    // preload tile 0
    uint4 rk0, rk1, rv0, rv1;
    {
        const unsigned short* kp = Kbase + (size_t)srow * C_DIM + sc16 * 8;
        rk0 = *(const uint4*)kp;
        rk1 = *(const uint4*)(kp + (size_t)32 * C_DIM);
        const unsigned short* vp = Vbase + (size_t)srow * MROWS + sc16 * 8;
        rv0 = *(const uint4*)vp;
        rv1 = *(const uint4*)(vp + (size_t)32 * MROWS);
    }

    for (int kt = 0; kt <= qt; ++kt) {
        __syncthreads();   // prev tile's readers done
        *(uint4*)&Ks[srow * 64 + dch]        = rk0;
        *(uint4*)&Ks[(srow + 32) * 64 + dch] = rk1;
        *(uint4*)&Vs[srow * 64 + dch]        = rv0;
        *(uint4*)&Vs[(srow + 32) * 64 + dch] = rv1;
        if (kt < qt) {   // prefetch next tile (latency hides under compute)
            const unsigned short* kp = Kbase + (size_t)((kt + 1) * 64 + srow) * C_DIM + sc16 * 8;
            rk0 = *(const uint4*)kp;
            rk1 = *(const uint4*)(kp + (size_t)32 * C_DIM);
            const unsigned short* vp = Vbase + (size_t)srow * MROWS + (kt + 1) * 64 + sc16 * 8;
            rv0 = *(const uint4*)vp;
            rv1 = *(const uint4*)(vp + (size_t)32 * MROWS);
        }
        __syncthreads();   // stage visible

        // ---- scores S = Q @ K^T (16q x 64k per wave)
        f32x4 sa[4];
        #pragma unroll
        for (int kf = 0; kf < 4; ++kf) {
            const int key = kf * 16 + mi;
            const unsigned short* kr = Ks + key * 64;
            const f16x8 kb0 = *(const f16x8*)(kr + ((kg ^ (key & 7)) << 3));
            const f16x8 kb1 = *(const f16x8*)(kr + (((4 + kg) ^ (key & 7)) << 3));
            f32x4 z = {0.f, 0.f, 0.f, 0.f};
            z = __builtin_amdgcn_mfma_f32_16x16x32_f16(QA0, kb0, z, 0, 0, 0);
            sa[kf] = __builtin_amdgcn_mfma_f32_16x16x32_f16(QA1, kb1, z, 0, 0, 0);
        }

        if (kt == qt) {   // causal mask within diagonal tile
            #pragma unroll
            for (int kf = 0; kf < 4; ++kf)
                #pragma unroll
                for (int j = 0; j < 4; ++j)
                    if (kf * 16 + mi > w * 16 + kg * 4 + j) sa[kf][j] = -1e30f;
        }

        // ---- online softmax: row j lives in (kg,reg); reduce over mi lanes
        #pragma unroll
        for (int j = 0; j < 4; ++j) {
            float rm = fmaxf(fmaxf(sa[0][j], sa[1][j]), fmaxf(sa[2][j], sa[3][j]));
            rm = fmaxf(rm, __shfl_xor(rm, 1, 16));
            rm = fmaxf(rm, __shfl_xor(rm, 2, 16));
            rm = fmaxf(rm, __shfl_xor(rm, 4, 16));
            rm = fmaxf(rm, __shfl_xor(rm, 8, 16));
            const float mn = fmaxf(mrow[j], rm);
            alj[j] = __expf(mrow[j] - mn);
            mrow[j] = mn;
            const float p0 = __expf(sa[0][j] - mn);
            const float p1 = __expf(sa[1][j] - mn);
            const float p2 = __expf(sa[2][j] - mn);
            const float p3 = __expf(sa[3][j] - mn);
            const int prow = w * 16 + kg * 4 + j;
            unsigned short* pr = Ps + prow * 64;
            const int sw = prow & 7, hi = mi >> 3, lo = mi & 7;
            pr[(((0 + hi) ^ sw) << 3) + lo] = f2h(p0);
            pr[(((2 + hi) ^ sw) << 3) + lo] = f2h(p1);
            pr[(((4 + hi) ^ sw) << 3) + lo] = f2h(p2);
            pr[(((6 + hi) ^ sw) << 3) + lo] = f2h(p3);
            float rs = p0 + p1 + p2 + p3;
            rs += __shfl_xor(rs, 1, 16);
            rs += __shfl_xor(rs, 2, 16);
            rs += __shfl_xor(rs, 4, 16);
            rs += __shfl_xor(rs, 8, 16);
            lrow[j] = lrow[j] * alj[j] + rs;
        }
        // no barrier needed: P written & read by the SAME wave's strip only

        // ---- O = O*alpha + P @ V (16q x 64d per wave)
        const unsigned short* pp = Ps + (w * 16 + mi) * 64;
        const int psw = mi & 7;
        const f16x8 PA0 = *(const f16x8*)(pp + ((kg ^ psw) << 3));
        const f16x8 PA1 = *(const f16x8*)(pp + (((4 + kg) ^ psw) << 3));
        #pragma unroll
        for (int df = 0; df < 4; ++df) {
            const int d = df * 16 + mi;
            const unsigned short* vr = Vs + d * 64;
            const f16x8 vb0 = *(const f16x8*)(vr + ((kg ^ (d & 7)) << 3));
            const f16x8 vb1 = *(const f16x8*)(vr + (((4 + kg) ^ (d & 7)) << 3));
            f32x4 o = Oacc[df];
            o[0] *= alj[0]; o[1] *= alj[1]; o[2] *= alj[2]; o[3] *= alj[3];
            o = __builtin_amdgcn_mfma_f32_16x16x32_f16(PA0, vb0, o, 0, 0, 0);
            Oacc[df] = __builtin_amdgcn_mfma_f32_16x16x32_f16(PA1, vb1, o, 0, 0, 0);
        }
    }

    // ---- normalize, bounce through LDS (Ob aliases Ks/Vs/Ps), coalesced store
    __syncthreads();
    float inv[4];
    #pragma unroll
    for (int j = 0; j < 4; ++j) inv[j] = 1.0f / lrow[j];
    #pragma unroll
    for (int df = 0; df < 4; ++df)
        #pragma unroll
        for (int j = 0; j < 4; ++j)
            Ob[(w * 16 + kg * 4 + j) * 68 + df * 16 + mi] = Oacc[df][j] * inv[j];
    __syncthreads();

    const int orow = tid >> 2, oc0 = (tid & 3) * 16;
    unsigned short __align__(16) hx[16];
    #pragma unroll
    for (int i = 0; i < 16; ++i) hx[i] = f2bf(Ob[orow * 68 + oc0 + i]);
    unsigned short* yp = Yb + qkbase + (size_t)(q0 + orow) * C_DIM + oc0;
    *(uint4*)yp       = *(uint4*)&hx[0];
    *(uint4*)(yp + 8) = *(uint4*)&hx[8];
}

// ---------------------------------------------------------------------------
// Head: block per (b,t); bf16 final-LN row @ s=3t+1 times head_w -> f32 out.
// ---------------------------------------------------------------------------
__global__ __launch_bounds__(256) void head_kernel(
    const unsigned short* __restrict__ Xb, const float* __restrict__ hw,
    float* __restrict__ out)
{
    const int n = blockIdx.x;
    const int b = n >> 8, t = n & 255;
    const int tid = threadIdx.x;
    __shared__ float rowv[C_DIM];

    const unsigned short* x = Xb + ((size_t)b * S_LEN + 3 * t + 1) * C_DIM;
    #pragma unroll
    for (int j = 0; j < 4; ++j) rowv[tid + j * 256] = bf2f(x[tid + j * 256]);
    __syncthreads();

    if (tid < NACT) {
        float a = 0.f;
        for (int k = 0; k < C_DIM; ++k) a += rowv[k] * hw[k * NACT + tid];
        out[(size_t)n * NACT + tid] = a;
    }
}

// ---------------------------------------------------------------------------
extern "C" void kernel_launch(void* const* d_in, const int* in_sizes, int n_in,
                              void* d_out, int out_size, void* d_ws, size_t ws_size,
                              hipStream_t stream) {
    const float* states  = (const float*)d_in[0];
    const float* rtgs    = (const float*)d_in[1];
    const float* meta    = (const float*)d_in[2];
    const float* c1w = (const float*)d_in[4];
    const float* c1b = (const float*)d_in[5];
    const float* c2w = (const float*)d_in[6];
    const float* c2b = (const float*)d_in[7];
    const float* c3w = (const float*)d_in[8];
    const float* c3b = (const float*)d_in[9];
    const float* encw = (const float*)d_in[10];
    const float* encb = (const float*)d_in[11];
    const float* mw1 = (const float*)d_in[12];
    const float* mb1 = (const float*)d_in[13];
    const float* mw2 = (const float*)d_in[14];
    const float* mb2 = (const float*)d_in[15];
    const float* retw = (const float*)d_in[16];
    const float* retb = (const float*)d_in[17];
    const float* aemb = (const float*)d_in[18];
    const float* pos  = (const float*)d_in[19];
    const float* gpos = (const float*)d_in[20];
    const float* ln1g = (const float*)d_in[21];
    const float* ln1b = (const float*)d_in[22];
    const float* ln2g = (const float*)d_in[23];
    const float* ln2b = (const float*)d_in[24];
    const float* Wq = (const float*)d_in[25];
    const float* bq = (const float*)d_in[26];
    const float* Wk = (const float*)d_in[27];
    const float* bk = (const float*)d_in[28];
    const float* Wv = (const float*)d_in[29];
    const float* bv = (const float*)d_in[30];
    const float* Wo = (const float*)d_in[31];
    const float* bo = (const float*)d_in[32];
    const float* Wm1 = (const float*)d_in[33];
    const float* bm1 = (const float*)d_in[34];
    const float* Wm2 = (const float*)d_in[35];
    const float* bm2 = (const float*)d_in[36];
    const float* lnfg = (const float*)d_in[37];
    const float* lnfb = (const float*)d_in[38];
    const float* hw   = (const float*)d_in[39];
    const int* actions   = (const int*)d_in[40];
    const int* timesteps = (const int*)d_in[41];

    float* out = (float*)d_out;

    // ws layout (bytes): X[0,12M) Qh[12,18) Kh[18,24) Vt[24,30) Xb[48,54)
    //                    Yb[54,60) Wb[60,84).  Hb (MLP hidden bf16, 24 MB)
    //                    overlaps Qh/Kh/Vt (dead during MLP phase).
    char* wsc = (char*)d_ws;
    const size_t SLABB = (size_t)MROWS * C_DIM * 4;   // 12 MB
    float* X  = (float*)wsc;
    unsigned short* Qh = (unsigned short*)(wsc + SLABB);
    unsigned short* Kh = Qh + (size_t)MROWS * C_DIM;
    unsigned short* Vt = (unsigned short*)(wsc + 2 * SLABB);
    unsigned short* Hb = (unsigned short*)(wsc + SLABB);
    unsigned short* Xb = (unsigned short*)(wsc + 4 * SLABB);
    unsigned short* Yb = (unsigned short*)(wsc + 4 * SLABB + SLABB / 2);
    unsigned short* Wb = (unsigned short*)(wsc + 5 * SLABB);   // 24 MB

    embed_kernel<<<BATCH * TCTX, 256, 0, stream>>>(
        states, rtgs, meta, c1w, c1b, c2w, c2b, c3w, c3b, encw, encb,
        mw1, mb1, mw2, mb2, retw, retb, aemb, pos, gpos, actions, timesteps, X);

    const dim3 gres(8, 24, 4);     // split-K=4 residual GEMMs -> 768 blocks
    const dim3 g4096(32, 24);
    const dim3 gattn(12, NHEAD, BATCH);

    for (int i = 0; i < 6; ++i) {
        const size_t wOff = (size_t)i * C_DIM * C_DIM;
        const size_t bOff = (size_t)i * C_DIM;
        const size_t m1Off = (size_t)i * C_DIM * DFF;

        transpose_w_kernel<<<3072, 256, 0, stream>>>(
            Wq + wOff, Wk + wOff, Wv + wOff, Wo + wOff, Wm1 + m1Off, Wm2 + m1Off, Wb);

        ln_bf16_kernel<<<MROWS / 4, 256, 0, stream>>>(X, Xb, ln1g + bOff, ln1b + bOff);
        mfma_gemm_qkvt<<<576, 256, 0, stream>>>(
            Xb, Wb, bq + bOff, bk + bOff, bv + bOff, Qh, Kh, Vt);
        attn_mfma<<<gattn, 256, 0, stream>>>(Qh, Kh, Vt, Yb);
        mfma_gemm_ressplit<<<gres, 256, 0, stream>>>(
            Yb, Wb + (size_t)3 * 1048576, bo + bOff, X, C_DIM, C_DIM);
        ln_bf16_kernel<<<MROWS / 4, 256, 0, stream>>>(X, Xb, ln2g + bOff, ln2b + bOff);
        mfma_gemm_up<<<g4096, 256, 0, stream>>>(
            Xb, Wb + (size_t)4 * 1048576, bm1 + (size_t)i * DFF, Hb, DFF, C_DIM);
        mfma_gemm_ressplit<<<gres, 256, 0, stream>>>(
            Hb, Wb + (size_t)8 * 1048576, bm2 + bOff, X, C_DIM, DFF);
    }

    ln_bf16_kernel<<<MROWS / 4, 256, 0, stream>>>(X, Xb, lnfg, lnfb);
    head_kernel<<<BATCH * TCTX, 256, 0, stream>>>(Xb, hw, out);
}

// Round 5
// 2307.613 us; speedup vs baseline: 1.4766x; 1.0464x over previous
//
#include <hip/hip_runtime.h>
#include <hip/hip_bf16.h>

// ---------------------------------------------------------------------------
// Decision-Transformer forward, MI355X round 9:
//  - gemm_core pipeline buffers split into SIX DISTINCT __shared__ objects
//    (As0/As1/As2, Bs0/Bs1/Bs2). R8 evidence: FETCH halved but time flat,
//    MfmaUtil pinned at 11% == pure pipeline drain. LLVM LDS alias analysis
//    is object-granular: ds_read(As[0]) vs global_load_lds(As[2]) on ONE
//    array forces a compiler vmcnt(0) drain each step; distinct objects are
//    provably disjoint -> the counted vmcnt(4) is the only wait and the
//    2-deep pipeline finally holds across the barrier.
//  - Everything else (XCD remaps, split-K atomics onto X, fused qkvt, attn)
//    unchanged from round 8.
// Workspace: 84 MB (X 12 | Qh 6 | Kh 6 | Vt 6 | Xb 6 | Yb 6 | Wb 24).
// ---------------------------------------------------------------------------

#define S_LEN 768
#define C_DIM 1024
#define NHEAD 16
#define HDIM 64
#define BATCH 4
#define TCTX 256
#define DFF 4096
#define NACT 80
#define MROWS (BATCH * S_LEN)   // 3072

typedef __attribute__((ext_vector_type(4))) float f32x4;
typedef __attribute__((ext_vector_type(8))) short bf16x8;
typedef __attribute__((ext_vector_type(8))) _Float16 f16x8;

static __device__ __forceinline__ unsigned short f2bf(float f) {
    unsigned int u = __float_as_uint(f);
    u += 0x7FFF + ((u >> 16) & 1);          // RNE
    return (unsigned short)(u >> 16);
}
static __device__ __forceinline__ float bf2f(unsigned short h) {
    return __uint_as_float(((unsigned int)h) << 16);
}
static __device__ __forceinline__ unsigned short f2h(float f) {
    _Float16 h = (_Float16)f;
    return __builtin_bit_cast(unsigned short, h);
}

// async global -> LDS, 16 bytes per lane. LDS dest must be wave-uniform base
// + lane*16 contiguous (our staging layout is exactly that).
static __device__ __forceinline__ void gload16(void* l, const void* g) {
    __builtin_amdgcn_global_load_lds(
        (__attribute__((address_space(1))) void*)(g),
        (__attribute__((address_space(3))) void*)(l), 16, 0, 0);
}

// ---------------------------------------------------------------------------
// Weight conversion: per layer, f32 [K][N] -> bf16 transposed [N][K] in Wb.
// Wb elem offsets: WqT 0, WkT 1M, WvT 2M, WoT 3M, Wm1T 4M (N=4096,K=1024),
// Wm2T 8M (N=1024,K=4096). 64x64 tiles via LDS, coalesced in and out.
// ---------------------------------------------------------------------------
__global__ __launch_bounds__(256) void transpose_w_kernel(
    const float* __restrict__ Wq, const float* __restrict__ Wk,
    const float* __restrict__ Wv, const float* __restrict__ Wo,
    const float* __restrict__ Wm1, const float* __restrict__ Wm2,
    unsigned short* __restrict__ Wb)
{
    const int t = blockIdx.x;
    const float* src; unsigned short* dst; int K, N, kt, nt;
    if (t < 1024) {
        const int m = t >> 8, tile = t & 255;
        src = (m == 0) ? Wq : (m == 1) ? Wk : (m == 2) ? Wv : Wo;
        dst = Wb + (size_t)m * 1048576;
        K = 1024; N = 1024; kt = tile >> 4; nt = tile & 15;
    } else if (t < 2048) {
        const int tile = t - 1024;
        src = Wm1; dst = Wb + (size_t)4 * 1048576;
        K = 1024; N = 4096; kt = tile >> 6; nt = tile & 63;
    } else {
        const int tile = t - 2048;
        src = Wm2; dst = Wb + (size_t)8 * 1048576;
        K = 4096; N = 1024; kt = tile >> 4; nt = tile & 15;
    }
    const int k0 = kt * 64, n0 = nt * 64;
    __shared__ float Ls[64][65];

    const int r = threadIdx.x >> 2, p = threadIdx.x & 3;
    #pragma unroll
    for (int i = 0; i < 4; ++i)
        *(float4*)&Ls[r][p * 16 + i * 4] =
            *(const float4*)&src[(size_t)(k0 + r) * N + n0 + p * 16 + i * 4];
    __syncthreads();

    unsigned short __align__(16) h[16];
    #pragma unroll
    for (int i = 0; i < 16; ++i) h[i] = f2bf(Ls[p * 16 + i][r]);
    unsigned short* d = dst + (size_t)(n0 + r) * K + k0 + p * 16;
    *(uint4*)d       = *(uint4*)&h[0];
    *(uint4*)(d + 8) = *(uint4*)&h[8];
}

// ---------------------------------------------------------------------------
// Embedding (unchanged): one block per (b,t) -> X f32.
// ---------------------------------------------------------------------------
__global__ __launch_bounds__(256) void embed_kernel(
    const float* __restrict__ states, const float* __restrict__ rtgs,
    const float* __restrict__ meta,
    const float* __restrict__ c1w, const float* __restrict__ c1b,
    const float* __restrict__ c2w, const float* __restrict__ c2b,
    const float* __restrict__ c3w, const float* __restrict__ c3b,
    const float* __restrict__ encw, const float* __restrict__ encb,
    const float* __restrict__ mw1, const float* __restrict__ mb1,
    const float* __restrict__ mw2, const float* __restrict__ mb2,
    const float* __restrict__ retw, const float* __restrict__ retb,
    const float* __restrict__ aemb, const float* __restrict__ pos,
    const float* __restrict__ gpos,
    const int* __restrict__ actions, const int* __restrict__ timesteps,
    float* __restrict__ X)
{
    const int n = blockIdx.x;
    const int b = n >> 8, t = n & 255;
    const int tid = threadIdx.x;

    __shared__ float sin_[640];
    __shared__ float h1[96];
    __shared__ float h2[32];
    __shared__ float feat[16];
    __shared__ float hidm[32];
    __shared__ float mer[4];

    for (int e = tid; e < 640; e += 256)
        sin_[e] = states[(size_t)n * 640 + e];
    __syncthreads();

    if (tid < 96) {
        int o = tid / 6, rem = tid % 6, oh = rem / 3, ow = rem % 3;
        float a = c1b[o];
        for (int ci = 0; ci < 8; ++ci)
            for (int kh = 0; kh < 8; ++kh) {
                int ih = oh * 2 - 1 + kh;
                if (ih < 0 || ih >= 8) continue;
                for (int kw = 0; kw < 8; ++kw) {
                    int iw = ow * 2 - 1 + kw;
                    if (iw < 0 || iw >= 10) continue;
                    a += c1w[((o * 8 + ci) * 8 + kh) * 8 + kw] * sin_[ci * 80 + ih * 10 + iw];
                }
            }
        h1[tid] = fmaxf(a, 0.f);
    }
    if (tid < 32) {
        float a = mb1[tid];
        for (int i = 0; i < 4; ++i)
            a += meta[(size_t)n * 4 + i] * mw1[i * 32 + tid];
        hidm[tid] = fmaxf(a, 0.f);
    }
    __syncthreads();

    if (tid < 32) {
        float a = c2b[tid];
        for (int ci = 0; ci < 16; ++ci)
            for (int kh = 0; kh < 4; ++kh) {
                int ih = -1 + kh;
                if (ih < 0 || ih >= 2) continue;
                for (int kw = 0; kw < 4; ++kw) {
                    int iw = -1 + kw;
                    if (iw < 0 || iw >= 3) continue;
                    a += c2w[((tid * 16 + ci) * 4 + kh) * 4 + kw] * h1[ci * 6 + ih * 3 + iw];
                }
            }
        h2[tid] = fmaxf(a, 0.f);
    }
    __syncthreads();

    if (tid < 16) {
        float a = c3b[tid];
        for (int ci = 0; ci < 32; ++ci)
            a += c3w[(tid * 32 + ci) * 9 + 4] * h2[ci];
        feat[tid] = fmaxf(a, 0.f);
    }
    if (tid < 4) {
        float a = mb2[tid];
        for (int j = 0; j < 32; ++j) a += hidm[j] * mw2[j * 4 + tid];
        mer[tid] = a;
    }
    __syncthreads();

    const float r = rtgs[n];
    const int a_idx = actions[n];
    const int g = timesteps[b];
    const size_t xbase = ((size_t)b * S_LEN + 3 * t) * C_DIM;

    for (int c = tid; c < C_DIM; c += 256) {
        float se;
        if (c < 1020) {
            float acc = encb[c];
            #pragma unroll
            for (int k = 0; k < 16; ++k) acc += feat[k] * encw[k * 1020 + c];
            se = acc;
        } else {
            se = mer[c - 1020];
        }
        const float st = tanhf(se);
        const float rt = tanhf(r * retw[c] + retb[c]);
        const float ae = aemb[(size_t)a_idx * C_DIM + c];
        const float gp = gpos[(size_t)g * C_DIM + c];
        X[xbase + c]             = rt + gp + pos[(size_t)(3 * t + 0) * C_DIM + c];
        X[xbase + C_DIM + c]     = st + gp + pos[(size_t)(3 * t + 1) * C_DIM + c];
        X[xbase + 2 * C_DIM + c] = ae + gp + pos[(size_t)(3 * t + 2) * C_DIM + c];
    }
}

// ---------------------------------------------------------------------------
// LayerNorm over last dim (1024), bf16 output. Wave-per-row: 64-lane
// shfl_xor reduction, no LDS, no barriers. Block = 4 rows.
// ---------------------------------------------------------------------------
__global__ __launch_bounds__(256) void ln_bf16_kernel(
    const float* __restrict__ in, unsigned short* __restrict__ out,
    const float* __restrict__ gw, const float* __restrict__ bw)
{
    const int row = blockIdx.x * 4 + (threadIdx.x >> 6);
    const int lane = threadIdx.x & 63;
    const float* x = in + (size_t)row * C_DIM;

    float4 v[4];
    float s = 0.f;
    #pragma unroll
    for (int j = 0; j < 4; ++j) {
        v[j] = *(const float4*)&x[lane * 4 + j * 256];
        s += (v[j].x + v[j].y) + (v[j].z + v[j].w);
    }
    #pragma unroll
    for (int o = 1; o < 64; o <<= 1) s += __shfl_xor(s, o, 64);
    const float mean = s * (1.0f / 1024.0f);

    float s2 = 0.f;
    #pragma unroll
    for (int j = 0; j < 4; ++j) {
        float dx = v[j].x - mean, dy = v[j].y - mean;
        float dz = v[j].z - mean, dw = v[j].w - mean;
        s2 += (dx * dx + dy * dy) + (dz * dz + dw * dw);
    }
    #pragma unroll
    for (int o = 1; o < 64; o <<= 1) s2 += __shfl_xor(s2, o, 64);
    const float inv = rsqrtf(s2 * (1.0f / 1024.0f) + 1e-5f);

    #pragma unroll
    for (int j = 0; j < 4; ++j) {
        const int c = lane * 4 + j * 256;
        ushort4 o4;
        o4.x = f2bf((v[j].x - mean) * inv * gw[c + 0] + bw[c + 0]);
        o4.y = f2bf((v[j].y - mean) * inv * gw[c + 1] + bw[c + 1]);
        o4.z = f2bf((v[j].z - mean) * inv * gw[c + 2] + bw[c + 2]);
        o4.w = f2bf((v[j].w - mean) * inv * gw[c + 3] + bw[c + 3]);
        *(ushort4*)&out[(size_t)row * C_DIM + c] = o4;
    }
}

// ---------------------------------------------------------------------------
// MFMA GEMM core v4: A bf16 [M][ldk] row-major; Bt bf16 [N][ldk].
// 128x128 tile, BK=32, 4 waves, 4x4 16x16x32 frags each, f32 accum.
// 2-deep pipeline over SIX DISTINCT LDS objects (3 A-bufs, 3 B-bufs):
// distinct objects are disjoint to LLVM alias analysis, so ds_read(cur)
// cannot be ordered against the in-flight global_load_lds(prefetch) --
// the inline vmcnt(4) is the only wait (no compiler vmcnt(0) drain).
// Requires nk % 3 == 2 (true for all callers: nk in {8, 32}).
// ---------------------------------------------------------------------------
__device__ __forceinline__ void gemm_core(
    const unsigned short* __restrict__ A, const unsigned short* __restrict__ Bt,
    int row0, int col0, int ldk, int nk, f32x4 (&acc)[4][4])
{
    __shared__ __align__(16) unsigned short As0[4][128][8];
    __shared__ __align__(16) unsigned short As1[4][128][8];
    __shared__ __align__(16) unsigned short As2[4][128][8];
    __shared__ __align__(16) unsigned short Bs0[4][128][8];
    __shared__ __align__(16) unsigned short Bs1[4][128][8];
    __shared__ __align__(16) unsigned short Bs2[4][128][8];

    const int tid = threadIdx.x;
    const int ar  = tid & 63, akg = tid >> 6;     // staging: row, k-group(=wave)
    const int lane = tid & 63, w = tid >> 6;
    const int rwl = (w >> 1) * 64, cwl = (w & 1) * 64;
    const int mi = lane & 15, kg = lane >> 4;

    const unsigned short* pa = A + (size_t)(row0 + ar) * ldk + akg * 8;
    const unsigned short* pb = Bt + (size_t)(col0 + ar) * ldk + akg * 8;
    const size_t rstep = (size_t)64 * ldk;

    // prologue: stage k=0 -> buf0, k=1 -> buf1 (8 loads in flight per wave)
    gload16(&As0[akg][ar][0],      pa);
    gload16(&As0[akg][ar + 64][0], pa + rstep);
    gload16(&Bs0[akg][ar][0],      pb);
    gload16(&Bs0[akg][ar + 64][0], pb + rstep);
    gload16(&As1[akg][ar][0],      pa + 32);
    gload16(&As1[akg][ar + 64][0], pa + rstep + 32);
    gload16(&Bs1[akg][ar][0],      pb + 32);
    gload16(&Bs1[akg][ar + 64][0], pb + rstep + 32);

#define GEMM_STEP(AC, BC, AP, BP, KK, VM, PF)                              \
    {                                                                      \
        asm volatile("s_waitcnt vmcnt(" #VM ")" ::: "memory");             \
        __builtin_amdgcn_s_barrier();                                      \
        __builtin_amdgcn_sched_barrier(0);                                 \
        if (PF) {                                                          \
            const unsigned short* ga = pa + (size_t)((KK) + 2) * 32;       \
            const unsigned short* gb = pb + (size_t)((KK) + 2) * 32;       \
            gload16(&AP[akg][ar][0],      ga);                             \
            gload16(&AP[akg][ar + 64][0], ga + rstep);                     \
            gload16(&BP[akg][ar][0],      gb);                             \
            gload16(&BP[akg][ar + 64][0], gb + rstep);                     \
        }                                                                  \
        bf16x8 af[4], bfr[4];                                              \
        _Pragma("unroll")                                                  \
        for (int i = 0; i < 4; ++i) {                                      \
            af[i]  = *(const bf16x8*)&AC[kg][rwl + i * 16 + mi][0];        \
            bfr[i] = *(const bf16x8*)&BC[kg][cwl + i * 16 + mi][0];        \
        }                                                                  \
        __builtin_amdgcn_s_setprio(1);                                     \
        _Pragma("unroll")                                                  \
        for (int ri = 0; ri < 4; ++ri)                                     \
            _Pragma("unroll")                                              \
            for (int ci = 0; ci < 4; ++ci)                                 \
                acc[ri][ci] = __builtin_amdgcn_mfma_f32_16x16x32_bf16(     \
                    af[ri], bfr[ci], acc[ri][ci], 0, 0, 0);                \
        __builtin_amdgcn_s_setprio(0);                                     \
    }

    int k = 0;
    while (k + 4 < nk) {           // all three bodies prefetch (k+2 < nk-2)
        GEMM_STEP(As0, Bs0, As2, Bs2, k,     4, 1)
        GEMM_STEP(As1, Bs1, As0, Bs0, k + 1, 4, 1)
        GEMM_STEP(As2, Bs2, As1, Bs1, k + 2, 4, 1)
        k += 3;
    }
    // tail: nk % 3 == 2 -> exactly two steps remain, buffers 0 then 1
    GEMM_STEP(As0, Bs0, As2, Bs2, k,     4, 0)
    GEMM_STEP(As1, Bs1, As0, Bs0, k + 1, 0, 0)
#undef GEMM_STEP
}

// ---------------------------------------------------------------------------
// MLP-up GEMM (gelu -> bf16 out). Grid MUST be (32, 24).
// XCD remap: rows grouped per XCD (A-panel reuse stays in one L2).
// ---------------------------------------------------------------------------
__global__ __launch_bounds__(256) void mfma_gemm_up(
    const unsigned short* __restrict__ A, const unsigned short* __restrict__ Bt,
    const float* __restrict__ bias, unsigned short* __restrict__ outb,
    int N, int K)
{
    const int h = blockIdx.x + (blockIdx.y << 5);   // 0..767
    const int xcd = h & 7, s = h >> 3;              // s 0..95
    const int col0 = (s & 31) * 128;                // x fastest
    const int row0 = (xcd + 8 * (s >> 5)) * 128;    // y = xcd + 8*y'

    f32x4 acc[4][4] = {};
    gemm_core(A, Bt, row0, col0, K, K >> 5, acc);

    const int lane = threadIdx.x & 63, w = threadIdx.x >> 6;
    const int rwl = (w >> 1) * 64, cwl = (w & 1) * 64;
    const int mi = lane & 15, kg = lane >> 4;

    #pragma unroll
    for (int ri = 0; ri < 4; ++ri)
        #pragma unroll
        for (int ci = 0; ci < 4; ++ci)
            #pragma unroll
            for (int j = 0; j < 4; ++j) {
                const int row = row0 + rwl + ri * 16 + kg * 4 + j;
                const int col = col0 + cwl + ci * 16 + mi;
                float v = acc[ri][ci][j] + bias[col];
                v = 0.5f * v * (1.0f + erff(v * 0.70710678118f));
                outb[(size_t)row * N + col] = f2bf(v);
            }
}

// ---------------------------------------------------------------------------
// Split-K=4 residual-accumulate GEMM: X += A@Bt^T (+bias on split 0).
// Grid MUST be (8, 24, 4). XCD remap: y = xcd+8*y' (A reuse in-L2) AND the
// 4 K-splits of a tile are adjacent slots on the SAME XCD -> atomics
// accumulate in that XCD's L2, single writeback.
// ---------------------------------------------------------------------------
__global__ __launch_bounds__(256) void mfma_gemm_ressplit(
    const unsigned short* __restrict__ A, const unsigned short* __restrict__ Bt,
    const float* __restrict__ bias, float* __restrict__ X,
    int N, int K)
{
    const int h = blockIdx.x + (blockIdx.y << 3) + blockIdx.z * 192;  // 0..767
    const int xcd = h & 7, s = h >> 3;              // s 0..95
    const int ks = s & 3;                           // split: fastest (adjacent)
    const int col0 = ((s >> 2) & 7) * 128;
    const int row0 = (xcd + 8 * (s >> 5)) * 128;

    const int kseg = K >> 2;
    f32x4 acc[4][4] = {};
    gemm_core(A + (size_t)ks * kseg, Bt + (size_t)ks * kseg,
              row0, col0, K, kseg >> 5, acc);

    const int lane = threadIdx.x & 63, w = threadIdx.x >> 6;
    const int rwl = (w >> 1) * 64, cwl = (w & 1) * 64;
    const int mi = lane & 15, kg = lane >> 4;

    #pragma unroll
    for (int ri = 0; ri < 4; ++ri)
        #pragma unroll
        for (int ci = 0; ci < 4; ++ci)
            #pragma unroll
            for (int j = 0; j < 4; ++j) {
                const int row = row0 + rwl + ri * 16 + kg * 4 + j;
                const int col = col0 + cwl + ci * 16 + mi;
                float v = acc[ri][ci][j] + (ks == 0 ? bias[col] : 0.f);
                atomicAdd(&X[(size_t)row * N + col], v);
            }
}

// ---------------------------------------------------------------------------
// Fused Q/K/V^T producer, ONE dispatch of 576 blocks.
//  h <  384: Q or K tile. grp = Q(0)/K(1); fp16 out, Q pre-scaled 1/8.
//            XCD remap: token-row y = xcd + 8*y' (Xb panel reuse in-L2).
//  h >= 384: V^T tile via operand swap (V^T = WvT @ Xb^T); bias per ROW.
//            XCD remap: cout-tile y = xcd (WvT panel resident per XCD).
// ---------------------------------------------------------------------------
__global__ __launch_bounds__(256) void mfma_gemm_qkvt(
    const unsigned short* __restrict__ Xb, const unsigned short* __restrict__ Wb,
    const float* __restrict__ bq, const float* __restrict__ bk,
    const float* __restrict__ bv,
    unsigned short* __restrict__ Qh, unsigned short* __restrict__ Kh,
    unsigned short* __restrict__ Vt)
{
    const int h = blockIdx.x;
    const unsigned short *A, *Bt;
    int row0, col0, grp = -1;

    if (h < 384) {
        const int xcd = h & 7, s = h >> 3;          // s 0..47
        const int x = s & 15;                       // grp*8 + coltile
        const int y = xcd + 8 * (s >> 4);           // token row tile 0..23
        grp = x >> 3;
        A = Xb; Bt = Wb + (size_t)grp * 1048576;
        row0 = y * 128; col0 = (x & 7) * 128;
    } else {
        const int j = h - 384;
        const int xcd = j & 7, s = j >> 3;          // s 0..23
        A = Wb + (size_t)2 * 1048576; Bt = Xb;
        row0 = xcd * 128;                           // cout tile = xcd
        col0 = s * 128;                             // token tile
    }

    f32x4 acc[4][4] = {};
    gemm_core(A, Bt, row0, col0, C_DIM, 32, acc);

    const int lane = threadIdx.x & 63, w = threadIdx.x >> 6;
    const int rwl = (w >> 1) * 64, cwl = (w & 1) * 64;
    const int mi = lane & 15, kg = lane >> 4;

    if (grp >= 0) {
        const float* bias = grp == 0 ? bq : bk;
        unsigned short* out = grp == 0 ? Qh : Kh;
        const float scale = grp == 0 ? 0.125f : 1.0f;
        #pragma unroll
        for (int ri = 0; ri < 4; ++ri)
            #pragma unroll
            for (int ci = 0; ci < 4; ++ci)
                #pragma unroll
                for (int j = 0; j < 4; ++j) {
                    const int row = row0 + rwl + ri * 16 + kg * 4 + j;
                    const int col = col0 + cwl + ci * 16 + mi;
                    out[(size_t)row * C_DIM + col] =
                        f2h((acc[ri][ci][j] + bias[col]) * scale);
                }
    } else {
        #pragma unroll
        for (int ri = 0; ri < 4; ++ri)
            #pragma unroll
            for (int ci = 0; ci < 4; ++ci)
                #pragma unroll
                for (int j = 0; j < 4; ++j) {
                    const int row = row0 + rwl + ri * 16 + kg * 4 + j;   // cout
                    const int col = col0 + cwl + ci * 16 + mi;           // token
                    Vt[(size_t)row * MROWS + col] = f2h(acc[ri][ci][j] + bv[row]);
                }
    }
}

// ---------------------------------------------------------------------------
// MFMA flash attention: block per (qtile=64, h, b), 4 waves x 16 q-rows,
// XOR-chunk-swizzled LDS, online softmax in registers, reg-prefetch of next
// K/V tile. XCD remap: each (h,b) pair's 12 causal blocks on ONE XCD
// (K/V reuse, ~1.6 MB/XCD), long-qt first for tail packing.
// ---------------------------------------------------------------------------
__global__ __launch_bounds__(256) void attn_mfma(
    const unsigned short* __restrict__ Qh, const unsigned short* __restrict__ Kh,
    const unsigned short* __restrict__ Vt, unsigned short* __restrict__ Yb)
{
    const int hw = blockIdx.x + 12 * (blockIdx.y + 16 * blockIdx.z);  // 0..767
    const int xcd = hw & 7, s = hw >> 3;            // s 0..95
    const int qt = 11 - (s % 12);                   // long blocks first
    const int pair = xcd + 8 * (s / 12);            // 0..63
    const int h = pair & 15, b = pair >> 4;

    const int tid = threadIdx.x;
    const int lane = tid & 63, w = tid >> 6;
    const int mi = lane & 15, kg = lane >> 4;
    const int q0 = qt * 64;

    __shared__ __align__(16) char ldsraw[24576];
    unsigned short* Ks = (unsigned short*)ldsraw;            // [64 key][64 c]
    unsigned short* Vs = (unsigned short*)(ldsraw + 8192);   // [64 d][64 key]
    unsigned short* Ps = (unsigned short*)(ldsraw + 16384);  // [64 q][64 key]
    float* Ob = (float*)ldsraw;                              // [64][68] after loop

    const size_t qkbase = (size_t)b * S_LEN * C_DIM + (size_t)h * HDIM;
    const unsigned short* Kbase = Kh + qkbase;
    const unsigned short* Vbase = Vt + (size_t)h * HDIM * MROWS + (size_t)b * S_LEN;

    // Q A-fragments: lane holds Q[q0+w*16+mi][kg*8..+8 (+32)]
    f16x8 QA0, QA1;
    {
        const unsigned short* qp = Qh + qkbase + (size_t)(q0 + w * 16 + mi) * C_DIM + kg * 8;
        QA0 = *(const f16x8*)qp;
        QA1 = *(const f16x8*)(qp + 32);
    }

    // staging: thread covers tile rows {srow, srow+32}, 16B chunk sc16
    const int srow = tid >> 3, sc16 = tid & 7;
    const int dch = (sc16 ^ (srow & 7)) << 3;   // swizzled half-offset in row

    float mrow[4], lrow[4], alj[4];
    f32x4 Oacc[4];
    #pragma unroll
    for (int j = 0; j < 4; ++j) { mrow[j] = -1e30f; lrow[j] = 0.f; }
    #pragma unroll
    for (int df = 0; df < 4; ++df) Oacc[df] = (f32x4){0.f, 0.f, 0.f, 0.f};

    // preload tile 0
    uint4 rk0, rk1, rv0, rv1;
    {
        const unsigned short* kp = Kbase + (size_t)srow * C_DIM + sc16 * 8;
        rk0 = *(const uint4*)kp;
        rk1 = *(const uint4*)(kp + (size_t)32 * C_DIM);
        const unsigned short* vp = Vbase + (size_t)srow * MROWS + sc16 * 8;
        rv0 = *(const uint4*)vp;
        rv1 = *(const uint4*)(vp + (size_t)32 * MROWS);
    }

    for (int kt = 0; kt <= qt; ++kt) {
        __syncthreads();   // prev tile's readers done
        *(uint4*)&Ks[srow * 64 + dch]        = rk0;
        *(uint4*)&Ks[(srow + 32) * 64 + dch] = rk1;
        *(uint4*)&Vs[srow * 64 + dch]        = rv0;
        *(uint4*)&Vs[(srow + 32) * 64 + dch] = rv1;
        if (kt < qt) {   // prefetch next tile (latency hides under compute)
            const unsigned short* kp = Kbase + (size_t)((kt + 1) * 64 + srow) * C_DIM + sc16 * 8;
            rk0 = *(const uint4*)kp;
            rk1 = *(const uint4*)(kp + (size_t)32 * C_DIM);
            const unsigned short* vp = Vbase + (size_t)srow * MROWS + (kt + 1) * 64 + sc16 * 8;
            rv0 = *(const uint4*)vp;
            rv1 = *(const uint4*)(vp + (size_t)32 * MROWS);
        }
        __syncthreads();   // stage visible

        // ---- scores S = Q @ K^T (16q x 64k per wave)
        f32x4 sa[4];
        #pragma unroll
        for (int kf = 0; kf < 4; ++kf) {
            const int key = kf * 16 + mi;
            const unsigned short* kr = Ks + key * 64;
            const f16x8 kb0 = *(const f16x8*)(kr + ((kg ^ (key & 7)) << 3));
            const f16x8 kb1 = *(const f16x8*)(kr + (((4 + kg) ^ (key & 7)) << 3));
            f32x4 z = {0.f, 0.f, 0.f, 0.f};
            z = __builtin_amdgcn_mfma_f32_16x16x32_f16(QA0, kb0, z, 0, 0, 0);
            sa[kf] = __builtin_amdgcn_mfma_f32_16x16x32_f16(QA1, kb1, z, 0, 0, 0);
        }

        if (kt == qt) {   // causal mask within diagonal tile
            #pragma unroll
            for (int kf = 0; kf < 4; ++kf)
                #pragma unroll
                for (int j = 0; j < 4; ++j)
                    if (kf * 16 + mi > w * 16 + kg * 4 + j) sa[kf][j] = -1e30f;
        }

        // ---- online softmax: row j lives in (kg,reg); reduce over mi lanes
        #pragma unroll
        for (int j = 0; j < 4; ++j) {
            float rm = fmaxf(fmaxf(sa[0][j], sa[1][j]), fmaxf(sa[2][j], sa[3][j]));
            rm = fmaxf(rm, __shfl_xor(rm, 1, 16));
            rm = fmaxf(rm, __shfl_xor(rm, 2, 16));
            rm = fmaxf(rm, __shfl_xor(rm, 4, 16));
            rm = fmaxf(rm, __shfl_xor(rm, 8, 16));
            const float mn = fmaxf(mrow[j], rm);
            alj[j] = __expf(mrow[j] - mn);
            mrow[j] = mn;
            const float p0 = __expf(sa[0][j] - mn);
            const float p1 = __expf(sa[1][j] - mn);
            const float p2 = __expf(sa[2][j] - mn);
            const float p3 = __expf(sa[3][j] - mn);
            const int prow = w * 16 + kg * 4 + j;
            unsigned short* pr = Ps + prow * 64;
            const int sw = prow & 7, hi = mi >> 3, lo = mi & 7;
            pr[(((0 + hi) ^ sw) << 3) + lo] = f2h(p0);
            pr[(((2 + hi) ^ sw) << 3) + lo] = f2h(p1);
            pr[(((4 + hi) ^ sw) << 3) + lo] = f2h(p2);
            pr[(((6 + hi) ^ sw) << 3) + lo] = f2h(p3);
            float rs = p0 + p1 + p2 + p3;
            rs += __shfl_xor(rs, 1, 16);
            rs += __shfl_xor(rs, 2, 16);
            rs += __shfl_xor(rs, 4, 16);
            rs += __shfl_xor(rs, 8, 16);
            lrow[j] = lrow[j] * alj[j] + rs;
        }
        // no barrier needed: P written & read by the SAME wave's strip only

        // ---- O = O*alpha + P @ V (16q x 64d per wave)
        const unsigned short* pp = Ps + (w * 16 + mi) * 64;
        const int psw = mi & 7;
        const f16x8 PA0 = *(const f16x8*)(pp + ((kg ^ psw) << 3));
        const f16x8 PA1 = *(const f16x8*)(pp + (((4 + kg) ^ psw) << 3));
        #pragma unroll
        for (int df = 0; df < 4; ++df) {
            const int d = df * 16 + mi;
            const unsigned short* vr = Vs + d * 64;
            const f16x8 vb0 = *(const f16x8*)(vr + ((kg ^ (d & 7)) << 3));
            const f16x8 vb1 = *(const f16x8*)(vr + (((4 + kg) ^ (d & 7)) << 3));
            f32x4 o = Oacc[df];
            o[0] *= alj[0]; o[1] *= alj[1]; o[2] *= alj[2]; o[3] *= alj[3];
            o = __builtin_amdgcn_mfma_f32_16x16x32_f16(PA0, vb0, o, 0, 0, 0);
            Oacc[df] = __builtin_amdgcn_mfma_f32_16x16x32_f16(PA1, vb1, o, 0, 0, 0);
        }
    }

    // ---- normalize, bounce through LDS (Ob aliases Ks/Vs/Ps), coalesced store
    __syncthreads();
    float inv[4];
    #pragma unroll
    for (int j = 0; j < 4; ++j) inv[j] = 1.0f / lrow[j];
    #pragma unroll
    for (int df = 0; df < 4; ++df)
        #pragma unroll
        for (int j = 0; j < 4; ++j)
            Ob[(w * 16 + kg * 4 + j) * 68 + df * 16 + mi] = Oacc[df][j] * inv[j];
    __syncthreads();

    const int orow = tid >> 2, oc0 = (tid & 3) * 16;
    unsigned short __align__(16) hx[16];
    #pragma unroll
    for (int i = 0; i < 16; ++i) hx[i] = f2bf(Ob[orow * 68 + oc0 + i]);
    unsigned short* yp = Yb + qkbase + (size_t)(q0 + orow) * C_DIM + oc0;
    *(uint4*)yp       = *(uint4*)&hx[0];
    *(uint4*)(yp + 8) = *(uint4*)&hx[8];
}

// ---------------------------------------------------------------------------
// Head: block per (b,t); bf16 final-LN row @ s=3t+1 times head_w -> f32 out.
// ---------------------------------------------------------------------------
__global__ __launch_bounds__(256) void head_kernel(
    const unsigned short* __restrict__ Xb, const float* __restrict__ hw,
    float* __restrict__ out)
{
    const int n = blockIdx.x;
    const int b = n >> 8, t = n & 255;
    const int tid = threadIdx.x;
    __shared__ float rowv[C_DIM];

    const unsigned short* x = Xb + ((size_t)b * S_LEN + 3 * t + 1) * C_DIM;
    #pragma unroll
    for (int j = 0; j < 4; ++j) rowv[tid + j * 256] = bf2f(x[tid + j * 256]);
    __syncthreads();

    if (tid < NACT) {
        float a = 0.f;
        for (int k = 0; k < C_DIM; ++k) a += rowv[k] * hw[k * NACT + tid];
        out[(size_t)n * NACT + tid] = a;
    }
}

// ---------------------------------------------------------------------------
extern "C" void kernel_launch(void* const* d_in, const int* in_sizes, int n_in,
                              void* d_out, int out_size, void* d_ws, size_t ws_size,
                              hipStream_t stream) {
    const float* states  = (const float*)d_in[0];
    const float* rtgs    = (const float*)d_in[1];
    const float* meta    = (const float*)d_in[2];
    const float* c1w = (const float*)d_in[4];
    const float* c1b = (const float*)d_in[5];
    const float* c2w = (const float*)d_in[6];
    const float* c2b = (const float*)d_in[7];
    const float* c3w = (const float*)d_in[8];
    const float* c3b = (const float*)d_in[9];
    const float* encw = (const float*)d_in[10];
    const float* encb = (const float*)d_in[11];
    const float* mw1 = (const float*)d_in[12];
    const float* mb1 = (const float*)d_in[13];
    const float* mw2 = (const float*)d_in[14];
    const float* mb2 = (const float*)d_in[15];
    const float* retw = (const float*)d_in[16];
    const float* retb = (const float*)d_in[17];
    const float* aemb = (const float*)d_in[18];
    const float* pos  = (const float*)d_in[19];
    const float* gpos = (const float*)d_in[20];
    const float* ln1g = (const float*)d_in[21];
    const float* ln1b = (const float*)d_in[22];
    const float* ln2g = (const float*)d_in[23];
    const float* ln2b = (const float*)d_in[24];
    const float* Wq = (const float*)d_in[25];
    const float* bq = (const float*)d_in[26];
    const float* Wk = (const float*)d_in[27];
    const float* bk = (const float*)d_in[28];
    const float* Wv = (const float*)d_in[29];
    const float* bv = (const float*)d_in[30];
    const float* Wo = (const float*)d_in[31];
    const float* bo = (const float*)d_in[32];
    const float* Wm1 = (const float*)d_in[33];
    const float* bm1 = (const float*)d_in[34];
    const float* Wm2 = (const float*)d_in[35];
    const float* bm2 = (const float*)d_in[36];
    const float* lnfg = (const float*)d_in[37];
    const float* lnfb = (const float*)d_in[38];
    const float* hw   = (const float*)d_in[39];
    const int* actions   = (const int*)d_in[40];
    const int* timesteps = (const int*)d_in[41];

    float* out = (float*)d_out;

    // ws layout (bytes): X[0,12M) Qh[12,18) Kh[18,24) Vt[24,30) Xb[48,54)
    //                    Yb[54,60) Wb[60,84).  Hb (MLP hidden bf16, 24 MB)
    //                    overlaps Qh/Kh/Vt (dead during MLP phase).
    char* wsc = (char*)d_ws;
    const size_t SLABB = (size_t)MROWS * C_DIM * 4;   // 12 MB
    float* X  = (float*)wsc;
    unsigned short* Qh = (unsigned short*)(wsc + SLABB);
    unsigned short* Kh = Qh + (size_t)MROWS * C_DIM;
    unsigned short* Vt = (unsigned short*)(wsc + 2 * SLABB);
    unsigned short* Hb = (unsigned short*)(wsc + SLABB);
    unsigned short* Xb = (unsigned short*)(wsc + 4 * SLABB);
    unsigned short* Yb = (unsigned short*)(wsc + 4 * SLABB + SLABB / 2);
    unsigned short* Wb = (unsigned short*)(wsc + 5 * SLABB);   // 24 MB

    embed_kernel<<<BATCH * TCTX, 256, 0, stream>>>(
        states, rtgs, meta, c1w, c1b, c2w, c2b, c3w, c3b, encw, encb,
        mw1, mb1, mw2, mb2, retw, retb, aemb, pos, gpos, actions, timesteps, X);

    const dim3 gres(8, 24, 4);     // split-K=4 residual GEMMs -> 768 blocks
    const dim3 g4096(32, 24);
    const dim3 gattn(12, NHEAD, BATCH);

    for (int i = 0; i < 6; ++i) {
        const size_t wOff = (size_t)i * C_DIM * C_DIM;
        const size_t bOff = (size_t)i * C_DIM;
        const size_t m1Off = (size_t)i * C_DIM * DFF;

        transpose_w_kernel<<<3072, 256, 0, stream>>>(
            Wq + wOff, Wk + wOff, Wv + wOff, Wo + wOff, Wm1 + m1Off, Wm2 + m1Off, Wb);

        ln_bf16_kernel<<<MROWS / 4, 256, 0, stream>>>(X, Xb, ln1g + bOff, ln1b + bOff);
        mfma_gemm_qkvt<<<576, 256, 0, stream>>>(
            Xb, Wb, bq + bOff, bk + bOff, bv + bOff, Qh, Kh, Vt);
        attn_mfma<<<gattn, 256, 0, stream>>>(Qh, Kh, Vt, Yb);
        mfma_gemm_ressplit<<<gres, 256, 0, stream>>>(
            Yb, Wb + (size_t)3 * 1048576, bo + bOff, X, C_DIM, C_DIM);
        ln_bf16_kernel<<<MROWS / 4, 256, 0, stream>>>(X, Xb, ln2g + bOff, ln2b + bOff);
        mfma_gemm_up<<<g4096, 256, 0, stream>>>(
            Xb, Wb + (size_t)4 * 1048576, bm1 + (size_t)i * DFF, Hb, DFF, C_DIM);
        mfma_gemm_ressplit<<<gres, 256, 0, stream>>>(
            Hb, Wb + (size_t)8 * 1048576, bm2 + bOff, X, C_DIM, DFF);
    }

    ln_bf16_kernel<<<MROWS / 4, 256, 0, stream>>>(X, Xb, lnfg, lnfb);
    head_kernel<<<BATCH * TCTX, 256, 0, stream>>>(Xb, hw, out);
}

// Round 6
// 2085.489 us; speedup vs baseline: 1.6339x; 1.1065x over previous
//
#include <hip/hip_runtime.h>
#include <hip/hip_bf16.h>

// ---------------------------------------------------------------------------
// Decision-Transformer forward, MI355X round 10:
//  - ATOMIC-ECTOMY: split-K residual GEMMs (o-proj, MLP-down) no longer
//    atomicAdd onto X (R9 counters: WRITE=4x output, FETCH inflated by RMW
//    read-for-ownership -> 12.6M L2 RMWs clog the whole dispatch). Each
//    split now writes a plain f32 PARTIAL (streaming stores); the reduction
//    X += P0+P1 is FUSED into the immediately-following LayerNorm (X is
//    only ever read by LN kernels, so deferral is free).
//  - gemm_core K-loop generalized to any nk (uniform vm/pf guards).
//  - Workspace re-laid-out; Pm1 reuses Wb's first 12 MB (dead: Wb is
//    regenerated per layer) -> ln1 moved BEFORE transpose_w.
// Layout (MB): X[0,12) Xb[12,18) Yb[18,24) Qh[24,30) Kh[30,36) Vt[36,42)
//   Po0=24 Po1=36 (alias QKV, live o-proj->ln2) | Hb[18,42) (MLP phase)
//   Pm0=42 Pm1=60 (Pm1 in dead Wb head) | Wb[60,84).
// ---------------------------------------------------------------------------

#define S_LEN 768
#define C_DIM 1024
#define NHEAD 16
#define HDIM 64
#define BATCH 4
#define TCTX 256
#define DFF 4096
#define NACT 80
#define MROWS (BATCH * S_LEN)   // 3072

typedef __attribute__((ext_vector_type(4))) float f32x4;
typedef __attribute__((ext_vector_type(8))) short bf16x8;
typedef __attribute__((ext_vector_type(8))) _Float16 f16x8;

static __device__ __forceinline__ unsigned short f2bf(float f) {
    unsigned int u = __float_as_uint(f);
    u += 0x7FFF + ((u >> 16) & 1);          // RNE
    return (unsigned short)(u >> 16);
}
static __device__ __forceinline__ float bf2f(unsigned short h) {
    return __uint_as_float(((unsigned int)h) << 16);
}
static __device__ __forceinline__ unsigned short f2h(float f) {
    _Float16 h = (_Float16)f;
    return __builtin_bit_cast(unsigned short, h);
}

// async global -> LDS, 16 bytes per lane. LDS dest must be wave-uniform base
// + lane*16 contiguous (our staging layout is exactly that).
static __device__ __forceinline__ void gload16(void* l, const void* g) {
    __builtin_amdgcn_global_load_lds(
        (__attribute__((address_space(1))) void*)(g),
        (__attribute__((address_space(3))) void*)(l), 16, 0, 0);
}

// ---------------------------------------------------------------------------
// Weight conversion: per layer, f32 [K][N] -> bf16 transposed [N][K] in Wb.
// Wb elem offsets: WqT 0, WkT 1M, WvT 2M, WoT 3M, Wm1T 4M (N=4096,K=1024),
// Wm2T 8M (N=1024,K=4096). 64x64 tiles via LDS, coalesced in and out.
// ---------------------------------------------------------------------------
__global__ __launch_bounds__(256) void transpose_w_kernel(
    const float* __restrict__ Wq, const float* __restrict__ Wk,
    const float* __restrict__ Wv, const float* __restrict__ Wo,
    const float* __restrict__ Wm1, const float* __restrict__ Wm2,
    unsigned short* __restrict__ Wb)
{
    const int t = blockIdx.x;
    const float* src; unsigned short* dst; int K, N, kt, nt;
    if (t < 1024) {
        const int m = t >> 8, tile = t & 255;
        src = (m == 0) ? Wq : (m == 1) ? Wk : (m == 2) ? Wv : Wo;
        dst = Wb + (size_t)m * 1048576;
        K = 1024; N = 1024; kt = tile >> 4; nt = tile & 15;
    } else if (t < 2048) {
        const int tile = t - 1024;
        src = Wm1; dst = Wb + (size_t)4 * 1048576;
        K = 1024; N = 4096; kt = tile >> 6; nt = tile & 63;
    } else {
        const int tile = t - 2048;
        src = Wm2; dst = Wb + (size_t)8 * 1048576;
        K = 4096; N = 1024; kt = tile >> 4; nt = tile & 15;
    }
    const int k0 = kt * 64, n0 = nt * 64;
    __shared__ float Ls[64][65];

    const int r = threadIdx.x >> 2, p = threadIdx.x & 3;
    #pragma unroll
    for (int i = 0; i < 4; ++i)
        *(float4*)&Ls[r][p * 16 + i * 4] =
            *(const float4*)&src[(size_t)(k0 + r) * N + n0 + p * 16 + i * 4];
    __syncthreads();

    unsigned short __align__(16) h[16];
    #pragma unroll
    for (int i = 0; i < 16; ++i) h[i] = f2bf(Ls[p * 16 + i][r]);
    unsigned short* d = dst + (size_t)(n0 + r) * K + k0 + p * 16;
    *(uint4*)d       = *(uint4*)&h[0];
    *(uint4*)(d + 8) = *(uint4*)&h[8];
}

// ---------------------------------------------------------------------------
// Embedding (unchanged): one block per (b,t) -> X f32.
// ---------------------------------------------------------------------------
__global__ __launch_bounds__(256) void embed_kernel(
    const float* __restrict__ states, const float* __restrict__ rtgs,
    const float* __restrict__ meta,
    const float* __restrict__ c1w, const float* __restrict__ c1b,
    const float* __restrict__ c2w, const float* __restrict__ c2b,
    const float* __restrict__ c3w, const float* __restrict__ c3b,
    const float* __restrict__ encw, const float* __restrict__ encb,
    const float* __restrict__ mw1, const float* __restrict__ mb1,
    const float* __restrict__ mw2, const float* __restrict__ mb2,
    const float* __restrict__ retw, const float* __restrict__ retb,
    const float* __restrict__ aemb, const float* __restrict__ pos,
    const float* __restrict__ gpos,
    const int* __restrict__ actions, const int* __restrict__ timesteps,
    float* __restrict__ X)
{
    const int n = blockIdx.x;
    const int b = n >> 8, t = n & 255;
    const int tid = threadIdx.x;

    __shared__ float sin_[640];
    __shared__ float h1[96];
    __shared__ float h2[32];
    __shared__ float feat[16];
    __shared__ float hidm[32];
    __shared__ float mer[4];

    for (int e = tid; e < 640; e += 256)
        sin_[e] = states[(size_t)n * 640 + e];
    __syncthreads();

    if (tid < 96) {
        int o = tid / 6, rem = tid % 6, oh = rem / 3, ow = rem % 3;
        float a = c1b[o];
        for (int ci = 0; ci < 8; ++ci)
            for (int kh = 0; kh < 8; ++kh) {
                int ih = oh * 2 - 1 + kh;
                if (ih < 0 || ih >= 8) continue;
                for (int kw = 0; kw < 8; ++kw) {
                    int iw = ow * 2 - 1 + kw;
                    if (iw < 0 || iw >= 10) continue;
                    a += c1w[((o * 8 + ci) * 8 + kh) * 8 + kw] * sin_[ci * 80 + ih * 10 + iw];
                }
            }
        h1[tid] = fmaxf(a, 0.f);
    }
    if (tid < 32) {
        float a = mb1[tid];
        for (int i = 0; i < 4; ++i)
            a += meta[(size_t)n * 4 + i] * mw1[i * 32 + tid];
        hidm[tid] = fmaxf(a, 0.f);
    }
    __syncthreads();

    if (tid < 32) {
        float a = c2b[tid];
        for (int ci = 0; ci < 16; ++ci)
            for (int kh = 0; kh < 4; ++kh) {
                int ih = -1 + kh;
                if (ih < 0 || ih >= 2) continue;
                for (int kw = 0; kw < 4; ++kw) {
                    int iw = -1 + kw;
                    if (iw < 0 || iw >= 3) continue;
                    a += c2w[((tid * 16 + ci) * 4 + kh) * 4 + kw] * h1[ci * 6 + ih * 3 + iw];
                }
            }
        h2[tid] = fmaxf(a, 0.f);
    }
    __syncthreads();

    if (tid < 16) {
        float a = c3b[tid];
        for (int ci = 0; ci < 32; ++ci)
            a += c3w[(tid * 32 + ci) * 9 + 4] * h2[ci];
        feat[tid] = fmaxf(a, 0.f);
    }
    if (tid < 4) {
        float a = mb2[tid];
        for (int j = 0; j < 32; ++j) a += hidm[j] * mw2[j * 4 + tid];
        mer[tid] = a;
    }
    __syncthreads();

    const float r = rtgs[n];
    const int a_idx = actions[n];
    const int g = timesteps[b];
    const size_t xbase = ((size_t)b * S_LEN + 3 * t) * C_DIM;

    for (int c = tid; c < C_DIM; c += 256) {
        float se;
        if (c < 1020) {
            float acc = encb[c];
            #pragma unroll
            for (int k = 0; k < 16; ++k) acc += feat[k] * encw[k * 1020 + c];
            se = acc;
        } else {
            se = mer[c - 1020];
        }
        const float st = tanhf(se);
        const float rt = tanhf(r * retw[c] + retb[c]);
        const float ae = aemb[(size_t)a_idx * C_DIM + c];
        const float gp = gpos[(size_t)g * C_DIM + c];
        X[xbase + c]             = rt + gp + pos[(size_t)(3 * t + 0) * C_DIM + c];
        X[xbase + C_DIM + c]     = st + gp + pos[(size_t)(3 * t + 1) * C_DIM + c];
        X[xbase + 2 * C_DIM + c] = ae + gp + pos[(size_t)(3 * t + 2) * C_DIM + c];
    }
}

// ---------------------------------------------------------------------------
// LayerNorm (plain): reads X, writes bf16 Xb. Wave-per-row, block = 4 rows.
// ---------------------------------------------------------------------------
__global__ __launch_bounds__(256) void ln_bf16_kernel(
    const float* __restrict__ in, unsigned short* __restrict__ out,
    const float* __restrict__ gw, const float* __restrict__ bw)
{
    const int row = blockIdx.x * 4 + (threadIdx.x >> 6);
    const int lane = threadIdx.x & 63;
    const float* x = in + (size_t)row * C_DIM;

    float4 v[4];
    float s = 0.f;
    #pragma unroll
    for (int j = 0; j < 4; ++j) {
        v[j] = *(const float4*)&x[lane * 4 + j * 256];
        s += (v[j].x + v[j].y) + (v[j].z + v[j].w);
    }
    #pragma unroll
    for (int o = 1; o < 64; o <<= 1) s += __shfl_xor(s, o, 64);
    const float mean = s * (1.0f / 1024.0f);

    float s2 = 0.f;
    #pragma unroll
    for (int j = 0; j < 4; ++j) {
        float dx = v[j].x - mean, dy = v[j].y - mean;
        float dz = v[j].z - mean, dw = v[j].w - mean;
        s2 += (dx * dx + dy * dy) + (dz * dz + dw * dw);
    }
    #pragma unroll
    for (int o = 1; o < 64; o <<= 1) s2 += __shfl_xor(s2, o, 64);
    const float inv = rsqrtf(s2 * (1.0f / 1024.0f) + 1e-5f);

    #pragma unroll
    for (int j = 0; j < 4; ++j) {
        const int c = lane * 4 + j * 256;
        ushort4 o4;
        o4.x = f2bf((v[j].x - mean) * inv * gw[c + 0] + bw[c + 0]);
        o4.y = f2bf((v[j].y - mean) * inv * gw[c + 1] + bw[c + 1]);
        o4.z = f2bf((v[j].z - mean) * inv * gw[c + 2] + bw[c + 2]);
        o4.w = f2bf((v[j].w - mean) * inv * gw[c + 3] + bw[c + 3]);
        *(ushort4*)&out[(size_t)row * C_DIM + c] = o4;
    }
}

// ---------------------------------------------------------------------------
// Fused reduce + LayerNorm: xr = X + P0 + P1 (bias pre-folded into P0).
// Writes xr back to X (residual stream) and LN(xr) -> bf16 out.
// ---------------------------------------------------------------------------
__global__ __launch_bounds__(256) void ln_red_bf16_kernel(
    float* __restrict__ X,
    const float* __restrict__ P0, const float* __restrict__ P1,
    unsigned short* __restrict__ out,
    const float* __restrict__ gw, const float* __restrict__ bw)
{
    const int row = blockIdx.x * 4 + (threadIdx.x >> 6);
    const int lane = threadIdx.x & 63;
    const size_t rb = (size_t)row * C_DIM;

    float4 v[4];
    float s = 0.f;
    #pragma unroll
    for (int j = 0; j < 4; ++j) {
        const int c = lane * 4 + j * 256;
        float4 a = *(const float4*)&X[rb + c];
        float4 p = *(const float4*)&P0[rb + c];
        float4 q = *(const float4*)&P1[rb + c];
        v[j].x = a.x + p.x + q.x;
        v[j].y = a.y + p.y + q.y;
        v[j].z = a.z + p.z + q.z;
        v[j].w = a.w + p.w + q.w;
        *(float4*)&X[rb + c] = v[j];
        s += (v[j].x + v[j].y) + (v[j].z + v[j].w);
    }
    #pragma unroll
    for (int o = 1; o < 64; o <<= 1) s += __shfl_xor(s, o, 64);
    const float mean = s * (1.0f / 1024.0f);

    float s2 = 0.f;
    #pragma unroll
    for (int j = 0; j < 4; ++j) {
        float dx = v[j].x - mean, dy = v[j].y - mean;
        float dz = v[j].z - mean, dw = v[j].w - mean;
        s2 += (dx * dx + dy * dy) + (dz * dz + dw * dw);
    }
    #pragma unroll
    for (int o = 1; o < 64; o <<= 1) s2 += __shfl_xor(s2, o, 64);
    const float inv = rsqrtf(s2 * (1.0f / 1024.0f) + 1e-5f);

    #pragma unroll
    for (int j = 0; j < 4; ++j) {
        const int c = lane * 4 + j * 256;
        ushort4 o4;
        o4.x = f2bf((v[j].x - mean) * inv * gw[c + 0] + bw[c + 0]);
        o4.y = f2bf((v[j].y - mean) * inv * gw[c + 1] + bw[c + 1]);
        o4.z = f2bf((v[j].z - mean) * inv * gw[c + 2] + bw[c + 2]);
        o4.w = f2bf((v[j].w - mean) * inv * gw[c + 3] + bw[c + 3]);
        *(ushort4*)&out[rb + c] = o4;
    }
}

// ---------------------------------------------------------------------------
// MFMA GEMM core v5: A bf16 [M][ldk] row-major; Bt bf16 [N][ldk].
// 128x128 tile, BK=32, 4 waves, 4x4 16x16x32 frags each, f32 accum.
// 2-deep pipeline over six distinct LDS objects; GENERAL nk (uniform
// vm/pf guards: wait vmcnt(4) unless last step, prefetch while k+2 < nk).
// ---------------------------------------------------------------------------
__device__ __forceinline__ void gemm_core(
    const unsigned short* __restrict__ A, const unsigned short* __restrict__ Bt,
    int row0, int col0, int ldk, int nk, f32x4 (&acc)[4][4])
{
    __shared__ __align__(16) unsigned short As0[4][128][8];
    __shared__ __align__(16) unsigned short As1[4][128][8];
    __shared__ __align__(16) unsigned short As2[4][128][8];
    __shared__ __align__(16) unsigned short Bs0[4][128][8];
    __shared__ __align__(16) unsigned short Bs1[4][128][8];
    __shared__ __align__(16) unsigned short Bs2[4][128][8];

    const int tid = threadIdx.x;
    const int ar  = tid & 63, akg = tid >> 6;     // staging: row, k-group(=wave)
    const int lane = tid & 63, w = tid >> 6;
    const int rwl = (w >> 1) * 64, cwl = (w & 1) * 64;
    const int mi = lane & 15, kg = lane >> 4;

    const unsigned short* pa = A + (size_t)(row0 + ar) * ldk + akg * 8;
    const unsigned short* pb = Bt + (size_t)(col0 + ar) * ldk + akg * 8;
    const size_t rstep = (size_t)64 * ldk;

    // prologue: stage k=0 -> buf0, k=1 -> buf1 (8 loads in flight per wave)
    gload16(&As0[akg][ar][0],      pa);
    gload16(&As0[akg][ar + 64][0], pa + rstep);
    gload16(&Bs0[akg][ar][0],      pb);
    gload16(&Bs0[akg][ar + 64][0], pb + rstep);
    gload16(&As1[akg][ar][0],      pa + 32);
    gload16(&As1[akg][ar + 64][0], pa + rstep + 32);
    gload16(&Bs1[akg][ar][0],      pb + 32);
    gload16(&Bs1[akg][ar + 64][0], pb + rstep + 32);

#define GEMM_STEP(AC, BC, AP, BP, KK)                                      \
    {                                                                      \
        if ((KK) + 1 < nk) { asm volatile("s_waitcnt vmcnt(4)" ::: "memory"); } \
        else               { asm volatile("s_waitcnt vmcnt(0)" ::: "memory"); } \
        __builtin_amdgcn_s_barrier();                                      \
        __builtin_amdgcn_sched_barrier(0);                                 \
        if ((KK) + 2 < nk) {                                               \
            const unsigned short* ga = pa + (size_t)((KK) + 2) * 32;       \
            const unsigned short* gb = pb + (size_t)((KK) + 2) * 32;       \
            gload16(&AP[akg][ar][0],      ga);                             \
            gload16(&AP[akg][ar + 64][0], ga + rstep);                     \
            gload16(&BP[akg][ar][0],      gb);                             \
            gload16(&BP[akg][ar + 64][0], gb + rstep);                     \
        }                                                                  \
        bf16x8 af[4], bfr[4];                                              \
        _Pragma("unroll")                                                  \
        for (int i = 0; i < 4; ++i) {                                      \
            af[i]  = *(const bf16x8*)&AC[kg][rwl + i * 16 + mi][0];        \
            bfr[i] = *(const bf16x8*)&BC[kg][cwl + i * 16 + mi][0];        \
        }                                                                  \
        __builtin_amdgcn_s_setprio(1);                                     \
        _Pragma("unroll")                                                  \
        for (int ri = 0; ri < 4; ++ri)                                     \
            _Pragma("unroll")                                              \
            for (int ci = 0; ci < 4; ++ci)                                 \
                acc[ri][ci] = __builtin_amdgcn_mfma_f32_16x16x32_bf16(     \
                    af[ri], bfr[ci], acc[ri][ci], 0, 0, 0);                \
        __builtin_amdgcn_s_setprio(0);                                     \
    }

    int k = 0;
    while (k < nk) {
        GEMM_STEP(As0, Bs0, As2, Bs2, k)
        if (k + 1 < nk) GEMM_STEP(As1, Bs1, As0, Bs0, k + 1)
        if (k + 2 < nk) GEMM_STEP(As2, Bs2, As1, Bs1, k + 2)
        k += 3;
    }
#undef GEMM_STEP
}

// ---------------------------------------------------------------------------
// MLP-up GEMM (gelu -> bf16 out). Grid MUST be (32, 24).
// XCD remap: rows grouped per XCD (A-panel reuse stays in one L2).
// ---------------------------------------------------------------------------
__global__ __launch_bounds__(256) void mfma_gemm_up(
    const unsigned short* __restrict__ A, const unsigned short* __restrict__ Bt,
    const float* __restrict__ bias, unsigned short* __restrict__ outb,
    int N, int K)
{
    const int h = blockIdx.x + (blockIdx.y << 5);   // 0..767
    const int xcd = h & 7, s = h >> 3;              // s 0..95
    const int col0 = (s & 31) * 128;                // x fastest
    const int row0 = (xcd + 8 * (s >> 5)) * 128;    // y = xcd + 8*y'

    f32x4 acc[4][4] = {};
    gemm_core(A, Bt, row0, col0, K, K >> 5, acc);

    const int lane = threadIdx.x & 63, w = threadIdx.x >> 6;
    const int rwl = (w >> 1) * 64, cwl = (w & 1) * 64;
    const int mi = lane & 15, kg = lane >> 4;

    #pragma unroll
    for (int ri = 0; ri < 4; ++ri)
        #pragma unroll
        for (int ci = 0; ci < 4; ++ci)
            #pragma unroll
            for (int j = 0; j < 4; ++j) {
                const int row = row0 + rwl + ri * 16 + kg * 4 + j;
                const int col = col0 + cwl + ci * 16 + mi;
                float v = acc[ri][ci][j] + bias[col];
                v = 0.5f * v * (1.0f + erff(v * 0.70710678118f));
                outb[(size_t)row * N + col] = f2bf(v);
            }
}

// ---------------------------------------------------------------------------
// Split-K=2 GEMM -> f32 PARTIALS (no atomics, no X access). Grid (8,24,2).
// ks==0 folds bias. Partial ks goes to P0/P1 (plain streaming stores).
// XCD remap: y = xcd+8*y', splits of a tile adjacent on the same XCD.
// ---------------------------------------------------------------------------
__global__ __launch_bounds__(256) void mfma_gemm_split2(
    const unsigned short* __restrict__ A, const unsigned short* __restrict__ Bt,
    const float* __restrict__ bias,
    float* __restrict__ P0, float* __restrict__ P1,
    int N, int K)
{
    const int h = blockIdx.x + (blockIdx.y << 3) + blockIdx.z * 192;  // 0..383
    const int xcd = h & 7, s = h >> 3;              // s 0..47
    const int ks = s & 1;                           // split fastest (same XCD)
    const int col0 = ((s >> 1) & 7) * 128;
    const int row0 = (xcd + 8 * (s >> 4)) * 128;

    const int kseg = K >> 1;
    f32x4 acc[4][4] = {};
    gemm_core(A + (size_t)ks * kseg, Bt + (size_t)ks * kseg,
              row0, col0, K, kseg >> 5, acc);

    float* P = ks == 0 ? P0 : P1;
    const int lane = threadIdx.x & 63, w = threadIdx.x >> 6;
    const int rwl = (w >> 1) * 64, cwl = (w & 1) * 64;
    const int mi = lane & 15, kg = lane >> 4;

    #pragma unroll
    for (int ri = 0; ri < 4; ++ri)
        #pragma unroll
        for (int ci = 0; ci < 4; ++ci)
            #pragma unroll
            for (int j = 0; j < 4; ++j) {
                const int row = row0 + rwl + ri * 16 + kg * 4 + j;
                const int col = col0 + cwl + ci * 16 + mi;
                P[(size_t)row * N + col] =
                    acc[ri][ci][j] + (ks == 0 ? bias[col] : 0.f);
            }
}

// ---------------------------------------------------------------------------
// Fused Q/K/V^T producer, ONE dispatch of 576 blocks (unchanged).
// ---------------------------------------------------------------------------
__global__ __launch_bounds__(256) void mfma_gemm_qkvt(
    const unsigned short* __restrict__ Xb, const unsigned short* __restrict__ Wb,
    const float* __restrict__ bq, const float* __restrict__ bk,
    const float* __restrict__ bv,
    unsigned short* __restrict__ Qh, unsigned short* __restrict__ Kh,
    unsigned short* __restrict__ Vt)
{
    const int h = blockIdx.x;
    const unsigned short *A, *Bt;
    int row0, col0, grp = -1;

    if (h < 384) {
        const int xcd = h & 7, s = h >> 3;          // s 0..47
        const int x = s & 15;                       // grp*8 + coltile
        const int y = xcd + 8 * (s >> 4);           // token row tile 0..23
        grp = x >> 3;
        A = Xb; Bt = Wb + (size_t)grp * 1048576;
        row0 = y * 128; col0 = (x & 7) * 128;
    } else {
        const int j = h - 384;
        const int xcd = j & 7, s = j >> 3;          // s 0..23
        A = Wb + (size_t)2 * 1048576; Bt = Xb;
        row0 = xcd * 128;                           // cout tile = xcd
        col0 = s * 128;                             // token tile
    }

    f32x4 acc[4][4] = {};
    gemm_core(A, Bt, row0, col0, C_DIM, 32, acc);

    const int lane = threadIdx.x & 63, w = threadIdx.x >> 6;
    const int rwl = (w >> 1) * 64, cwl = (w & 1) * 64;
    const int mi = lane & 15, kg = lane >> 4;

    if (grp >= 0) {
        const float* bias = grp == 0 ? bq : bk;
        unsigned short* out = grp == 0 ? Qh : Kh;
        const float scale = grp == 0 ? 0.125f : 1.0f;
        #pragma unroll
        for (int ri = 0; ri < 4; ++ri)
            #pragma unroll
            for (int ci = 0; ci < 4; ++ci)
                #pragma unroll
                for (int j = 0; j < 4; ++j) {
                    const int row = row0 + rwl + ri * 16 + kg * 4 + j;
                    const int col = col0 + cwl + ci * 16 + mi;
                    out[(size_t)row * C_DIM + col] =
                        f2h((acc[ri][ci][j] + bias[col]) * scale);
                }
    } else {
        #pragma unroll
        for (int ri = 0; ri < 4; ++ri)
            #pragma unroll
            for (int ci = 0; ci < 4; ++ci)
                #pragma unroll
                for (int j = 0; j < 4; ++j) {
                    const int row = row0 + rwl + ri * 16 + kg * 4 + j;   // cout
                    const int col = col0 + cwl + ci * 16 + mi;           // token
                    Vt[(size_t)row * MROWS + col] = f2h(acc[ri][ci][j] + bv[row]);
                }
    }
}

// ---------------------------------------------------------------------------
// MFMA flash attention (unchanged from round 8).
// ---------------------------------------------------------------------------
__global__ __launch_bounds__(256) void attn_mfma(
    const unsigned short* __restrict__ Qh, const unsigned short* __restrict__ Kh,
    const unsigned short* __restrict__ Vt, unsigned short* __restrict__ Yb)
{
    const int hw = blockIdx.x + 12 * (blockIdx.y + 16 * blockIdx.z);  // 0..767
    const int xcd = hw & 7, s = hw >> 3;            // s 0..95
    const int qt = 11 - (s % 12);                   // long blocks first
    const int pair = xcd + 8 * (s / 12);            // 0..63
    const int h = pair & 15, b = pair >> 4;

    const int tid = threadIdx.x;
    const int lane = tid & 63, w = tid >> 6;
    const int mi = lane & 15, kg = lane >> 4;
    const int q0 = qt * 64;

    __shared__ __align__(16) char ldsraw[24576];
    unsigned short* Ks = (unsigned short*)ldsraw;            // [64 key][64 c]
    unsigned short* Vs = (unsigned short*)(ldsraw + 8192);   // [64 d][64 key]
    unsigned short* Ps = (unsigned short*)(ldsraw + 16384);  // [64 q][64 key]
    float* Ob = (float*)ldsraw;                              // [64][68] after loop

    const size_t qkbase = (size_t)b * S_LEN * C_DIM + (size_t)h * HDIM;
    const unsigned short* Kbase = Kh + qkbase;
    const unsigned short* Vbase = Vt + (size_t)h * HDIM * MROWS + (size_t)b * S_LEN;

    // Q A-fragments: lane holds Q[q0+w*16+mi][kg*8..+8 (+32)]
    f16x8 QA0, QA1;
    {
        const unsigned short* qp = Qh + qkbase + (size_t)(q0 + w * 16 + mi) * C_DIM + kg * 8;
        QA0 = *(const f16x8*)qp;
        QA1 = *(const f16x8*)(qp + 32);
    }

    // staging: thread covers tile rows {srow, srow+32}, 16B chunk sc16
    const int srow = tid >> 3, sc16 = tid & 7;
    const int dch = (sc16 ^ (srow & 7)) << 3;   // swizzled half-offset in row

    float mrow[4], lrow[4], alj[4];
    f32x4 Oacc[4];
    #pragma unroll
    for (int j = 0; j < 4; ++j) { mrow[j] = -1e30f; lrow[j] = 0.f; }
    #pragma unroll
    for (int df = 0; df < 4; ++df) Oacc[df] = (f32x4){0.f, 0.f, 0.f, 0.f};

    // preload tile 0
    uint4 rk0, rk1, rv0, rv1;
    {
        const unsigned short* kp = Kbase + (size_t)srow * C_DIM + sc16 * 8;
        rk0 = *(const uint4*)kp;
        rk1 = *(const uint4*)(kp + (size_t)32 * C_DIM);
        const unsigned short* vp = Vbase + (size_t)srow * MROWS + sc16 * 8;
        rv0 = *(const uint4*)vp;
        rv1 = *(const uint4*)(vp + (size_t)32 * MROWS);
    }

    for (int kt = 0; kt <= qt; ++kt) {
        __syncthreads();   // prev tile's readers done
        *(uint4*)&Ks[srow * 64 + dch]        = rk0;
        *(uint4*)&Ks[(srow + 32) * 64 + dch] = rk1;
        *(uint4*)&Vs[srow * 64 + dch]        = rv0;
        *(uint4*)&Vs[(srow + 32) * 64 + dch] = rv1;
        if (kt < qt) {   // prefetch next tile (latency hides under compute)
            const unsigned short* kp = Kbase + (size_t)((kt + 1) * 64 + srow) * C_DIM + sc16 * 8;
            rk0 = *(const uint4*)kp;
            rk1 = *(const uint4*)(kp + (size_t)32 * C_DIM);
            const unsigned short* vp = Vbase + (size_t)srow * MROWS + (kt + 1) * 64 + sc16 * 8;
            rv0 = *(const uint4*)vp;
            rv1 = *(const uint4*)(vp + (size_t)32 * MROWS);
        }
        __syncthreads();   // stage visible

        // ---- scores S = Q @ K^T (16q x 64k per wave)
        f32x4 sa[4];
        #pragma unroll
        for (int kf = 0; kf < 4; ++kf) {
            const int key = kf * 16 + mi;
            const unsigned short* kr = Ks + key * 64;
            const f16x8 kb0 = *(const f16x8*)(kr + ((kg ^ (key & 7)) << 3));
            const f16x8 kb1 = *(const f16x8*)(kr + (((4 + kg) ^ (key & 7)) << 3));
            f32x4 z = {0.f, 0.f, 0.f, 0.f};
            z = __builtin_amdgcn_mfma_f32_16x16x32_f16(QA0, kb0, z, 0, 0, 0);
            sa[kf] = __builtin_amdgcn_mfma_f32_16x16x32_f16(QA1, kb1, z, 0, 0, 0);
        }

        if (kt == qt) {   // causal mask within diagonal tile
            #pragma unroll
            for (int kf = 0; kf < 4; ++kf)
                #pragma unroll
                for (int j = 0; j < 4; ++j)
                    if (kf * 16 + mi > w * 16 + kg * 4 + j) sa[kf][j] = -1e30f;
        }

        // ---- online softmax: row j lives in (kg,reg); reduce over mi lanes
        #pragma unroll
        for (int j = 0; j < 4; ++j) {
            float rm = fmaxf(fmaxf(sa[0][j], sa[1][j]), fmaxf(sa[2][j], sa[3][j]));
            rm = fmaxf(rm, __shfl_xor(rm, 1, 16));
            rm = fmaxf(rm, __shfl_xor(rm, 2, 16));
            rm = fmaxf(rm, __shfl_xor(rm, 4, 16));
            rm = fmaxf(rm, __shfl_xor(rm, 8, 16));
            const float mn = fmaxf(mrow[j], rm);
            alj[j] = __expf(mrow[j] - mn);
            mrow[j] = mn;
            const float p0 = __expf(sa[0][j] - mn);
            const float p1 = __expf(sa[1][j] - mn);
            const float p2 = __expf(sa[2][j] - mn);
            const float p3 = __expf(sa[3][j] - mn);
            const int prow = w * 16 + kg * 4 + j;
            unsigned short* pr = Ps + prow * 64;
            const int sw = prow & 7, hi = mi >> 3, lo = mi & 7;
            pr[(((0 + hi) ^ sw) << 3) + lo] = f2h(p0);
            pr[(((2 + hi) ^ sw) << 3) + lo] = f2h(p1);
            pr[(((4 + hi) ^ sw) << 3) + lo] = f2h(p2);
            pr[(((6 + hi) ^ sw) << 3) + lo] = f2h(p3);
            float rs = p0 + p1 + p2 + p3;
            rs += __shfl_xor(rs, 1, 16);
            rs += __shfl_xor(rs, 2, 16);
            rs += __shfl_xor(rs, 4, 16);
            rs += __shfl_xor(rs, 8, 16);
            lrow[j] = lrow[j] * alj[j] + rs;
        }
        // no barrier needed: P written & read by the SAME wave's strip only

        // ---- O = O*alpha + P @ V (16q x 64d per wave)
        const unsigned short* pp = Ps + (w * 16 + mi) * 64;
        const int psw = mi & 7;
        const f16x8 PA0 = *(const f16x8*)(pp + ((kg ^ psw) << 3));
        const f16x8 PA1 = *(const f16x8*)(pp + (((4 + kg) ^ psw) << 3));
        #pragma unroll
        for (int df = 0; df < 4; ++df) {
            const int d = df * 16 + mi;
            const unsigned short* vr = Vs + d * 64;
            const f16x8 vb0 = *(const f16x8*)(vr + ((kg ^ (d & 7)) << 3));
            const f16x8 vb1 = *(const f16x8*)(vr + (((4 + kg) ^ (d & 7)) << 3));
            f32x4 o = Oacc[df];
            o[0] *= alj[0]; o[1] *= alj[1]; o[2] *= alj[2]; o[3] *= alj[3];
            o = __builtin_amdgcn_mfma_f32_16x16x32_f16(PA0, vb0, o, 0, 0, 0);
            Oacc[df] = __builtin_amdgcn_mfma_f32_16x16x32_f16(PA1, vb1, o, 0, 0, 0);
        }
    }

    // ---- normalize, bounce through LDS (Ob aliases Ks/Vs/Ps), coalesced store
    __syncthreads();
    float inv[4];
    #pragma unroll
    for (int j = 0; j < 4; ++j) inv[j] = 1.0f / lrow[j];
    #pragma unroll
    for (int df = 0; df < 4; ++df)
        #pragma unroll
        for (int j = 0; j < 4; ++j)
            Ob[(w * 16 + kg * 4 + j) * 68 + df * 16 + mi] = Oacc[df][j] * inv[j];
    __syncthreads();

    const int orow = tid >> 2, oc0 = (tid & 3) * 16;
    unsigned short __align__(16) hx[16];
    #pragma unroll
    for (int i = 0; i < 16; ++i) hx[i] = f2bf(Ob[orow * 68 + oc0 + i]);
    unsigned short* yp = Yb + qkbase + (size_t)(q0 + orow) * C_DIM + oc0;
    *(uint4*)yp       = *(uint4*)&hx[0];
    *(uint4*)(yp + 8) = *(uint4*)&hx[8];
}

// ---------------------------------------------------------------------------
// Head: block per (b,t); bf16 final-LN row @ s=3t+1 times head_w -> f32 out.
// ---------------------------------------------------------------------------
__global__ __launch_bounds__(256) void head_kernel(
    const unsigned short* __restrict__ Xb, const float* __restrict__ hw,
    float* __restrict__ out)
{
    const int n = blockIdx.x;
    const int b = n >> 8, t = n & 255;
    const int tid = threadIdx.x;
    __shared__ float rowv[C_DIM];

    const unsigned short* x = Xb + ((size_t)b * S_LEN + 3 * t + 1) * C_DIM;
    #pragma unroll
    for (int j = 0; j < 4; ++j) rowv[tid + j * 256] = bf2f(x[tid + j * 256]);
    __syncthreads();

    if (tid < NACT) {
        float a = 0.f;
        for (int k = 0; k < C_DIM; ++k) a += rowv[k] * hw[k * NACT + tid];
        out[(size_t)n * NACT + tid] = a;
    }
}

// ---------------------------------------------------------------------------
extern "C" void kernel_launch(void* const* d_in, const int* in_sizes, int n_in,
                              void* d_out, int out_size, void* d_ws, size_t ws_size,
                              hipStream_t stream) {
    const float* states  = (const float*)d_in[0];
    const float* rtgs    = (const float*)d_in[1];
    const float* meta    = (const float*)d_in[2];
    const float* c1w = (const float*)d_in[4];
    const float* c1b = (const float*)d_in[5];
    const float* c2w = (const float*)d_in[6];
    const float* c2b = (const float*)d_in[7];
    const float* c3w = (const float*)d_in[8];
    const float* c3b = (const float*)d_in[9];
    const float* encw = (const float*)d_in[10];
    const float* encb = (const float*)d_in[11];
    const float* mw1 = (const float*)d_in[12];
    const float* mb1 = (const float*)d_in[13];
    const float* mw2 = (const float*)d_in[14];
    const float* mb2 = (const float*)d_in[15];
    const float* retw = (const float*)d_in[16];
    const float* retb = (const float*)d_in[17];
    const float* aemb = (const float*)d_in[18];
    const float* pos  = (const float*)d_in[19];
    const float* gpos = (const float*)d_in[20];
    const float* ln1g = (const float*)d_in[21];
    const float* ln1b = (const float*)d_in[22];
    const float* ln2g = (const float*)d_in[23];
    const float* ln2b = (const float*)d_in[24];
    const float* Wq = (const float*)d_in[25];
    const float* bq = (const float*)d_in[26];
    const float* Wk = (const float*)d_in[27];
    const float* bk = (const float*)d_in[28];
    const float* Wv = (const float*)d_in[29];
    const float* bv = (const float*)d_in[30];
    const float* Wo = (const float*)d_in[31];
    const float* bo = (const float*)d_in[32];
    const float* Wm1 = (const float*)d_in[33];
    const float* bm1 = (const float*)d_in[34];
    const float* Wm2 = (const float*)d_in[35];
    const float* bm2 = (const float*)d_in[36];
    const float* lnfg = (const float*)d_in[37];
    const float* lnfb = (const float*)d_in[38];
    const float* hw   = (const float*)d_in[39];
    const int* actions   = (const int*)d_in[40];
    const int* timesteps = (const int*)d_in[41];

    float* out = (float*)d_out;

    // Layout (MB): X[0,12) Xb[12,18) Yb[18,24) Qh[24,30) Kh[30,36) Vt[36,42)
    //   Po0@24 Po1@36 (alias QKV; live o-proj -> ln2_red)
    //   Hb[18,42) (MLP phase; Yb/QKV dead)
    //   Pm0@42 Pm1@60 (Pm1 in Wb head, dead; read by ln1_red BEFORE
    //   transpose_w regenerates Wb) | Wb[60,84).
    char* wsc = (char*)d_ws;
    const size_t MB = (size_t)1 << 20;
    float*          X   = (float*)wsc;
    unsigned short* Xb  = (unsigned short*)(wsc + 12 * MB);
    unsigned short* Yb  = (unsigned short*)(wsc + 18 * MB);
    unsigned short* Qh  = (unsigned short*)(wsc + 24 * MB);
    unsigned short* Kh  = (unsigned short*)(wsc + 30 * MB);
    unsigned short* Vt  = (unsigned short*)(wsc + 36 * MB);
    float*          Po0 = (float*)(wsc + 24 * MB);
    float*          Po1 = (float*)(wsc + 36 * MB);
    unsigned short* Hb  = (unsigned short*)(wsc + 18 * MB);
    float*          Pm0 = (float*)(wsc + 42 * MB);
    float*          Pm1 = (float*)(wsc + 60 * MB);
    unsigned short* Wb  = (unsigned short*)(wsc + 60 * MB);

    embed_kernel<<<BATCH * TCTX, 256, 0, stream>>>(
        states, rtgs, meta, c1w, c1b, c2w, c2b, c3w, c3b, encw, encb,
        mw1, mb1, mw2, mb2, retw, retb, aemb, pos, gpos, actions, timesteps, X);

    const dim3 gsplit(8, 24, 2);   // split-K=2 partial GEMMs -> 384 blocks
    const dim3 g4096(32, 24);
    const dim3 gattn(12, NHEAD, BATCH);

    for (int i = 0; i < 6; ++i) {
        const size_t wOff = (size_t)i * C_DIM * C_DIM;
        const size_t bOff = (size_t)i * C_DIM;
        const size_t m1Off = (size_t)i * C_DIM * DFF;

        // ln1: layer 0 plain; layers 1..5 fused with MLP-down partial reduce.
        // MUST run before transpose_w (Pm1 lives in Wb's dead head).
        if (i == 0)
            ln_bf16_kernel<<<MROWS / 4, 256, 0, stream>>>(
                X, Xb, ln1g + bOff, ln1b + bOff);
        else
            ln_red_bf16_kernel<<<MROWS / 4, 256, 0, stream>>>(
                X, Pm0, Pm1, Xb, ln1g + bOff, ln1b + bOff);

        transpose_w_kernel<<<3072, 256, 0, stream>>>(
            Wq + wOff, Wk + wOff, Wv + wOff, Wo + wOff, Wm1 + m1Off, Wm2 + m1Off, Wb);

        mfma_gemm_qkvt<<<576, 256, 0, stream>>>(
            Xb, Wb, bq + bOff, bk + bOff, bv + bOff, Qh, Kh, Vt);
        attn_mfma<<<gattn, 256, 0, stream>>>(Qh, Kh, Vt, Yb);

        // o-proj -> partials Po0/Po1 (bias folded into Po0)
        mfma_gemm_split2<<<gsplit, 256, 0, stream>>>(
            Yb, Wb + (size_t)3 * 1048576, bo + bOff, Po0, Po1, C_DIM, C_DIM);
        // ln2 fused with o-proj reduce: X += Po0+Po1, Xb = LN(X)
        ln_red_bf16_kernel<<<MROWS / 4, 256, 0, stream>>>(
            X, Po0, Po1, Xb, ln2g + bOff, ln2b + bOff);

        mfma_gemm_up<<<g4096, 256, 0, stream>>>(
            Xb, Wb + (size_t)4 * 1048576, bm1 + (size_t)i * DFF, Hb, DFF, C_DIM);
        // MLP-down -> partials Pm0/Pm1 (bias folded into Pm0)
        mfma_gemm_split2<<<gsplit, 256, 0, stream>>>(
            Hb, Wb + (size_t)8 * 1048576, bm2 + bOff, Pm0, Pm1, C_DIM, DFF);
    }

    // final LN fused with last MLP-down reduce
    ln_red_bf16_kernel<<<MROWS / 4, 256, 0, stream>>>(
        X, Pm0, Pm1, Xb, lnfg, lnfb);
    head_kernel<<<BATCH * TCTX, 256, 0, stream>>>(Xb, hw, out);
}